// Round 1
// baseline (5012.877 us; speedup 1.0000x reference)
//
#include <hip/hip_runtime.h>
#include <math.h>

#define N_ENT 30000
#define R_REL 1000
#define T_EDGE 300000
#define B_PAIR 1024
#define NNZ_E 600000
#define GAMMAF 3.0f
#define EPSV 1e-12f
#define EMBD 768
#define NJT 469  // ceil(30000/64)

__device__ inline unsigned fenc(float f){ unsigned u=__float_as_uint(f); return (u&0x80000000u)? ~u : (u|0x80000000u); }
__device__ inline float fdec(unsigned k){ return (k&0x80000000u)? __uint_as_float(k&0x7fffffffu) : __uint_as_float(~k); }

__device__ inline float waveRedSum(float v){
  #pragma unroll
  for(int m=32;m>=1;m>>=1) v += __shfl_xor(v, m, 64);
  return v;
}

// ---- degree count: one thread per edge ----
__global__ __launch_bounds__(256) void k_deg(const int* __restrict__ row, float* deg, int nE){
  int e = blockIdx.x*256 + threadIdx.x;
  if(e < nE) unsafeAtomicAdd(&deg[row[e]], 1.0f);
}

// ---- _avg accumulate: wave per edge, float2 per lane ----
__global__ __launch_bounds__(256) void k_avg(const int* __restrict__ rows, const int* __restrict__ cols,
                      const float* __restrict__ deg, const float* __restrict__ src,
                      float* dst, int nE){
  int wid = (blockIdx.x*256 + threadIdx.x) >> 6;
  int lane = threadIdx.x & 63;
  if (wid >= nE) return;
  int r = rows[wid], c = cols[wid];
  float inv = 1.0f / deg[r];
  float2 v = *(const float2*)(src + (size_t)c*128 + lane*2);
  unsafeAtomicAdd(dst + (size_t)r*128 + lane*2    , v.x*inv);
  unsafeAtomicAdd(dst + (size_t)r*128 + lane*2 + 1, v.y*inv);
}

// ---- normalized relation table + attention dots (4 kernels) ----
__global__ __launch_bounds__(256) void k_relnorm(const float* __restrict__ rel, const float* __restrict__ ae,
                          const float* __restrict__ ar, float* relnorm, float* attdot){
  int r = (blockIdx.x*256 + threadIdx.x) >> 6;
  int lane = threadIdx.x & 63;
  if (r >= R_REL) return;
  float2 v = *(const float2*)(rel + (size_t)r*128 + lane*2);
  float ss = waveRedSum(v.x*v.x + v.y*v.y);
  float nrm = fmaxf(sqrtf(ss), EPSV);
  float2 u; u.x = v.x/nrm; u.y = v.y/nrm;
  *(float2*)(relnorm + (size_t)r*128 + lane*2) = u;
  const float* ks[4] = {ae, ae+128, ar, ar+128};
  #pragma unroll
  for(int k=0;k<4;k++){
    float2 w = *(const float2*)(ks[k] + lane*2);
    float d = waveRedSum(u.x*w.x + u.y*w.y);
    if(lane==0) attdot[k*R_REL + r] = d;
  }
}

// ---- tanh: working features + emb slice write ----
__global__ __launch_bounds__(256) void k_tanh(const float* __restrict__ src, float* featA, float* emb, int coloff){
  int i = blockIdx.x*256 + threadIdx.x;
  if(i >= N_ENT*128) return;
  float v = tanhf(src[i]);
  featA[i] = v;
  int n = i >> 7, d = i & 127;
  emb[(size_t)n*EMBD + coloff + d] = v;
}

// ---- att raw + segment max (ordered-uint atomicMax) ----
__global__ __launch_bounds__(256) void k_attmax(const int* __restrict__ row, const int* __restrict__ rid,
                         const float* __restrict__ attdot_k, float* att_raw, unsigned* segmax){
  int t = blockIdx.x*256 + threadIdx.x;
  if(t >= T_EDGE) return;
  float a = attdot_k[rid[t]];
  att_raw[t] = a;
  atomicMax(segmax + row[t], fenc(a));
}

// ---- exp + segment sum ----
__global__ __launch_bounds__(256) void k_attexp(const int* __restrict__ row, float* att_raw,
                         const unsigned* __restrict__ segmax, float* segsum){
  int t = blockIdx.x*256 + threadIdx.x;
  if(t >= T_EDGE) return;
  int r = row[t];
  float e = expf(att_raw[t] - fdec(segmax[r]));
  att_raw[t] = e;
  unsafeAtomicAdd(segsum + r, e);
}

// ---- GAT edge pass: wave per edge, Householder reflect + softmax weight, atomic scatter ----
__global__ __launch_bounds__(256) void k_edge(const int* __restrict__ row, const int* __restrict__ col,
                       const int* __restrict__ rid, const float* __restrict__ relnorm,
                       const float* __restrict__ featA, const float* __restrict__ att_raw,
                       const float* __restrict__ segsum, float* featB){
  int wid = (blockIdx.x*256 + threadIdx.x) >> 6;
  int lane = threadIdx.x & 63;
  if (wid >= T_EDGE) return;
  int r = row[wid], c = col[wid], q = rid[wid];
  float2 u = *(const float2*)(relnorm + (size_t)q*128 + lane*2);
  float2 h = *(const float2*)(featA   + (size_t)c*128 + lane*2);
  float dot = waveRedSum(h.x*u.x + h.y*u.y);
  float a = att_raw[wid] / segsum[r];
  float t2 = 2.0f*dot;
  unsafeAtomicAdd(featB + (size_t)r*128 + lane*2    , a*(h.x - t2*u.x));
  unsafeAtomicAdd(featB + (size_t)r*128 + lane*2 + 1, a*(h.y - t2*u.y));
}

// ---- gather pair rows, pos, c_i = pos + gamma - ||a||^2 ----
__global__ __launch_bounds__(256) void k_gather(const float* __restrict__ emb, const int* __restrict__ tp,
                         float* W, float* cvec){
  int i = blockIdx.x; int tid = threadIdx.x;
  int l = tp[2*i], r = tp[2*i+1];
  float sl=0.f, sr=0.f, sp=0.f;
  for(int c=tid;c<EMBD;c+=256){
    float le = emb[(size_t)l*EMBD+c], re = emb[(size_t)r*EMBD+c];
    W[(size_t)i*EMBD+c]=le; W[(size_t)(B_PAIR+i)*EMBD+c]=re;
    sl += le*le; sr += re*re; float d = le-re; sp += d*d;
  }
  __shared__ float s0[256], s1[256], s2[256];
  s0[tid]=sl; s1[tid]=sr; s2[tid]=sp;
  __syncthreads();
  for(int w=128;w>0;w>>=1){
    if(tid<w){ s0[tid]+=s0[tid+w]; s1[tid]+=s1[tid+w]; s2[tid]+=s2[tid+w]; }
    __syncthreads();
  }
  if(tid==0){
    float pos = s2[0];
    cvec[i]        = pos + GAMMAF - s0[0];
    cvec[B_PAIR+i] = pos + GAMMAF - s1[0];
  }
}

// ---- q_j = ||emb_j||^2, wave per node ----
__global__ __launch_bounds__(256) void k_qn(const float* __restrict__ emb, float* qn){
  int j = (blockIdx.x*256 + threadIdx.x) >> 6;
  int lane = threadIdx.x & 63;
  if(j >= N_ENT) return;
  float s=0.f;
  #pragma unroll
  for(int q=0;q<12;q++){ float v = emb[(size_t)j*EMBD + lane + 64*q]; s += v*v; }
  s = waveRedSum(s);
  if(lane==0) qn[j]=s;
}

// ================== shared GEMM mainloop (64x64x16 fp32 tile) ==================
#define GEMM_MAIN(W_, EMB_) \
  __shared__ float As[16][68]; \
  __shared__ float Bs[16][68]; \
  int tid = threadIdx.x; \
  int tx = tid & 15, ty = tid >> 4; \
  int m0 = blockIdx.y*64, n0 = blockIdx.x*64; \
  int lm = tid >> 2, lk = (tid & 3) * 4; \
  float acc[4][4] = {}; \
  const float* aPtr = W_ + (size_t)(m0+lm)*EMBD + lk; \
  int gn = n0 + lm; \
  const float* bPtr = EMB_ + (size_t)gn*EMBD + lk; \
  bool bok = gn < N_ENT; \
  for(int k0=0;k0<EMBD;k0+=16){ \
    float4 av = *(const float4*)(aPtr + k0); \
    float4 bv = bok ? *(const float4*)(bPtr + k0) : make_float4(0.f,0.f,0.f,0.f); \
    As[lk+0][lm]=av.x; As[lk+1][lm]=av.y; As[lk+2][lm]=av.z; As[lk+3][lm]=av.w; \
    Bs[lk+0][lm]=bv.x; Bs[lk+1][lm]=bv.y; Bs[lk+2][lm]=bv.z; Bs[lk+3][lm]=bv.w; \
    __syncthreads(); \
    _Pragma("unroll") \
    for(int k=0;k<16;k++){ \
      float4 a = *(const float4*)&As[k][ty*4]; \
      float4 b = *(const float4*)&Bs[k][tx*4]; \
      acc[0][0]+=a.x*b.x; acc[0][1]+=a.x*b.y; acc[0][2]+=a.x*b.z; acc[0][3]+=a.x*b.w; \
      acc[1][0]+=a.y*b.x; acc[1][1]+=a.y*b.y; acc[1][2]+=a.y*b.z; acc[1][3]+=a.y*b.w; \
      acc[2][0]+=a.z*b.x; acc[2][1]+=a.z*b.y; acc[2][2]+=a.z*b.z; acc[2][3]+=a.z*b.w; \
      acc[3][0]+=a.w*b.x; acc[3][1]+=a.w*b.y; acc[3][2]+=a.w*b.z; acc[3][3]+=a.w*b.w; \
    } \
    __syncthreads(); \
  }

// ---- pass A: row sums / sumsq of loss (fp64 accumulation) ----
__global__ __launch_bounds__(256) void k_gemmA(const float* __restrict__ W, const float* __restrict__ emb,
    const float* __restrict__ cvec, const float* __restrict__ qn, const int* __restrict__ tp,
    double* rowsum, double* rowsumsq){
  GEMM_MAIN(W, emb)
  float qv[4]; int jv[4];
  #pragma unroll
  for(int j=0;j<4;j++){ jv[j] = n0 + tx*4 + j; qv[j] = (jv[j] < N_ENT) ? qn[jv[j]] : 0.f; }
  #pragma unroll
  for(int i=0;i<4;i++){
    int mg = m0 + ty*4 + i;
    int pi = mg & (B_PAIR-1);
    int lp = tp[2*pi], rp = tp[2*pi+1];
    float cv = cvec[mg];
    double s=0.0, ss=0.0;
    #pragma unroll
    for(int j=0;j<4;j++){
      if(jv[j] < N_ENT){
        float mask = 1.0f - (jv[j]==lp ? 1.0f:0.0f) - (jv[j]==rp ? 1.0f:0.0f);
        float loss = (cv - qv[j] + 2.0f*acc[i][j]) * mask;
        s += (double)loss; ss += (double)loss*(double)loss;
      }
    }
    #pragma unroll
    for(int m=8;m>=1;m>>=1){ s += __shfl_xor(s,m,64); ss += __shfl_xor(ss,m,64); }
    if(tx==0){ unsafeAtomicAdd(&rowsum[mg], s); unsafeAtomicAdd(&rowsumsq[mg], ss); }
  }
}

// ---- stats: alpha = 20/sd, beta = 8 - 20 mu/sd ----
__global__ __launch_bounds__(256) void k_stats(const double* __restrict__ rowsum, const double* __restrict__ rowsumsq,
                        float* alpha, float* betav){
  int i = blockIdx.x*256 + threadIdx.x;
  if(i >= 2*B_PAIR) return;
  double mu = rowsum[i] / (double)N_ENT;
  double var = rowsumsq[i] / (double)N_ENT - mu*mu;
  double sd = sqrt(fmax(var, 0.0));
  double al = 20.0 / sd;
  alpha[i] = (float)al;
  betav[i] = (float)(8.0 - al*mu);
}

__device__ inline void lseMerge(float& mx, float& sm, float om, float os){
  if(om > mx){ sm = sm*expf(mx-om) + os; mx = om; }
  else if(om != -INFINITY){ sm += os*expf(om-mx); }
}

// ---- pass B: z = alpha*loss + beta, per-tile online logsumexp partials ----
__global__ __launch_bounds__(256) void k_gemmB(const float* __restrict__ W, const float* __restrict__ emb,
    const float* __restrict__ cvec, const float* __restrict__ qn, const int* __restrict__ tp,
    const float* __restrict__ alpha, const float* __restrict__ betav, float* pm, float* ps){
  GEMM_MAIN(W, emb)
  float qv[4]; int jv[4];
  #pragma unroll
  for(int j=0;j<4;j++){ jv[j] = n0 + tx*4 + j; qv[j] = (jv[j] < N_ENT) ? qn[jv[j]] : 0.f; }
  #pragma unroll
  for(int i=0;i<4;i++){
    int mg = m0 + ty*4 + i;
    int pi = mg & (B_PAIR-1);
    int lp = tp[2*pi], rp = tp[2*pi+1];
    float cv = cvec[mg], al = alpha[mg], be = betav[mg];
    float mx = -INFINITY, sm = 0.f;
    #pragma unroll
    for(int j=0;j<4;j++){
      if(jv[j] < N_ENT){
        float mask = 1.0f - (jv[j]==lp ? 1.0f:0.0f) - (jv[j]==rp ? 1.0f:0.0f);
        float loss = (cv - qv[j] + 2.0f*acc[i][j]) * mask;
        float z = al*loss + be;
        if(z > mx){ sm = sm*expf(mx-z) + 1.0f; mx = z; }
        else sm += expf(z-mx);
      }
    }
    #pragma unroll
    for(int m=8;m>=1;m>>=1){
      float om = __shfl_xor(mx,m,64), os = __shfl_xor(sm,m,64);
      lseMerge(mx, sm, om, os);
    }
    if(tx==0){ pm[(size_t)mg*NJT + blockIdx.x] = mx; ps[(size_t)mg*NJT + blockIdx.x] = sm; }
  }
}

// ---- combine per-tile LSE partials: wave per row ----
__global__ __launch_bounds__(256) void k_lse(const float* __restrict__ pm, const float* __restrict__ ps, float* lse){
  int row = (blockIdx.x*256 + threadIdx.x) >> 6;
  int lane = threadIdx.x & 63;
  if(row >= 2*B_PAIR) return;
  float mx = -INFINITY, sm = 0.f;
  for(int t=lane;t<NJT;t+=64) lseMerge(mx, sm, pm[(size_t)row*NJT+t], ps[(size_t)row*NJT+t]);
  #pragma unroll
  for(int m=32;m>=1;m>>=1){
    float om = __shfl_xor(mx,m,64), os = __shfl_xor(sm,m,64);
    lseMerge(mx, sm, om, os);
  }
  if(lane==0) lse[row] = mx + logf(sm);
}

// ---- final mean ----
__global__ __launch_bounds__(256) void k_final(const float* __restrict__ lse, float* out){
  __shared__ double sh[256];
  int tid = threadIdx.x;
  double s = 0.0;
  for(int i=tid;i<B_PAIR;i+=256) s += (double)lse[i] + (double)lse[B_PAIR+i];
  sh[tid]=s; __syncthreads();
  for(int w=128;w>0;w>>=1){ if(tid<w) sh[tid]+=sh[tid+w]; __syncthreads(); }
  if(tid==0) out[0] = (float)(sh[0] / (double)B_PAIR);
}

extern "C" void kernel_launch(void* const* d_in, const int* in_sizes, int n_in,
                              void* d_out, int out_size, void* d_ws, size_t ws_size,
                              hipStream_t stream) {
  const float* ent_emb = (const float*)d_in[0];
  const float* rel_emb = (const float*)d_in[1];
  const float* attn_e  = (const float*)d_in[2];   // (2,128,1)
  const float* attn_r  = (const float*)d_in[3];
  // d_in[4] = r_val (all ones): absorbed by normalization of tri_rel
  const int* adj     = (const int*)d_in[5];       // (2,T)
  const int* r_index = (const int*)d_in[6];       // (2,T); r_index[0]=arange(T)
  const int* ent_adj = (const int*)d_in[7];       // (2,NNZ)
  const int* rel_adj = (const int*)d_in[8];
  const int* tp      = (const int*)d_in[9];       // (B,2)
  float* out = (float*)d_out;

  const int* adj_row = adj;
  const int* adj_col = adj + T_EDGE;
  const int* rid1    = r_index + T_EDGE;

  char* base = (char*)d_ws;
  size_t off = 0;
  auto A = [&](size_t b)->void*{ void* p = base + off; off = (off + b + 255) & ~(size_t)255; return p; };
  // zero-region 1 (zeroed once per launch): accumulators
  float*  entF     = (float*) A((size_t)N_ENT*128*4);
  float*  relF     = (float*) A((size_t)N_ENT*128*4);
  float*  degE     = (float*) A((size_t)N_ENT*4);
  float*  degR     = (float*) A((size_t)N_ENT*4);
  double* rowsum   = (double*)A(2*B_PAIR*8);
  double* rowsumsq = (double*)A(2*B_PAIR*8);
  size_t zero1_end = off;
  // zero-region 2 (zeroed per GAT layer)
  float*    featB  = (float*)   A((size_t)N_ENT*128*4);
  size_t zero2_beg = (char*)featB - base;
  unsigned* segmax = (unsigned*)A((size_t)N_ENT*4);
  float*    segsum = (float*)   A((size_t)N_ENT*4);
  size_t zero2_end = off;
  // plain buffers (fully overwritten before use)
  float* featA   = (float*)A((size_t)N_ENT*128*4);
  float* emb     = (float*)A((size_t)N_ENT*EMBD*4);
  float* relnorm = (float*)A((size_t)R_REL*128*4);
  float* attdot  = (float*)A(4*R_REL*4);
  float* att_raw = (float*)A((size_t)T_EDGE*4);
  float* Wm      = (float*)A((size_t)2*B_PAIR*EMBD*4);
  float* cvec    = (float*)A(2*B_PAIR*4);
  float* qn      = (float*)A((size_t)N_ENT*4);
  float* alpha   = (float*)A(2*B_PAIR*4);
  float* betav   = (float*)A(2*B_PAIR*4);
  float* pm      = (float*)A((size_t)2*B_PAIR*NJT*4);
  float* ps      = (float*)A((size_t)2*B_PAIR*NJT*4);
  float* lse     = (float*)A(2*B_PAIR*4);
  (void)ws_size; (void)in_sizes; (void)n_in; (void)out_size;

  hipMemsetAsync(d_ws, 0, zero1_end, stream);

  // ---- _avg for entities and relations ----
  k_deg<<<(NNZ_E+255)/256, 256, 0, stream>>>(ent_adj, degE, NNZ_E);
  k_deg<<<(NNZ_E+255)/256, 256, 0, stream>>>(rel_adj, degR, NNZ_E);
  k_avg<<<NNZ_E/4, 256, 0, stream>>>(ent_adj, ent_adj+NNZ_E, degE, ent_emb, entF, NNZ_E);
  k_avg<<<NNZ_E/4, 256, 0, stream>>>(rel_adj, rel_adj+NNZ_E, degR, rel_emb, relF, NNZ_E);
  k_relnorm<<<R_REL/4, 256, 0, stream>>>(rel_emb, attn_e, attn_r, relnorm, attdot);

  // ---- two GAT stacks: call 0 = ent (attn_e, emb cols 0..383), call 1 = rel (attn_r, cols 384..767) ----
  for(int call=0; call<2; ++call){
    const float* src = call ? relF : entF;
    int koff = call ? 2 : 0;
    int coloff = call ? 384 : 0;
    k_tanh<<<N_ENT*128/256, 256, 0, stream>>>(src, featA, emb, coloff);
    for(int l=0;l<2;l++){
      hipMemsetAsync(base + zero2_beg, 0, zero2_end - zero2_beg, stream);
      k_attmax<<<(T_EDGE+255)/256, 256, 0, stream>>>(adj_row, rid1, attdot + (koff+l)*R_REL, att_raw, segmax);
      k_attexp<<<(T_EDGE+255)/256, 256, 0, stream>>>(adj_row, att_raw, segmax, segsum);
      k_edge<<<T_EDGE/4, 256, 0, stream>>>(adj_row, adj_col, rid1, relnorm, featA, att_raw, segsum, featB);
      k_tanh<<<N_ENT*128/256, 256, 0, stream>>>(featB, featA, emb, coloff + (l+1)*128);
    }
  }

  // ---- align loss ----
  k_gather<<<B_PAIR, 256, 0, stream>>>(emb, tp, Wm, cvec);
  k_qn<<<N_ENT/4, 256, 0, stream>>>(emb, qn);
  dim3 gg(NJT, 2*B_PAIR/64);
  k_gemmA<<<gg, 256, 0, stream>>>(Wm, emb, cvec, qn, tp, rowsum, rowsumsq);
  k_stats<<<2*B_PAIR/256, 256, 0, stream>>>(rowsum, rowsumsq, alpha, betav);
  k_gemmB<<<gg, 256, 0, stream>>>(Wm, emb, cvec, qn, tp, alpha, betav, pm, ps);
  k_lse<<<2*B_PAIR/(256/64), 256, 0, stream>>>(pm, ps, lse);
  k_final<<<1, 256, 0, stream>>>(lse, out);
}

// Round 2
// 2813.978 us; speedup vs baseline: 1.7814x; 1.7814x over previous
//
#include <hip/hip_runtime.h>
#include <math.h>

#define N_ENT 30000
#define R_REL 1000
#define T_EDGE 300000
#define B_PAIR 1024
#define NNZ_E 600000
#define GAMMAF 3.0f
#define EPSV 1e-12f
#define EMBD 768
#define NJT 469  // ceil(30000/64)

__device__ inline float waveRedSum(float v){
  #pragma unroll
  for(int m=32;m>=1;m>>=1) v += __shfl_xor(v, m, 64);
  return v;
}

__device__ inline float fast_tanh(float x){
  x = fminf(10.f, fmaxf(-10.f, x));
  float e = __expf(2.f*x);
  return (e-1.f)/(e+1.f);
}

// ---- edge-count: one thread per edge ----
__global__ __launch_bounds__(256) void k_count(const int* __restrict__ row, int* cnt, int nE){
  int e = blockIdx.x*256 + threadIdx.x;
  if(e < nE) atomicAdd(&cnt[row[e]], 1);
}

// ---- exclusive scan over N_ENT counts (single block) ----
__global__ __launch_bounds__(1024) void k_scan(const int* __restrict__ cnt, int* start, int* cursor){
  __shared__ int sh[1024];
  __shared__ int carry;
  int tid = threadIdx.x;
  if(tid==0) carry = 0;
  __syncthreads();
  for(int base=0; base<N_ENT; base+=1024){
    int i = base + tid;
    int v = (i<N_ENT)? cnt[i] : 0;
    sh[tid]=v; __syncthreads();
    for(int off=1; off<1024; off<<=1){
      int t = (tid>=off)? sh[tid-off] : 0;
      __syncthreads();
      sh[tid]+=t; __syncthreads();
    }
    int excl = sh[tid] - v + carry;
    if(i<N_ENT){ start[i]=excl; cursor[i]=excl; }
    __syncthreads();
    if(tid==1023) carry += sh[1023];
    __syncthreads();
  }
  if(tid==0) start[N_ENT] = carry;
}

// ---- scatter edges into CSR order ----
__global__ __launch_bounds__(256) void k_scatter(const int* __restrict__ row, const int* __restrict__ col,
                        const int* __restrict__ rid, int* cursor, int* scol, int* srid, int nE){
  int e = blockIdx.x*256 + threadIdx.x;
  if(e >= nE) return;
  int p = atomicAdd(&cursor[row[e]], 1);
  scol[p] = col[e];
  if(rid) srid[p] = rid[e];
}

// ---- _avg via CSR gather, fused tanh + emb slice write; wave per row ----
__global__ __launch_bounds__(256) void k_avg_tanh(const int* __restrict__ start, const int* __restrict__ scol,
                        const float* __restrict__ src, float* featOut, float* emb, int coloff){
  int r = blockIdx.x*4 + (threadIdx.x>>6);
  int lane = threadIdx.x & 63;
  int s0 = start[r], s1 = start[r+1];
  float2 acc = make_float2(0.f,0.f);
  for(int e=s0;e<s1;e++){
    int c = scol[e];
    float2 v = *(const float2*)(src + (size_t)c*128 + lane*2);
    acc.x += v.x; acc.y += v.y;
  }
  float inv = (s1>s0) ? 1.0f/(float)(s1-s0) : 0.f;
  float vx = fast_tanh(acc.x*inv), vy = fast_tanh(acc.y*inv);
  *(float2*)(featOut + (size_t)r*128 + lane*2) = make_float2(vx,vy);
  float* ep = emb + (size_t)r*EMBD + coloff + lane*2;
  ep[0]=vx; ep[1]=vy;
}

// ---- normalized relation table + attention dots ----
__global__ __launch_bounds__(256) void k_relnorm(const float* __restrict__ rel, const float* __restrict__ ae,
                          const float* __restrict__ ar, float* relnorm, float* attdot){
  int r = (blockIdx.x*256 + threadIdx.x) >> 6;
  int lane = threadIdx.x & 63;
  if (r >= R_REL) return;
  float2 v = *(const float2*)(rel + (size_t)r*128 + lane*2);
  float ss = waveRedSum(v.x*v.x + v.y*v.y);
  float nrm = fmaxf(sqrtf(ss), EPSV);
  float2 u; u.x = v.x/nrm; u.y = v.y/nrm;
  *(float2*)(relnorm + (size_t)r*128 + lane*2) = u;
  const float* ks[4] = {ae, ae+128, ar, ar+128};
  #pragma unroll
  for(int k=0;k<4;k++){
    float2 w = *(const float2*)(ks[k] + lane*2);
    float d = waveRedSum(u.x*w.x + u.y*w.y);
    if(lane==0) attdot[k*R_REL + r] = d;
  }
}

// ---- GAT layer via CSR gather: softmax + Householder reflect, fused tanh + emb write ----
__global__ __launch_bounds__(256) void k_edge_csr(const int* __restrict__ start, const int* __restrict__ scol,
                        const int* __restrict__ srid, const float* __restrict__ relnorm,
                        const float* __restrict__ attdot_k, const float* __restrict__ featIn,
                        float* featOut, float* emb, int coloff){
  int r = blockIdx.x*4 + (threadIdx.x>>6);
  int lane = threadIdx.x & 63;
  int s0 = start[r], s1 = start[r+1];
  float mx = -INFINITY;
  for(int e=s0;e<s1;e++) mx = fmaxf(mx, attdot_k[srid[e]]);
  float2 acc = make_float2(0.f,0.f);
  float sumw = 0.f;
  for(int e=s0;e<s1;e++){
    int c = scol[e], q = srid[e];
    float w = __expf(attdot_k[q] - mx);
    sumw += w;
    float2 u = *(const float2*)(relnorm + (size_t)q*128 + lane*2);
    float2 h = *(const float2*)(featIn  + (size_t)c*128 + lane*2);
    float dot = waveRedSum(h.x*u.x + h.y*u.y);
    float t2 = 2.0f*dot*w;
    acc.x += w*h.x - t2*u.x;
    acc.y += w*h.y - t2*u.y;
  }
  float inv = (s1>s0) ? 1.0f/sumw : 0.f;
  float vx = fast_tanh(acc.x*inv), vy = fast_tanh(acc.y*inv);
  *(float2*)(featOut + (size_t)r*128 + lane*2) = make_float2(vx,vy);
  float* ep = emb + (size_t)r*EMBD + coloff + lane*2;
  ep[0]=vx; ep[1]=vy;
}

// ---- gather pair rows, pos, c_i = pos + gamma - ||a||^2 ----
__global__ __launch_bounds__(256) void k_gather(const float* __restrict__ emb, const int* __restrict__ tp,
                         float* W, float* cvec){
  int i = blockIdx.x; int tid = threadIdx.x;
  int l = tp[2*i], r = tp[2*i+1];
  float sl=0.f, sr=0.f, sp=0.f;
  for(int c=tid;c<EMBD;c+=256){
    float le = emb[(size_t)l*EMBD+c], re = emb[(size_t)r*EMBD+c];
    W[(size_t)i*EMBD+c]=le; W[(size_t)(B_PAIR+i)*EMBD+c]=re;
    sl += le*le; sr += re*re; float d = le-re; sp += d*d;
  }
  __shared__ float s0[256], s1[256], s2[256];
  s0[tid]=sl; s1[tid]=sr; s2[tid]=sp;
  __syncthreads();
  for(int w=128;w>0;w>>=1){
    if(tid<w){ s0[tid]+=s0[tid+w]; s1[tid]+=s1[tid+w]; s2[tid]+=s2[tid+w]; }
    __syncthreads();
  }
  if(tid==0){
    float pos = s2[0];
    cvec[i]        = pos + GAMMAF - s0[0];
    cvec[B_PAIR+i] = pos + GAMMAF - s1[0];
  }
}

// ---- q_j = ||emb_j||^2, wave per node ----
__global__ __launch_bounds__(256) void k_qn(const float* __restrict__ emb, float* qn){
  int j = (blockIdx.x*256 + threadIdx.x) >> 6;
  int lane = threadIdx.x & 63;
  if(j >= N_ENT) return;
  float s=0.f;
  #pragma unroll
  for(int q=0;q<12;q++){ float v = emb[(size_t)j*EMBD + lane + 64*q]; s += v*v; }
  s = waveRedSum(s);
  if(lane==0) qn[j]=s;
}

// ---- S = sum_j b_j, P = sum_j q_j b_j, Q = sum q, Q2 = sum q^2 ----
__global__ __launch_bounds__(256) void k_embstats(const float* __restrict__ emb, const float* __restrict__ qn,
                           float* Svec, float* Pvec, float* QQ){
  int tid = threadIdx.x;
  int n0 = blockIdx.x*128;
  int nend = n0+128; if(nend > N_ENT) nend = N_ENT;
  float s[3]={0,0,0}, p[3]={0,0,0};
  float q1=0.f, q2=0.f;
  for(int n=n0;n<nend;n++){
    float qv = qn[n];
    if(tid==0){ q1 += qv; q2 += qv*qv; }
    #pragma unroll
    for(int k=0;k<3;k++){
      float v = emb[(size_t)n*EMBD + tid + k*256];
      s[k] += v; p[k] += qv*v;
    }
  }
  #pragma unroll
  for(int k=0;k<3;k++){
    unsafeAtomicAdd(&Svec[tid + k*256], s[k]);
    unsafeAtomicAdd(&Pvec[tid + k*256], p[k]);
  }
  if(tid==0){ unsafeAtomicAdd(&QQ[0], q1); unsafeAtomicAdd(&QQ[1], q2); }
}

// ---- G = E^T E (768x768), split-K with fp32 atomics ----
#define KSPLIT 8
__global__ __launch_bounds__(256) void k_syrk(const float* __restrict__ emb, float* G){
  __shared__ float As[16][68];
  __shared__ float Bs[16][68];
  int tid = threadIdx.x;
  int tx = tid & 15, ty = tid >> 4;
  int m0 = blockIdx.y*64, n0 = blockIdx.x*64;
  int kchunk = (N_ENT + KSPLIT - 1)/KSPLIT;
  int kbeg = blockIdx.z*kchunk, kend = kbeg + kchunk;
  if(kend > N_ENT) kend = N_ENT;
  int lr = tid >> 4, lc = (tid & 15)*4;
  float acc[4][4] = {};
  for(int k0=kbeg;k0<kend;k0+=16){
    int kk = k0 + lr;
    float4 av, bv;
    if(kk < kend){
      av = *(const float4*)(emb + (size_t)kk*EMBD + m0 + lc);
      bv = *(const float4*)(emb + (size_t)kk*EMBD + n0 + lc);
    } else { av = make_float4(0,0,0,0); bv = av; }
    *(float4*)&As[lr][lc] = av;
    *(float4*)&Bs[lr][lc] = bv;
    __syncthreads();
    #pragma unroll
    for(int k=0;k<16;k++){
      float4 a = *(const float4*)&As[k][ty*4];
      float4 b = *(const float4*)&Bs[k][tx*4];
      acc[0][0]+=a.x*b.x; acc[0][1]+=a.x*b.y; acc[0][2]+=a.x*b.z; acc[0][3]+=a.x*b.w;
      acc[1][0]+=a.y*b.x; acc[1][1]+=a.y*b.y; acc[1][2]+=a.y*b.z; acc[1][3]+=a.y*b.w;
      acc[2][0]+=a.z*b.x; acc[2][1]+=a.z*b.y; acc[2][2]+=a.z*b.z; acc[2][3]+=a.z*b.w;
      acc[3][0]+=a.w*b.x; acc[3][1]+=a.w*b.y; acc[3][2]+=a.w*b.z; acc[3][3]+=a.w*b.w;
    }
    __syncthreads();
  }
  #pragma unroll
  for(int i=0;i<4;i++)
    #pragma unroll
    for(int j=0;j<4;j++)
      unsafeAtomicAdd(&G[(size_t)(m0+ty*4+i)*EMBD + n0+tx*4+j], acc[i][j]);
}

// ================== shared GEMM mainloop (64x64x16 fp32 tile, NT) ==================
#define GEMM_MAIN(W_, EMB_, NB_) \
  __shared__ float As[16][68]; \
  __shared__ float Bs[16][68]; \
  int tid = threadIdx.x; \
  int tx = tid & 15, ty = tid >> 4; \
  int m0 = blockIdx.y*64, n0 = blockIdx.x*64; \
  int lm = tid >> 2, lk = (tid & 3) * 4; \
  float acc[4][4] = {}; \
  const float* aPtr = W_ + (size_t)(m0+lm)*EMBD + lk; \
  int gn = n0 + lm; \
  const float* bPtr = EMB_ + (size_t)gn*EMBD + lk; \
  bool bok = gn < (NB_); \
  for(int k0=0;k0<EMBD;k0+=16){ \
    float4 av = *(const float4*)(aPtr + k0); \
    float4 bv = bok ? *(const float4*)(bPtr + k0) : make_float4(0.f,0.f,0.f,0.f); \
    As[lk+0][lm]=av.x; As[lk+1][lm]=av.y; As[lk+2][lm]=av.z; As[lk+3][lm]=av.w; \
    Bs[lk+0][lm]=bv.x; Bs[lk+1][lm]=bv.y; Bs[lk+2][lm]=bv.z; Bs[lk+3][lm]=bv.w; \
    __syncthreads(); \
    _Pragma("unroll") \
    for(int k=0;k<16;k++){ \
      float4 a = *(const float4*)&As[k][ty*4]; \
      float4 b = *(const float4*)&Bs[k][tx*4]; \
      acc[0][0]+=a.x*b.x; acc[0][1]+=a.x*b.y; acc[0][2]+=a.x*b.z; acc[0][3]+=a.x*b.w; \
      acc[1][0]+=a.y*b.x; acc[1][1]+=a.y*b.y; acc[1][2]+=a.y*b.z; acc[1][3]+=a.y*b.w; \
      acc[2][0]+=a.z*b.x; acc[2][1]+=a.z*b.y; acc[2][2]+=a.z*b.z; acc[2][3]+=a.z*b.w; \
      acc[3][0]+=a.w*b.x; acc[3][1]+=a.w*b.y; acc[3][2]+=a.w*b.z; acc[3][3]+=a.w*b.w; \
    } \
    __syncthreads(); \
  }

// ---- T = W * G (G symmetric => NT layout valid) ----
__global__ __launch_bounds__(256) void k_gemmT(const float* __restrict__ W, const float* __restrict__ G, float* Tm){
  GEMM_MAIN(W, G, EMBD)
  #pragma unroll
  for(int i=0;i<4;i++){
    int mg = m0 + ty*4 + i;
    #pragma unroll
    for(int j=0;j<4;j++){
      int jv = n0 + tx*4 + j;
      Tm[(size_t)mg*EMBD + jv] = acc[i][j];
    }
  }
}

// ---- per-row closed-form stats: alpha = 20/sd, beta = 8 - 20 mu/sd ----
__global__ __launch_bounds__(256) void k_rowstats(const float* __restrict__ W, const float* __restrict__ Tm,
      const float* __restrict__ emb, const float* __restrict__ qn, const float* __restrict__ cvec,
      const int* __restrict__ tp, const float* __restrict__ Svec, const float* __restrict__ Pvec,
      const float* __restrict__ QQ, float* alpha, float* betav){
  int row = blockIdx.x*4 + (threadIdx.x>>6);
  int lane = threadIdx.x & 63;
  if(row >= 2*B_PAIR) return;
  int pi = row & (B_PAIR-1);
  int lp = tp[2*pi], rp = tp[2*pi+1];
  float d1=0,d2=0,d3=0,dl=0,dr=0;
  #pragma unroll
  for(int k=0;k<12;k++){
    int d = lane + 64*k;
    float a = W[(size_t)row*EMBD + d];
    d1 += a*Svec[d];
    d2 += a*Pvec[d];
    d3 += a*Tm[(size_t)row*EMBD + d];
    dl += a*emb[(size_t)lp*EMBD + d];
    dr += a*emb[(size_t)rp*EMBD + d];
  }
  d1=waveRedSum(d1); d2=waveRedSum(d2); d3=waveRedSum(d3);
  dl=waveRedSum(dl); dr=waveRedSum(dr);
  if(lane==0){
    double c = (double)cvec[row], Q = (double)QQ[0], Q2 = (double)QQ[1], Nn = (double)N_ENT;
    double su  = Nn*c - Q + 2.0*(double)d1;
    double su2 = Nn*c*c - 2.0*c*Q + Q2 + 4.0*(c*(double)d1 - (double)d2) + 4.0*(double)d3;
    double ul = c - (double)qn[lp] + 2.0*(double)dl;
    double ur = c - (double)qn[rp] + 2.0*(double)dr;
    su -= ul + ur;
    if(lp != rp) su2 -= ul*ul + ur*ur;
    double mu = su/Nn;
    double var = su2/Nn - mu*mu;
    double sd = sqrt(fmax(var, 0.0));
    double al = 20.0/sd;
    alpha[row] = (float)al;
    betav[row] = (float)(8.0 - al*mu);
  }
}

__device__ inline void lseMerge(float& mx, float& sm, float om, float os){
  if(om > mx){ sm = sm*expf(mx-om) + os; mx = om; }
  else if(om != -INFINITY){ sm += os*expf(om-mx); }
}

// ---- pass B: z = alpha*loss + beta, per-tile online logsumexp partials ----
__global__ __launch_bounds__(256) void k_gemmB(const float* __restrict__ W, const float* __restrict__ emb,
    const float* __restrict__ cvec, const float* __restrict__ qn, const int* __restrict__ tp,
    const float* __restrict__ alpha, const float* __restrict__ betav, float* pm, float* ps){
  GEMM_MAIN(W, emb, N_ENT)
  float qv[4]; int jv[4];
  #pragma unroll
  for(int j=0;j<4;j++){ jv[j] = n0 + tx*4 + j; qv[j] = (jv[j] < N_ENT) ? qn[jv[j]] : 0.f; }
  #pragma unroll
  for(int i=0;i<4;i++){
    int mg = m0 + ty*4 + i;
    int pi = mg & (B_PAIR-1);
    int lp = tp[2*pi], rp = tp[2*pi+1];
    float cv = cvec[mg], al = alpha[mg], be = betav[mg];
    float mx = -INFINITY, sm = 0.f;
    #pragma unroll
    for(int j=0;j<4;j++){
      if(jv[j] < N_ENT){
        float mask = 1.0f - (jv[j]==lp ? 1.0f:0.0f) - (jv[j]==rp ? 1.0f:0.0f);
        float loss = (cv - qv[j] + 2.0f*acc[i][j]) * mask;
        float z = al*loss + be;
        if(z > mx){ sm = sm*__expf(mx-z) + 1.0f; mx = z; }
        else sm += __expf(z-mx);
      }
    }
    #pragma unroll
    for(int m=8;m>=1;m>>=1){
      float om = __shfl_xor(mx,m,64), os = __shfl_xor(sm,m,64);
      lseMerge(mx, sm, om, os);
    }
    if(tx==0){ pm[(size_t)mg*NJT + blockIdx.x] = mx; ps[(size_t)mg*NJT + blockIdx.x] = sm; }
  }
}

// ---- combine per-tile LSE partials: block per row ----
__global__ __launch_bounds__(256) void k_lse(const float* __restrict__ pm, const float* __restrict__ ps, float* lse){
  __shared__ float shm[256], shs[256];
  int row = blockIdx.x, tid = threadIdx.x;
  float mx = -INFINITY, sm = 0.f;
  for(int t=tid;t<NJT;t+=256) lseMerge(mx, sm, pm[(size_t)row*NJT+t], ps[(size_t)row*NJT+t]);
  shm[tid]=mx; shs[tid]=sm;
  __syncthreads();
  for(int w=128;w>0;w>>=1){
    if(tid<w){
      float m2=shm[tid], s2=shs[tid];
      lseMerge(m2, s2, shm[tid+w], shs[tid+w]);
      shm[tid]=m2; shs[tid]=s2;
    }
    __syncthreads();
  }
  if(tid==0) lse[row] = shm[0] + logf(shs[0]);
}

// ---- final mean ----
__global__ __launch_bounds__(256) void k_final(const float* __restrict__ lse, float* out){
  __shared__ double sh[256];
  int tid = threadIdx.x;
  double s = 0.0;
  for(int i=tid;i<B_PAIR;i+=256) s += (double)lse[i] + (double)lse[B_PAIR+i];
  sh[tid]=s; __syncthreads();
  for(int w=128;w>0;w>>=1){ if(tid<w) sh[tid]+=sh[tid+w]; __syncthreads(); }
  if(tid==0) out[0] = (float)(sh[0] / (double)B_PAIR);
}

extern "C" void kernel_launch(void* const* d_in, const int* in_sizes, int n_in,
                              void* d_out, int out_size, void* d_ws, size_t ws_size,
                              hipStream_t stream) {
  const float* ent_emb = (const float*)d_in[0];
  const float* rel_emb = (const float*)d_in[1];
  const float* attn_e  = (const float*)d_in[2];
  const float* attn_r  = (const float*)d_in[3];
  const int* adj     = (const int*)d_in[5];
  const int* r_index = (const int*)d_in[6];
  const int* ent_adj = (const int*)d_in[7];
  const int* rel_adj = (const int*)d_in[8];
  const int* tp      = (const int*)d_in[9];
  float* out = (float*)d_out;

  const int* adj_row = adj;
  const int* adj_col = adj + T_EDGE;
  const int* rid1    = r_index + T_EDGE;

  char* base = (char*)d_ws;
  size_t off = 0;
  auto A = [&](size_t b)->void*{ void* p = base + off; off = (off + b + 255) & ~(size_t)255; return p; };
  // zero region (one memset): counts + G + emb-stat accumulators
  int*   cntA  = (int*)  A((size_t)N_ENT*4);
  int*   cntE  = (int*)  A((size_t)N_ENT*4);
  int*   cntR  = (int*)  A((size_t)N_ENT*4);
  float* G     = (float*)A((size_t)EMBD*EMBD*4);
  float* Svec  = (float*)A(EMBD*4);
  float* Pvec  = (float*)A(EMBD*4);
  float* QQ    = (float*)A(2*4);
  size_t zero_end = off;
  // plain buffers
  int* startA = (int*)A((size_t)(N_ENT+1)*4);
  int* startE = (int*)A((size_t)(N_ENT+1)*4);
  int* startR = (int*)A((size_t)(N_ENT+1)*4);
  int* curA   = (int*)A((size_t)N_ENT*4);
  int* curE   = (int*)A((size_t)N_ENT*4);
  int* curR   = (int*)A((size_t)N_ENT*4);
  int* scolA  = (int*)A((size_t)T_EDGE*4);
  int* sridA  = (int*)A((size_t)T_EDGE*4);
  int* scolE  = (int*)A((size_t)NNZ_E*4);
  int* scolR  = (int*)A((size_t)NNZ_E*4);
  float* featA   = (float*)A((size_t)N_ENT*128*4);
  float* featB   = (float*)A((size_t)N_ENT*128*4);
  float* emb     = (float*)A((size_t)N_ENT*EMBD*4);
  float* relnorm = (float*)A((size_t)R_REL*128*4);
  float* attdot  = (float*)A(4*R_REL*4);
  float* Wm      = (float*)A((size_t)2*B_PAIR*EMBD*4);
  float* Tm      = (float*)A((size_t)2*B_PAIR*EMBD*4);
  float* cvec    = (float*)A(2*B_PAIR*4);
  float* qn      = (float*)A((size_t)N_ENT*4);
  float* alpha   = (float*)A(2*B_PAIR*4);
  float* betav   = (float*)A(2*B_PAIR*4);
  float* pm      = (float*)A((size_t)2*B_PAIR*NJT*4);
  float* ps      = (float*)A((size_t)2*B_PAIR*NJT*4);
  float* lse     = (float*)A(2*B_PAIR*4);
  (void)ws_size; (void)in_sizes; (void)n_in; (void)out_size;

  hipMemsetAsync(d_ws, 0, zero_end, stream);

  // ---- CSR counting sorts (adj once; ent_adj; rel_adj) ----
  k_count<<<(T_EDGE+255)/256, 256, 0, stream>>>(adj_row, cntA, T_EDGE);
  k_count<<<(NNZ_E+255)/256, 256, 0, stream>>>(ent_adj, cntE, NNZ_E);
  k_count<<<(NNZ_E+255)/256, 256, 0, stream>>>(rel_adj, cntR, NNZ_E);
  k_scan<<<1, 1024, 0, stream>>>(cntA, startA, curA);
  k_scan<<<1, 1024, 0, stream>>>(cntE, startE, curE);
  k_scan<<<1, 1024, 0, stream>>>(cntR, startR, curR);
  k_scatter<<<(T_EDGE+255)/256, 256, 0, stream>>>(adj_row, adj_col, rid1, curA, scolA, sridA, T_EDGE);
  k_scatter<<<(NNZ_E+255)/256, 256, 0, stream>>>(ent_adj, ent_adj+NNZ_E, nullptr, curE, scolE, nullptr, NNZ_E);
  k_scatter<<<(NNZ_E+255)/256, 256, 0, stream>>>(rel_adj, rel_adj+NNZ_E, nullptr, curR, scolR, nullptr, NNZ_E);

  k_relnorm<<<R_REL/4, 256, 0, stream>>>(rel_emb, attn_e, attn_r, relnorm, attdot);

  // ---- two GAT stacks ----
  for(int call=0; call<2; ++call){
    const float* src  = call ? rel_emb : ent_emb;
    const int* startS = call ? startR : startE;
    const int* scolS  = call ? scolR : scolE;
    int koff = call ? 2 : 0;
    int coloff = call ? 384 : 0;
    k_avg_tanh<<<N_ENT/4, 256, 0, stream>>>(startS, scolS, src, featA, emb, coloff);
    k_edge_csr<<<N_ENT/4, 256, 0, stream>>>(startA, scolA, sridA, relnorm, attdot + (koff+0)*R_REL,
                                            featA, featB, emb, coloff + 128);
    k_edge_csr<<<N_ENT/4, 256, 0, stream>>>(startA, scolA, sridA, relnorm, attdot + (koff+1)*R_REL,
                                            featB, featA, emb, coloff + 256);
  }

  // ---- align loss ----
  k_gather<<<B_PAIR, 256, 0, stream>>>(emb, tp, Wm, cvec);
  k_qn<<<N_ENT/4, 256, 0, stream>>>(emb, qn);
  k_embstats<<<(N_ENT+127)/128, 256, 0, stream>>>(emb, qn, Svec, Pvec, QQ);
  dim3 gsyrk(EMBD/64, EMBD/64, KSPLIT);
  k_syrk<<<gsyrk, 256, 0, stream>>>(emb, G);
  dim3 gT(EMBD/64, 2*B_PAIR/64);
  k_gemmT<<<gT, 256, 0, stream>>>(Wm, G, Tm);
  k_rowstats<<<2*B_PAIR/4, 256, 0, stream>>>(Wm, Tm, emb, qn, cvec, tp, Svec, Pvec, QQ, alpha, betav);
  dim3 gg(NJT, 2*B_PAIR/64);
  k_gemmB<<<gg, 256, 0, stream>>>(Wm, emb, cvec, qn, tp, alpha, betav, pm, ps);
  k_lse<<<2*B_PAIR, 256, 0, stream>>>(pm, ps, lse);
  k_final<<<1, 256, 0, stream>>>(lse, out);
}

// Round 3
// 1210.739 us; speedup vs baseline: 4.1403x; 2.3242x over previous
//
#include <hip/hip_runtime.h>
#include <math.h>

#define N_ENT 30000
#define R_REL 1000
#define T_EDGE 300000
#define B_PAIR 1024
#define NNZ_E 600000
#define GAMMAF 3.0f
#define EPSV 1e-12f
#define EMBD 768
#define NPAD 30016           // N_ENT padded to 64 for syrk K-loop
#define GB_NT 469            // ceil(30000/64) n-tiles for gemmB / lse partials

typedef _Float16 half8 __attribute__((ext_vector_type(8)));
typedef _Float16 half2v __attribute__((ext_vector_type(2)));
typedef float f32x4 __attribute__((ext_vector_type(4)));

__device__ inline float waveRedSum(float v){
  #pragma unroll
  for(int m=32;m>=1;m>>=1) v += __shfl_xor(v, m, 64);
  return v;
}

__device__ inline float fast_tanh(float x){
  x = fminf(10.f, fmaxf(-10.f, x));
  float e = __expf(2.f*x);
  return (e-1.f)/(e+1.f);
}

// ---- edge-count ----
__global__ __launch_bounds__(256) void k_count(const int* __restrict__ row, int* cnt, int nE){
  int e = blockIdx.x*256 + threadIdx.x;
  if(e < nE) atomicAdd(&cnt[row[e]], 1);
}

// ---- 3 exclusive scans in one launch (block per list) ----
__global__ __launch_bounds__(1024) void k_scan3(const int* c0, int* s0, int* u0,
                                                const int* c1, int* s1, int* u1,
                                                const int* c2, int* s2, int* u2){
  const int* cnt = blockIdx.x==0 ? c0 : (blockIdx.x==1 ? c1 : c2);
  int* start     = blockIdx.x==0 ? s0 : (blockIdx.x==1 ? s1 : s2);
  int* cursor    = blockIdx.x==0 ? u0 : (blockIdx.x==1 ? u1 : u2);
  __shared__ int sh[1024];
  __shared__ int carry;
  int tid = threadIdx.x;
  if(tid==0) carry = 0;
  __syncthreads();
  for(int base=0; base<N_ENT; base+=1024){
    int i = base + tid;
    int v = (i<N_ENT)? cnt[i] : 0;
    sh[tid]=v; __syncthreads();
    for(int off=1; off<1024; off<<=1){
      int t = (tid>=off)? sh[tid-off] : 0;
      __syncthreads();
      sh[tid]+=t; __syncthreads();
    }
    int excl = sh[tid] - v + carry;
    if(i<N_ENT){ start[i]=excl; cursor[i]=excl; }
    __syncthreads();
    if(tid==1023) carry += sh[1023];
    __syncthreads();
  }
  if(tid==0) start[N_ENT] = carry;
}

// ---- scatter edges into CSR order ----
__global__ __launch_bounds__(256) void k_scatter(const int* __restrict__ row, const int* __restrict__ col,
                        const int* __restrict__ rid, int* cursor, int* scol, int* srid, int nE){
  int e = blockIdx.x*256 + threadIdx.x;
  if(e >= nE) return;
  int p = atomicAdd(&cursor[row[e]], 1);
  scol[p] = col[e];
  if(rid) srid[p] = rid[e];
}

// ---- _avg via CSR gather, fused tanh + fp16 emb slice write; wave per row ----
__global__ __launch_bounds__(256) void k_avg_tanh(const int* __restrict__ start, const int* __restrict__ scol,
                        const float* __restrict__ src, float* featOut, _Float16* Eh, int coloff){
  int r = blockIdx.x*4 + (threadIdx.x>>6);
  int lane = threadIdx.x & 63;
  int s0 = start[r], s1 = start[r+1];
  float2 acc = make_float2(0.f,0.f);
  for(int e=s0;e<s1;e++){
    int c = scol[e];
    float2 v = *(const float2*)(src + (size_t)c*128 + lane*2);
    acc.x += v.x; acc.y += v.y;
  }
  float inv = (s1>s0) ? 1.0f/(float)(s1-s0) : 0.f;
  float vx = fast_tanh(acc.x*inv), vy = fast_tanh(acc.y*inv);
  *(float2*)(featOut + (size_t)r*128 + lane*2) = make_float2(vx,vy);
  half2v hv = {(_Float16)vx, (_Float16)vy};
  *(half2v*)(Eh + (size_t)r*EMBD + coloff + lane*2) = hv;
}

// ---- normalized relation table + attention dots ----
__global__ __launch_bounds__(256) void k_relnorm(const float* __restrict__ rel, const float* __restrict__ ae,
                          const float* __restrict__ ar, float* relnorm, float* attdot){
  int r = (blockIdx.x*256 + threadIdx.x) >> 6;
  int lane = threadIdx.x & 63;
  if (r >= R_REL) return;
  float2 v = *(const float2*)(rel + (size_t)r*128 + lane*2);
  float ss = waveRedSum(v.x*v.x + v.y*v.y);
  float nrm = fmaxf(sqrtf(ss), EPSV);
  float2 u; u.x = v.x/nrm; u.y = v.y/nrm;
  *(float2*)(relnorm + (size_t)r*128 + lane*2) = u;
  const float* ks[4] = {ae, ae+128, ar, ar+128};
  #pragma unroll
  for(int k=0;k<4;k++){
    float2 w = *(const float2*)(ks[k] + lane*2);
    float d = waveRedSum(u.x*w.x + u.y*w.y);
    if(lane==0) attdot[k*R_REL + r] = d;
  }
}

// ---- GAT layer via CSR gather, fused tanh + fp16 emb write ----
__global__ __launch_bounds__(256) void k_edge_csr(const int* __restrict__ start, const int* __restrict__ scol,
                        const int* __restrict__ srid, const float* __restrict__ relnorm,
                        const float* __restrict__ attdot_k, const float* __restrict__ featIn,
                        float* featOut, _Float16* Eh, int coloff){
  int r = blockIdx.x*4 + (threadIdx.x>>6);
  int lane = threadIdx.x & 63;
  int s0 = start[r], s1 = start[r+1];
  float mx = -INFINITY;
  for(int e=s0;e<s1;e++) mx = fmaxf(mx, attdot_k[srid[e]]);
  float2 acc = make_float2(0.f,0.f);
  float sumw = 0.f;
  for(int e=s0;e<s1;e++){
    int c = scol[e], q = srid[e];
    float w = __expf(attdot_k[q] - mx);
    sumw += w;
    float2 u = *(const float2*)(relnorm + (size_t)q*128 + lane*2);
    float2 h = *(const float2*)(featIn  + (size_t)c*128 + lane*2);
    float dot = waveRedSum(h.x*u.x + h.y*u.y);
    float t2 = 2.0f*dot*w;
    acc.x += w*h.x - t2*u.x;
    acc.y += w*h.y - t2*u.y;
  }
  float inv = (s1>s0) ? 1.0f/sumw : 0.f;
  float vx = fast_tanh(acc.x*inv), vy = fast_tanh(acc.y*inv);
  *(float2*)(featOut + (size_t)r*128 + lane*2) = make_float2(vx,vy);
  half2v hv = {(_Float16)vx, (_Float16)vy};
  *(half2v*)(Eh + (size_t)r*EMBD + coloff + lane*2) = hv;
}

// ---- gather pair rows from Eh -> Wm fp32, Wh fp16, cvec ----
__global__ __launch_bounds__(256) void k_gather(const _Float16* __restrict__ Eh, const int* __restrict__ tp,
                         float* W, _Float16* Wh, float* cvec){
  int i = blockIdx.x; int tid = threadIdx.x;
  int l = tp[2*i], r = tp[2*i+1];
  float sl=0.f, sr=0.f, sp=0.f;
  for(int c=tid;c<EMBD;c+=256){
    _Float16 lh = Eh[(size_t)l*EMBD+c], rh = Eh[(size_t)r*EMBD+c];
    float le = (float)lh, re = (float)rh;
    W[(size_t)i*EMBD+c]=le; W[(size_t)(B_PAIR+i)*EMBD+c]=re;
    Wh[(size_t)i*EMBD+c]=lh; Wh[(size_t)(B_PAIR+i)*EMBD+c]=rh;
    sl += le*le; sr += re*re; float d = le-re; sp += d*d;
  }
  __shared__ float s0[256], s1[256], s2[256];
  s0[tid]=sl; s1[tid]=sr; s2[tid]=sp;
  __syncthreads();
  for(int w=128;w>0;w>>=1){
    if(tid<w){ s0[tid]+=s0[tid+w]; s1[tid]+=s1[tid+w]; s2[tid]+=s2[tid+w]; }
    __syncthreads();
  }
  if(tid==0){
    float pos = s2[0];
    cvec[i]        = pos + GAMMAF - s0[0];
    cvec[B_PAIR+i] = pos + GAMMAF - s1[0];
  }
}

// ---- q_j = ||e_j||^2 from Eh, wave per node ----
__global__ __launch_bounds__(256) void k_qn(const _Float16* __restrict__ Eh, float* qn){
  int j = (blockIdx.x*256 + threadIdx.x) >> 6;
  int lane = threadIdx.x & 63;
  if(j >= N_ENT) return;
  float s=0.f;
  #pragma unroll
  for(int q=0;q<12;q++){ float v = (float)Eh[(size_t)j*EMBD + lane + 64*q]; s += v*v; }
  s = waveRedSum(s);
  if(lane==0) qn[j]=s;
}

// ---- S = sum_j e_j, P = sum_j q_j e_j, Q = sum q, Q2 = sum q^2 ----
__global__ __launch_bounds__(256) void k_embstats(const _Float16* __restrict__ Eh, const float* __restrict__ qn,
                           float* Svec, float* Pvec, float* QQ){
  int tid = threadIdx.x;
  int n0 = blockIdx.x*128;
  int nend = n0+128; if(nend > N_ENT) nend = N_ENT;
  float s[3]={0,0,0}, p[3]={0,0,0};
  float q1=0.f, q2=0.f;
  for(int n=n0;n<nend;n++){
    float qv = qn[n];
    if(tid==0){ q1 += qv; q2 += qv*qv; }
    #pragma unroll
    for(int k=0;k<3;k++){
      float v = (float)Eh[(size_t)n*EMBD + tid + k*256];
      s[k] += v; p[k] += qv*v;
    }
  }
  #pragma unroll
  for(int k=0;k<3;k++){
    unsafeAtomicAdd(&Svec[tid + k*256], s[k]);
    unsafeAtomicAdd(&Pvec[tid + k*256], p[k]);
  }
  if(tid==0){ unsafeAtomicAdd(&QQ[0], q1); unsafeAtomicAdd(&QQ[1], q2); }
}

// ---- transpose Eh (30000x768) -> embT (768 x NPAD), zero-padded ----
__global__ __launch_bounds__(256) void k_transp(const _Float16* __restrict__ Eh, _Float16* embT){
  __shared__ __align__(16) _Float16 til[64][72];
  int r0 = blockIdx.x*64, c0 = blockIdx.y*64;
  int t = threadIdx.x;
  int rr = t>>3, c8 = (t&7)*8;
  #pragma unroll
  for(int p=0;p<2;p++){
    int gr = r0 + rr + p*32;
    uint4 v = make_uint4(0u,0u,0u,0u);
    if(gr < N_ENT) v = *(const uint4*)(Eh + (size_t)gr*EMBD + c0 + c8);
    *(uint4*)&til[rr + p*32][c8] = v;
  }
  __syncthreads();
  #pragma unroll
  for(int p=0;p<2;p++){
    int cc = rr + p*32;
    __align__(16) _Float16 tmp[8];
    #pragma unroll
    for(int j=0;j<8;j++) tmp[j] = til[c8 + j][cc];
    *(uint4*)(embT + (size_t)(c0+cc)*NPAD + r0 + c8) = *(uint4*)tmp;
  }
}

// ---- G = E^T E via f16 MFMA on embT; 128x128 tiles, split-K atomics ----
__global__ __launch_bounds__(256) void k_syrk(const _Float16* __restrict__ embT, float* G){
  __shared__ __align__(16) _Float16 As[128][72];
  __shared__ __align__(16) _Float16 Bs[128][72];
  int tid = threadIdx.x;
  int w = tid>>6, lane = tid&63;
  int quad = lane>>4, l15 = lane&15;
  int wm = (w>>1)*64, wn = (w&1)*64;
  int m0 = blockIdx.y*128, n0 = blockIdx.x*128;
  int kbeg = blockIdx.z*3776;
  int kend = kbeg + 3776; if(kend > NPAD) kend = NPAD;
  int srow = tid>>3, scol = (tid&7)*8;
  f32x4 acc[4][4];
  #pragma unroll
  for(int i=0;i<4;i++)
    #pragma unroll
    for(int j=0;j<4;j++) acc[i][j] = (f32x4){0.f,0.f,0.f,0.f};
  for(int k0=kbeg;k0<kend;k0+=64){
    #pragma unroll
    for(int p=0;p<4;p++){
      int r = srow + p*32;
      *(uint4*)&As[r][scol] = *(const uint4*)(embT + (size_t)(m0+r)*NPAD + k0 + scol);
      *(uint4*)&Bs[r][scol] = *(const uint4*)(embT + (size_t)(n0+r)*NPAD + k0 + scol);
    }
    __syncthreads();
    #pragma unroll
    for(int ks=0;ks<2;ks++){
      int kc = ks*32 + quad*8;
      half8 af[4], bf[4];
      #pragma unroll
      for(int i=0;i<4;i++) af[i] = *(half8*)&As[wm + i*16 + l15][kc];
      #pragma unroll
      for(int j=0;j<4;j++) bf[j] = *(half8*)&Bs[wn + j*16 + l15][kc];
      #pragma unroll
      for(int i=0;i<4;i++)
        #pragma unroll
        for(int j=0;j<4;j++)
          acc[i][j] = __builtin_amdgcn_mfma_f32_16x16x32_f16(af[i], bf[j], acc[i][j], 0,0,0);
    }
    __syncthreads();
  }
  #pragma unroll
  for(int i=0;i<4;i++){
    #pragma unroll
    for(int r=0;r<4;r++){
      int m = m0 + wm + i*16 + quad*4 + r;
      #pragma unroll
      for(int j=0;j<4;j++){
        int n = n0 + wn + j*16 + l15;
        unsafeAtomicAdd(&G[(size_t)m*EMBD + n], acc[i][j][r]);
      }
    }
  }
}

// ================== fp32 GEMM mainloop (64x64x16 tile) — used for gemmT only ==================
#define GEMM_MAIN(W_, EMB_, NB_) \
  __shared__ float Asf[16][68]; \
  __shared__ float Bsf[16][68]; \
  int tid = threadIdx.x; \
  int tx = tid & 15, ty = tid >> 4; \
  int m0 = blockIdx.y*64, n0 = blockIdx.x*64; \
  int lm = tid >> 2, lk = (tid & 3) * 4; \
  float acc[4][4] = {}; \
  const float* aPtr = W_ + (size_t)(m0+lm)*EMBD + lk; \
  int gn = n0 + lm; \
  const float* bPtr = EMB_ + (size_t)gn*EMBD + lk; \
  bool bok = gn < (NB_); \
  for(int k0=0;k0<EMBD;k0+=16){ \
    float4 av = *(const float4*)(aPtr + k0); \
    float4 bv = bok ? *(const float4*)(bPtr + k0) : make_float4(0.f,0.f,0.f,0.f); \
    Asf[lk+0][lm]=av.x; Asf[lk+1][lm]=av.y; Asf[lk+2][lm]=av.z; Asf[lk+3][lm]=av.w; \
    Bsf[lk+0][lm]=bv.x; Bsf[lk+1][lm]=bv.y; Bsf[lk+2][lm]=bv.z; Bsf[lk+3][lm]=bv.w; \
    __syncthreads(); \
    _Pragma("unroll") \
    for(int k=0;k<16;k++){ \
      float4 a = *(const float4*)&Asf[k][ty*4]; \
      float4 b = *(const float4*)&Bsf[k][tx*4]; \
      acc[0][0]+=a.x*b.x; acc[0][1]+=a.x*b.y; acc[0][2]+=a.x*b.z; acc[0][3]+=a.x*b.w; \
      acc[1][0]+=a.y*b.x; acc[1][1]+=a.y*b.y; acc[1][2]+=a.y*b.z; acc[1][3]+=a.y*b.w; \
      acc[2][0]+=a.z*b.x; acc[2][1]+=a.z*b.y; acc[2][2]+=a.z*b.z; acc[2][3]+=a.z*b.w; \
      acc[3][0]+=a.w*b.x; acc[3][1]+=a.w*b.y; acc[3][2]+=a.w*b.z; acc[3][3]+=a.w*b.w; \
    } \
    __syncthreads(); \
  }

// ---- T = W * G (G symmetric) ----
__global__ __launch_bounds__(256) void k_gemmT(const float* __restrict__ W, const float* __restrict__ G, float* Tm){
  GEMM_MAIN(W, G, EMBD)
  #pragma unroll
  for(int i=0;i<4;i++){
    int mg = m0 + ty*4 + i;
    #pragma unroll
    for(int j=0;j<4;j++){
      int jv = n0 + tx*4 + j;
      Tm[(size_t)mg*EMBD + jv] = acc[i][j];
    }
  }
}

// ---- per-row closed-form stats ----
__global__ __launch_bounds__(256) void k_rowstats(const float* __restrict__ W, const float* __restrict__ Tm,
      const _Float16* __restrict__ Eh, const float* __restrict__ qn, const float* __restrict__ cvec,
      const int* __restrict__ tp, const float* __restrict__ Svec, const float* __restrict__ Pvec,
      const float* __restrict__ QQ, float* alpha, float* betav){
  int row = blockIdx.x*4 + (threadIdx.x>>6);
  int lane = threadIdx.x & 63;
  if(row >= 2*B_PAIR) return;
  int pi = row & (B_PAIR-1);
  int lp = tp[2*pi], rp = tp[2*pi+1];
  float d1=0,d2=0,d3=0,dl=0,dr=0;
  #pragma unroll
  for(int k=0;k<12;k++){
    int d = lane + 64*k;
    float a = W[(size_t)row*EMBD + d];
    d1 += a*Svec[d];
    d2 += a*Pvec[d];
    d3 += a*Tm[(size_t)row*EMBD + d];
    dl += a*(float)Eh[(size_t)lp*EMBD + d];
    dr += a*(float)Eh[(size_t)rp*EMBD + d];
  }
  d1=waveRedSum(d1); d2=waveRedSum(d2); d3=waveRedSum(d3);
  dl=waveRedSum(dl); dr=waveRedSum(dr);
  if(lane==0){
    double c = (double)cvec[row], Q = (double)QQ[0], Q2 = (double)QQ[1], Nn = (double)N_ENT;
    double su  = Nn*c - Q + 2.0*(double)d1;
    double su2 = Nn*c*c - 2.0*c*Q + Q2 + 4.0*(c*(double)d1 - (double)d2) + 4.0*(double)d3;
    double ul = c - (double)qn[lp] + 2.0*(double)dl;
    double ur = c - (double)qn[rp] + 2.0*(double)dr;
    su -= ul + ur;
    if(lp != rp) su2 -= ul*ul + ur*ur;
    double mu = su/Nn;
    double var = su2/Nn - mu*mu;
    double sd = sqrt(fmax(var, 0.0));
    double al = 20.0/sd;
    alpha[row] = (float)al;
    betav[row] = (float)(8.0 - al*mu);
  }
}

__device__ inline void lseMerge(float& mx, float& sm, float om, float os){
  if(om > mx){ sm = sm*expf(mx-om) + os; mx = om; }
  else if(om != -INFINITY){ sm += os*expf(om-mx); }
}

// ---- pass B: f16 MFMA GEMM + fused z/lse epilogue; BM=256, BN=64, BK=64 ----
__global__ __launch_bounds__(256) void k_gemmB(const _Float16* __restrict__ Wh, const _Float16* __restrict__ Eh,
    const float* __restrict__ cvec, const float* __restrict__ qn, const int* __restrict__ tp,
    const float* __restrict__ alpha, const float* __restrict__ betav, float* pm, float* ps){
  __shared__ __align__(16) _Float16 As[256][72];
  __shared__ __align__(16) _Float16 Bs[64][72];
  int tid = threadIdx.x;
  int w = tid>>6, lane = tid&63;
  int quad = lane>>4, l15 = lane&15;
  int m0 = blockIdx.y*256, n0 = blockIdx.x*64;
  int srow = tid>>3, scol = (tid&7)*8;
  f32x4 acc[4][4];
  #pragma unroll
  for(int i=0;i<4;i++)
    #pragma unroll
    for(int j=0;j<4;j++) acc[i][j] = (f32x4){0.f,0.f,0.f,0.f};
  for(int k0=0;k0<EMBD;k0+=64){
    #pragma unroll
    for(int p=0;p<8;p++){
      int r = srow + p*32;
      *(uint4*)&As[r][scol] = *(const uint4*)(Wh + (size_t)(m0+r)*EMBD + k0 + scol);
    }
    #pragma unroll
    for(int p=0;p<2;p++){
      int r = srow + p*32;
      int gn = n0 + r;
      uint4 v = make_uint4(0u,0u,0u,0u);
      if(gn < N_ENT) v = *(const uint4*)(Eh + (size_t)gn*EMBD + k0 + scol);
      *(uint4*)&Bs[r][scol] = v;
    }
    __syncthreads();
    #pragma unroll
    for(int ks=0;ks<2;ks++){
      int kc = ks*32 + quad*8;
      half8 af[4], bf[4];
      #pragma unroll
      for(int i=0;i<4;i++) af[i] = *(half8*)&As[w*64 + i*16 + l15][kc];
      #pragma unroll
      for(int j=0;j<4;j++) bf[j] = *(half8*)&Bs[j*16 + l15][kc];
      #pragma unroll
      for(int i=0;i<4;i++)
        #pragma unroll
        for(int j=0;j<4;j++)
          acc[i][j] = __builtin_amdgcn_mfma_f32_16x16x32_f16(af[i], bf[j], acc[i][j], 0,0,0);
    }
    __syncthreads();
  }
  // epilogue: per-element loss -> z -> online lse, reduce across 16 lanes per row
  float qv[4]; int jv[4];
  #pragma unroll
  for(int j=0;j<4;j++){ jv[j] = n0 + j*16 + l15; qv[j] = (jv[j]<N_ENT)? qn[jv[j]] : 0.f; }
  #pragma unroll
  for(int i=0;i<4;i++){
    int mbase = m0 + w*64 + i*16 + quad*4;
    #pragma unroll
    for(int r=0;r<4;r++){
      int mg = mbase + r;
      int pi = mg & (B_PAIR-1);
      int lp = tp[2*pi], rp = tp[2*pi+1];
      float cv = cvec[mg], al = alpha[mg], be = betav[mg];
      float mx = -INFINITY, sm = 0.f;
      #pragma unroll
      for(int j=0;j<4;j++){
        if(jv[j] < N_ENT){
          float mask = 1.0f - (float)(jv[j]==lp) - (float)(jv[j]==rp);
          float loss = (cv - qv[j] + 2.0f*acc[i][j][r]) * mask;
          float z = al*loss + be;
          if(z > mx){ sm = sm*__expf(mx - z) + 1.f; mx = z; }
          else sm += __expf(z - mx);
        }
      }
      #pragma unroll
      for(int m=8;m>=1;m>>=1){
        float om = __shfl_xor(mx, m, 64), os = __shfl_xor(sm, m, 64);
        lseMerge(mx, sm, om, os);
      }
      if(l15==0){ pm[(size_t)mg*GB_NT + blockIdx.x] = mx; ps[(size_t)mg*GB_NT + blockIdx.x] = sm; }
    }
  }
}

// ---- combine per-tile LSE partials: block per row ----
__global__ __launch_bounds__(256) void k_lse(const float* __restrict__ pm, const float* __restrict__ ps, float* lse){
  __shared__ float shm[256], shs[256];
  int row = blockIdx.x, tid = threadIdx.x;
  float mx = -INFINITY, sm = 0.f;
  for(int t=tid;t<GB_NT;t+=256) lseMerge(mx, sm, pm[(size_t)row*GB_NT+t], ps[(size_t)row*GB_NT+t]);
  shm[tid]=mx; shs[tid]=sm;
  __syncthreads();
  for(int w=128;w>0;w>>=1){
    if(tid<w){
      float m2=shm[tid], s2=shs[tid];
      lseMerge(m2, s2, shm[tid+w], shs[tid+w]);
      shm[tid]=m2; shs[tid]=s2;
    }
    __syncthreads();
  }
  if(tid==0) lse[row] = shm[0] + logf(shs[0]);
}

// ---- final mean ----
__global__ __launch_bounds__(256) void k_final(const float* __restrict__ lse, float* out){
  __shared__ double sh[256];
  int tid = threadIdx.x;
  double s = 0.0;
  for(int i=tid;i<B_PAIR;i+=256) s += (double)lse[i] + (double)lse[B_PAIR+i];
  sh[tid]=s; __syncthreads();
  for(int w=128;w>0;w>>=1){ if(tid<w) sh[tid]+=sh[tid+w]; __syncthreads(); }
  if(tid==0) out[0] = (float)(sh[0] / (double)B_PAIR);
}

extern "C" void kernel_launch(void* const* d_in, const int* in_sizes, int n_in,
                              void* d_out, int out_size, void* d_ws, size_t ws_size,
                              hipStream_t stream) {
  const float* ent_emb = (const float*)d_in[0];
  const float* rel_emb = (const float*)d_in[1];
  const float* attn_e  = (const float*)d_in[2];
  const float* attn_r  = (const float*)d_in[3];
  const int* adj     = (const int*)d_in[5];
  const int* r_index = (const int*)d_in[6];
  const int* ent_adj = (const int*)d_in[7];
  const int* rel_adj = (const int*)d_in[8];
  const int* tp      = (const int*)d_in[9];
  float* out = (float*)d_out;

  const int* adj_row = adj;
  const int* adj_col = adj + T_EDGE;
  const int* rid1    = r_index + T_EDGE;

  char* base = (char*)d_ws;
  size_t off = 0;
  auto A = [&](size_t b)->void*{ void* p = base + off; off = (off + b + 255) & ~(size_t)255; return p; };
  // zero region
  int*   cntA  = (int*)  A((size_t)N_ENT*4);
  int*   cntE  = (int*)  A((size_t)N_ENT*4);
  int*   cntR  = (int*)  A((size_t)N_ENT*4);
  float* G     = (float*)A((size_t)EMBD*EMBD*4);
  float* Svec  = (float*)A(EMBD*4);
  float* Pvec  = (float*)A(EMBD*4);
  float* QQ    = (float*)A(2*4);
  size_t zero_end = off;
  // plain buffers
  int* startA = (int*)A((size_t)(N_ENT+1)*4);
  int* startE = (int*)A((size_t)(N_ENT+1)*4);
  int* startR = (int*)A((size_t)(N_ENT+1)*4);
  int* curA   = (int*)A((size_t)N_ENT*4);
  int* curE   = (int*)A((size_t)N_ENT*4);
  int* curR   = (int*)A((size_t)N_ENT*4);
  int* scolA  = (int*)A((size_t)T_EDGE*4);
  int* sridA  = (int*)A((size_t)T_EDGE*4);
  int* scolE  = (int*)A((size_t)NNZ_E*4);
  int* scolR  = (int*)A((size_t)NNZ_E*4);
  _Float16* Eh = (_Float16*)A((size_t)N_ENT*EMBD*2);
  // region X: phase-aliased (featA/featB -> embT -> pm/ps)
  char* X = (char*)A((size_t)EMBD*NPAD*2);   // 46.1 MB
  float*    featA = (float*)X;
  float*    featB = (float*)(X + 16u*1024u*1024u);
  _Float16* embT  = (_Float16*)X;
  float*    pm    = (float*)X;
  float*    ps    = (float*)(X + 8u*1024u*1024u);
  float* relnorm = (float*)A((size_t)R_REL*128*4);
  float* attdot  = (float*)A(4*R_REL*4);
  float* Wm      = (float*)A((size_t)2*B_PAIR*EMBD*4);
  _Float16* Wh   = (_Float16*)A((size_t)2*B_PAIR*EMBD*2);
  float* Tm      = (float*)A((size_t)2*B_PAIR*EMBD*4);
  float* cvec    = (float*)A(2*B_PAIR*4);
  float* qn      = (float*)A((size_t)N_ENT*4);
  float* alpha   = (float*)A(2*B_PAIR*4);
  float* betav   = (float*)A(2*B_PAIR*4);
  float* lse     = (float*)A(2*B_PAIR*4);
  (void)ws_size; (void)in_sizes; (void)n_in; (void)out_size;

  hipMemsetAsync(d_ws, 0, zero_end, stream);

  // ---- CSR builds ----
  k_count<<<(T_EDGE+255)/256, 256, 0, stream>>>(adj_row, cntA, T_EDGE);
  k_count<<<(NNZ_E+255)/256, 256, 0, stream>>>(ent_adj, cntE, NNZ_E);
  k_count<<<(NNZ_E+255)/256, 256, 0, stream>>>(rel_adj, cntR, NNZ_E);
  k_scan3<<<3, 1024, 0, stream>>>(cntA, startA, curA, cntE, startE, curE, cntR, startR, curR);
  k_scatter<<<(T_EDGE+255)/256, 256, 0, stream>>>(adj_row, adj_col, rid1, curA, scolA, sridA, T_EDGE);
  k_scatter<<<(NNZ_E+255)/256, 256, 0, stream>>>(ent_adj, ent_adj+NNZ_E, nullptr, curE, scolE, nullptr, NNZ_E);
  k_scatter<<<(NNZ_E+255)/256, 256, 0, stream>>>(rel_adj, rel_adj+NNZ_E, nullptr, curR, scolR, nullptr, NNZ_E);

  k_relnorm<<<R_REL/4, 256, 0, stream>>>(rel_emb, attn_e, attn_r, relnorm, attdot);

  // ---- two GAT stacks ----
  for(int call=0; call<2; ++call){
    const float* src  = call ? rel_emb : ent_emb;
    const int* startS = call ? startR : startE;
    const int* scolS  = call ? scolR : scolE;
    int koff = call ? 2 : 0;
    int coloff = call ? 384 : 0;
    k_avg_tanh<<<N_ENT/4, 256, 0, stream>>>(startS, scolS, src, featA, Eh, coloff);
    k_edge_csr<<<N_ENT/4, 256, 0, stream>>>(startA, scolA, sridA, relnorm, attdot + (koff+0)*R_REL,
                                            featA, featB, Eh, coloff + 128);
    k_edge_csr<<<N_ENT/4, 256, 0, stream>>>(startA, scolA, sridA, relnorm, attdot + (koff+1)*R_REL,
                                            featB, featA, Eh, coloff + 256);
  }

  // ---- align loss ----
  k_gather<<<B_PAIR, 256, 0, stream>>>(Eh, tp, Wm, Wh, cvec);
  k_qn<<<N_ENT/4, 256, 0, stream>>>(Eh, qn);
  k_embstats<<<(N_ENT+127)/128, 256, 0, stream>>>(Eh, qn, Svec, Pvec, QQ);
  dim3 gtr(469, 12);
  k_transp<<<gtr, 256, 0, stream>>>(Eh, embT);
  dim3 gsy(6, 6, 8);
  k_syrk<<<gsy, 256, 0, stream>>>(embT, G);
  dim3 gT(EMBD/64, 2*B_PAIR/64);
  k_gemmT<<<gT, 256, 0, stream>>>(Wm, G, Tm);
  k_rowstats<<<2*B_PAIR/4, 256, 0, stream>>>(Wm, Tm, Eh, qn, cvec, tp, Svec, Pvec, QQ, alpha, betav);
  dim3 gg(GB_NT, 2*B_PAIR/256);
  k_gemmB<<<gg, 256, 0, stream>>>(Wh, Eh, cvec, qn, tp, alpha, betav, pm, ps);
  k_lse<<<2*B_PAIR, 256, 0, stream>>>(pm, ps, lse);
  k_final<<<1, 256, 0, stream>>>(lse, out);
}

// Round 4
// 1117.661 us; speedup vs baseline: 4.4852x; 1.0833x over previous
//
#include <hip/hip_runtime.h>
#include <math.h>

#define N_ENT 30000
#define R_REL 1000
#define T_EDGE 300000
#define B_PAIR 1024
#define NNZ_E 600000
#define GAMMAF 3.0f
#define EPSV 1e-12f
#define EMBD 768
#define NPAD 30016           // N_ENT padded to 64 (zeroed pad rows in Eh)
#define GB_NT 469            // ceil(30000/64) n-tiles for gemmB / lse partials

typedef _Float16 half8 __attribute__((ext_vector_type(8)));
typedef _Float16 half2v __attribute__((ext_vector_type(2)));
typedef float f32x4 __attribute__((ext_vector_type(4)));

__device__ inline void gl_lds16(const _Float16* g, _Float16* l){
  __builtin_amdgcn_global_load_lds(
      (const __attribute__((address_space(1))) unsigned int*)g,
      (__attribute__((address_space(3))) unsigned int*)l, 16, 0, 0);
}

__device__ inline float waveRedSum(float v){
  #pragma unroll
  for(int m=32;m>=1;m>>=1) v += __shfl_xor(v, m, 64);
  return v;
}

__device__ inline float fast_tanh(float x){
  x = fminf(10.f, fmaxf(-10.f, x));
  float e = __expf(2.f*x);
  return (e-1.f)/(e+1.f);
}

// ---- edge-count ----
__global__ __launch_bounds__(256) void k_count(const int* __restrict__ row, int* cnt, int nE){
  int e = blockIdx.x*256 + threadIdx.x;
  if(e < nE) atomicAdd(&cnt[row[e]], 1);
}

// ---- 3 exclusive scans in one launch (block per list) ----
__global__ __launch_bounds__(1024) void k_scan3(const int* c0, int* s0, int* u0,
                                                const int* c1, int* s1, int* u1,
                                                const int* c2, int* s2, int* u2){
  const int* cnt = blockIdx.x==0 ? c0 : (blockIdx.x==1 ? c1 : c2);
  int* start     = blockIdx.x==0 ? s0 : (blockIdx.x==1 ? s1 : s2);
  int* cursor    = blockIdx.x==0 ? u0 : (blockIdx.x==1 ? u1 : u2);
  __shared__ int sh[1024];
  __shared__ int carry;
  int tid = threadIdx.x;
  if(tid==0) carry = 0;
  __syncthreads();
  for(int base=0; base<N_ENT; base+=1024){
    int i = base + tid;
    int v = (i<N_ENT)? cnt[i] : 0;
    sh[tid]=v; __syncthreads();
    for(int off=1; off<1024; off<<=1){
      int t = (tid>=off)? sh[tid-off] : 0;
      __syncthreads();
      sh[tid]+=t; __syncthreads();
    }
    int excl = sh[tid] - v + carry;
    if(i<N_ENT){ start[i]=excl; cursor[i]=excl; }
    __syncthreads();
    if(tid==1023) carry += sh[1023];
    __syncthreads();
  }
  if(tid==0) start[N_ENT] = carry;
}

// ---- scatter edges into CSR order ----
__global__ __launch_bounds__(256) void k_scatter(const int* __restrict__ row, const int* __restrict__ col,
                        const int* __restrict__ rid, int* cursor, int* scol, int* srid, int nE){
  int e = blockIdx.x*256 + threadIdx.x;
  if(e >= nE) return;
  int p = atomicAdd(&cursor[row[e]], 1);
  scol[p] = col[e];
  if(rid) srid[p] = rid[e];
}

// ---- _avg via CSR gather, fused tanh + fp16 emb slice write; wave per row ----
__global__ __launch_bounds__(256) void k_avg_tanh(const int* __restrict__ start, const int* __restrict__ scol,
                        const float* __restrict__ src, float* featOut, _Float16* Eh, int coloff){
  int r = blockIdx.x*4 + (threadIdx.x>>6);
  int lane = threadIdx.x & 63;
  int s0 = start[r], s1 = start[r+1];
  float2 acc = make_float2(0.f,0.f);
  for(int e=s0;e<s1;e++){
    int c = scol[e];
    float2 v = *(const float2*)(src + (size_t)c*128 + lane*2);
    acc.x += v.x; acc.y += v.y;
  }
  float inv = (s1>s0) ? 1.0f/(float)(s1-s0) : 0.f;
  float vx = fast_tanh(acc.x*inv), vy = fast_tanh(acc.y*inv);
  *(float2*)(featOut + (size_t)r*128 + lane*2) = make_float2(vx,vy);
  half2v hv = {(_Float16)vx, (_Float16)vy};
  *(half2v*)(Eh + (size_t)r*EMBD + coloff + lane*2) = hv;
}

// ---- normalized relation table + attention dots ----
__global__ __launch_bounds__(256) void k_relnorm(const float* __restrict__ rel, const float* __restrict__ ae,
                          const float* __restrict__ ar, float* relnorm, float* attdot){
  int r = (blockIdx.x*256 + threadIdx.x) >> 6;
  int lane = threadIdx.x & 63;
  if (r >= R_REL) return;
  float2 v = *(const float2*)(rel + (size_t)r*128 + lane*2);
  float ss = waveRedSum(v.x*v.x + v.y*v.y);
  float nrm = fmaxf(sqrtf(ss), EPSV);
  float2 u; u.x = v.x/nrm; u.y = v.y/nrm;
  *(float2*)(relnorm + (size_t)r*128 + lane*2) = u;
  const float* ks[4] = {ae, ae+128, ar, ar+128};
  #pragma unroll
  for(int k=0;k<4;k++){
    float2 w = *(const float2*)(ks[k] + lane*2);
    float d = waveRedSum(u.x*w.x + u.y*w.y);
    if(lane==0) attdot[k*R_REL + r] = d;
  }
}

// ---- GAT layer via CSR gather (unshifted softmax: |attdot|<=~1.2), fused tanh + fp16 emb write ----
__global__ __launch_bounds__(256) void k_edge_csr(const int* __restrict__ start, const int* __restrict__ scol,
                        const int* __restrict__ srid, const float* __restrict__ relnorm,
                        const float* __restrict__ attdot_k, const float* __restrict__ featIn,
                        float* featOut, _Float16* Eh, int coloff){
  int r = blockIdx.x*4 + (threadIdx.x>>6);
  int lane = threadIdx.x & 63;
  int s0 = start[r], s1 = start[r+1];
  float2 acc = make_float2(0.f,0.f);
  float sumw = 0.f;
  for(int e=s0;e<s1;e++){
    int c = scol[e], q = srid[e];
    float w = __expf(attdot_k[q]);
    sumw += w;
    float2 u = *(const float2*)(relnorm + (size_t)q*128 + lane*2);
    float2 h = *(const float2*)(featIn  + (size_t)c*128 + lane*2);
    float dot = waveRedSum(h.x*u.x + h.y*u.y);
    float t2 = 2.0f*dot*w;
    acc.x += w*h.x - t2*u.x;
    acc.y += w*h.y - t2*u.y;
  }
  float inv = (s1>s0) ? 1.0f/sumw : 0.f;
  float vx = fast_tanh(acc.x*inv), vy = fast_tanh(acc.y*inv);
  *(float2*)(featOut + (size_t)r*128 + lane*2) = make_float2(vx,vy);
  half2v hv = {(_Float16)vx, (_Float16)vy};
  *(half2v*)(Eh + (size_t)r*EMBD + coloff + lane*2) = hv;
}

// ---- gather pair rows from Eh -> Wm fp32, Wh fp16, cvec ----
__global__ __launch_bounds__(256) void k_gather(const _Float16* __restrict__ Eh, const int* __restrict__ tp,
                         float* W, _Float16* Wh, float* cvec){
  int i = blockIdx.x; int tid = threadIdx.x;
  int l = tp[2*i], r = tp[2*i+1];
  float sl=0.f, sr=0.f, sp=0.f;
  for(int c=tid;c<EMBD;c+=256){
    _Float16 lh = Eh[(size_t)l*EMBD+c], rh = Eh[(size_t)r*EMBD+c];
    float le = (float)lh, re = (float)rh;
    W[(size_t)i*EMBD+c]=le; W[(size_t)(B_PAIR+i)*EMBD+c]=re;
    Wh[(size_t)i*EMBD+c]=lh; Wh[(size_t)(B_PAIR+i)*EMBD+c]=rh;
    sl += le*le; sr += re*re; float d = le-re; sp += d*d;
  }
  __shared__ float s0[256], s1[256], s2[256];
  s0[tid]=sl; s1[tid]=sr; s2[tid]=sp;
  __syncthreads();
  for(int w=128;w>0;w>>=1){
    if(tid<w){ s0[tid]+=s0[tid+w]; s1[tid]+=s1[tid+w]; s2[tid]+=s2[tid+w]; }
    __syncthreads();
  }
  if(tid==0){
    float pos = s2[0];
    cvec[i]        = pos + GAMMAF - s0[0];
    cvec[B_PAIR+i] = pos + GAMMAF - s1[0];
  }
}

// ---- q_j = ||e_j||^2 from Eh, wave per node ----
__global__ __launch_bounds__(256) void k_qn(const _Float16* __restrict__ Eh, float* qn){
  int j = (blockIdx.x*256 + threadIdx.x) >> 6;
  int lane = threadIdx.x & 63;
  if(j >= N_ENT) return;
  float s=0.f;
  #pragma unroll
  for(int q=0;q<12;q++){ float v = (float)Eh[(size_t)j*EMBD + lane + 64*q]; s += v*v; }
  s = waveRedSum(s);
  if(lane==0) qn[j]=s;
}

// ---- S = sum_j e_j, P = sum_j q_j e_j, Q = sum q, Q2 = sum q^2 ----
__global__ __launch_bounds__(256) void k_embstats(const _Float16* __restrict__ Eh, const float* __restrict__ qn,
                           float* Svec, float* Pvec, float* QQ){
  int tid = threadIdx.x;
  int n0 = blockIdx.x*128;
  int nend = n0+128; if(nend > N_ENT) nend = N_ENT;
  float s[3]={0,0,0}, p[3]={0,0,0};
  float q1=0.f, q2=0.f;
  for(int n=n0;n<nend;n++){
    float qv = qn[n];
    if(tid==0){ q1 += qv; q2 += qv*qv; }
    #pragma unroll
    for(int k=0;k<3;k++){
      float v = (float)Eh[(size_t)n*EMBD + tid + k*256];
      s[k] += v; p[k] += qv*v;
    }
  }
  #pragma unroll
  for(int k=0;k<3;k++){
    unsafeAtomicAdd(&Svec[tid + k*256], s[k]);
    unsafeAtomicAdd(&Pvec[tid + k*256], p[k]);
  }
  if(tid==0){ unsafeAtomicAdd(&QQ[0], q1); unsafeAtomicAdd(&QQ[1], q2); }
}

// ---- transpose Eh (30000x768) -> embT (768 x NPAD), zero-padded ----
__global__ __launch_bounds__(256) void k_transp(const _Float16* __restrict__ Eh, _Float16* embT){
  __shared__ __align__(16) _Float16 til[64][72];
  int r0 = blockIdx.x*64, c0 = blockIdx.y*64;
  int t = threadIdx.x;
  int rr = t>>3, c8 = (t&7)*8;
  #pragma unroll
  for(int p=0;p<2;p++){
    int gr = r0 + rr + p*32;
    uint4 v = make_uint4(0u,0u,0u,0u);
    if(gr < N_ENT) v = *(const uint4*)(Eh + (size_t)gr*EMBD + c0 + c8);
    *(uint4*)&til[rr + p*32][c8] = v;
  }
  __syncthreads();
  #pragma unroll
  for(int p=0;p<2;p++){
    int cc = rr + p*32;
    __align__(16) _Float16 tmp[8];
    #pragma unroll
    for(int j=0;j<8;j++) tmp[j] = til[c8 + j][cc];
    *(uint4*)(embT + (size_t)(c0+cc)*NPAD + r0 + c8) = *(uint4*)tmp;
  }
}

// ---- G = E^T E via f16 MFMA on embT; 128x128 tiles, split-K atomics ----
__global__ __launch_bounds__(256) void k_syrk(const _Float16* __restrict__ embT, float* G){
  __shared__ __align__(16) _Float16 As[128][72];
  __shared__ __align__(16) _Float16 Bs[128][72];
  int tid = threadIdx.x;
  int w = tid>>6, lane = tid&63;
  int quad = lane>>4, l15 = lane&15;
  int wm = (w>>1)*64, wn = (w&1)*64;
  int m0 = blockIdx.y*128, n0 = blockIdx.x*128;
  int kbeg = blockIdx.z*3776;
  int kend = kbeg + 3776; if(kend > NPAD) kend = NPAD;
  int srow = tid>>3, scol = (tid&7)*8;
  f32x4 acc[4][4];
  #pragma unroll
  for(int i=0;i<4;i++)
    #pragma unroll
    for(int j=0;j<4;j++) acc[i][j] = (f32x4){0.f,0.f,0.f,0.f};
  for(int k0=kbeg;k0<kend;k0+=64){
    #pragma unroll
    for(int p=0;p<4;p++){
      int r = srow + p*32;
      *(uint4*)&As[r][scol] = *(const uint4*)(embT + (size_t)(m0+r)*NPAD + k0 + scol);
      *(uint4*)&Bs[r][scol] = *(const uint4*)(embT + (size_t)(n0+r)*NPAD + k0 + scol);
    }
    __syncthreads();
    #pragma unroll
    for(int ks=0;ks<2;ks++){
      int kc = ks*32 + quad*8;
      half8 af[4], bf[4];
      #pragma unroll
      for(int i=0;i<4;i++) af[i] = *(half8*)&As[wm + i*16 + l15][kc];
      #pragma unroll
      for(int j=0;j<4;j++) bf[j] = *(half8*)&Bs[wn + j*16 + l15][kc];
      #pragma unroll
      for(int i=0;i<4;i++)
        #pragma unroll
        for(int j=0;j<4;j++)
          acc[i][j] = __builtin_amdgcn_mfma_f32_16x16x32_f16(af[i], bf[j], acc[i][j], 0,0,0);
    }
    __syncthreads();
  }
  #pragma unroll
  for(int i=0;i<4;i++){
    #pragma unroll
    for(int r=0;r<4;r++){
      int m = m0 + wm + i*16 + quad*4 + r;
      #pragma unroll
      for(int j=0;j<4;j++){
        int n = n0 + wn + j*16 + l15;
        unsafeAtomicAdd(&G[(size_t)m*EMBD + n], acc[i][j][r]);
      }
    }
  }
}

// ================== fp32 GEMM mainloop (64x64x16 tile) — used for gemmT only ==================
#define GEMM_MAIN(W_, EMB_, NB_) \
  __shared__ float Asf[16][68]; \
  __shared__ float Bsf[16][68]; \
  int tid = threadIdx.x; \
  int tx = tid & 15, ty = tid >> 4; \
  int m0 = blockIdx.y*64, n0 = blockIdx.x*64; \
  int lm = tid >> 2, lk = (tid & 3) * 4; \
  float acc[4][4] = {}; \
  const float* aPtr = W_ + (size_t)(m0+lm)*EMBD + lk; \
  int gn = n0 + lm; \
  const float* bPtr = EMB_ + (size_t)gn*EMBD + lk; \
  bool bok = gn < (NB_); \
  for(int k0=0;k0<EMBD;k0+=16){ \
    float4 av = *(const float4*)(aPtr + k0); \
    float4 bv = bok ? *(const float4*)(bPtr + k0) : make_float4(0.f,0.f,0.f,0.f); \
    Asf[lk+0][lm]=av.x; Asf[lk+1][lm]=av.y; Asf[lk+2][lm]=av.z; Asf[lk+3][lm]=av.w; \
    Bsf[lk+0][lm]=bv.x; Bsf[lk+1][lm]=bv.y; Bsf[lk+2][lm]=bv.z; Bsf[lk+3][lm]=bv.w; \
    __syncthreads(); \
    _Pragma("unroll") \
    for(int k=0;k<16;k++){ \
      float4 a = *(const float4*)&Asf[k][ty*4]; \
      float4 b = *(const float4*)&Bsf[k][tx*4]; \
      acc[0][0]+=a.x*b.x; acc[0][1]+=a.x*b.y; acc[0][2]+=a.x*b.z; acc[0][3]+=a.x*b.w; \
      acc[1][0]+=a.y*b.x; acc[1][1]+=a.y*b.y; acc[1][2]+=a.y*b.z; acc[1][3]+=a.y*b.w; \
      acc[2][0]+=a.z*b.x; acc[2][1]+=a.z*b.y; acc[2][2]+=a.z*b.z; acc[2][3]+=a.z*b.w; \
      acc[3][0]+=a.w*b.x; acc[3][1]+=a.w*b.y; acc[3][2]+=a.w*b.z; acc[3][3]+=a.w*b.w; \
    } \
    __syncthreads(); \
  }

// ---- T = W * G (G symmetric) ----
__global__ __launch_bounds__(256) void k_gemmT(const float* __restrict__ W, const float* __restrict__ G, float* Tm){
  GEMM_MAIN(W, G, EMBD)
  #pragma unroll
  for(int i=0;i<4;i++){
    int mg = m0 + ty*4 + i;
    #pragma unroll
    for(int j=0;j<4;j++){
      int jv = n0 + tx*4 + j;
      Tm[(size_t)mg*EMBD + jv] = acc[i][j];
    }
  }
}

// ---- per-row closed-form stats ----
__global__ __launch_bounds__(256) void k_rowstats(const float* __restrict__ W, const float* __restrict__ Tm,
      const _Float16* __restrict__ Eh, const float* __restrict__ qn, const float* __restrict__ cvec,
      const int* __restrict__ tp, const float* __restrict__ Svec, const float* __restrict__ Pvec,
      const float* __restrict__ QQ, float* alpha, float* betav){
  int row = blockIdx.x*4 + (threadIdx.x>>6);
  int lane = threadIdx.x & 63;
  if(row >= 2*B_PAIR) return;
  int pi = row & (B_PAIR-1);
  int lp = tp[2*pi], rp = tp[2*pi+1];
  float d1=0,d2=0,d3=0,dl=0,dr=0;
  #pragma unroll
  for(int k=0;k<12;k++){
    int d = lane + 64*k;
    float a = W[(size_t)row*EMBD + d];
    d1 += a*Svec[d];
    d2 += a*Pvec[d];
    d3 += a*Tm[(size_t)row*EMBD + d];
    dl += a*(float)Eh[(size_t)lp*EMBD + d];
    dr += a*(float)Eh[(size_t)rp*EMBD + d];
  }
  d1=waveRedSum(d1); d2=waveRedSum(d2); d3=waveRedSum(d3);
  dl=waveRedSum(dl); dr=waveRedSum(dr);
  if(lane==0){
    double c = (double)cvec[row], Q = (double)QQ[0], Q2 = (double)QQ[1], Nn = (double)N_ENT;
    double su  = Nn*c - Q + 2.0*(double)d1;
    double su2 = Nn*c*c - 2.0*c*Q + Q2 + 4.0*(c*(double)d1 - (double)d2) + 4.0*(double)d3;
    double ul = c - (double)qn[lp] + 2.0*(double)dl;
    double ur = c - (double)qn[rp] + 2.0*(double)dr;
    su -= ul + ur;
    if(lp != rp) su2 -= ul*ul + ur*ur;
    double mu = su/Nn;
    double var = su2/Nn - mu*mu;
    double sd = sqrt(fmax(var, 0.0));
    double al = 20.0/sd;
    alpha[row] = (float)al;
    betav[row] = (float)(8.0 - al*mu);
  }
}

__device__ inline void lseMerge(float& mx, float& sm, float om, float os){
  if(om > mx){ sm = sm*expf(mx-om) + os; mx = om; }
  else if(om != -INFINITY){ sm += os*expf(om-mx); }
}

// ---- pass B: f16 MFMA GEMM, m97-style: global_load_lds staging + XOR-swizzled LDS,
//      grid (469 n, 2 m-half), inner loop over 4 m-subtiles of 256 rows ----
__global__ __launch_bounds__(256) void k_gemmB(const _Float16* __restrict__ Wh, const _Float16* __restrict__ Eh,
    const float* __restrict__ cvec, const float* __restrict__ qn, const int* __restrict__ tp,
    const float* __restrict__ alpha, const float* __restrict__ betav, float* pm, float* ps){
  __shared__ __align__(16) _Float16 AsF[256*64];   // [row][64k], chunk-swizzled
  __shared__ __align__(16) _Float16 BsF[64*64];
  int tid = threadIdx.x;
  int w = tid>>6, lane = tid&63;
  int quad = lane>>4, l15 = lane&15;
  int lr = lane>>3, lc = lane&7;       // staging: row-within-8, chunk slot
  int n0 = blockIdx.x*64;
  // B frag qn / masks (invariant over msub)
  float qv[4]; int jv[4];
  #pragma unroll
  for(int j=0;j<4;j++){ jv[j] = n0 + j*16 + l15; qv[j] = (jv[j]<N_ENT)? qn[jv[j]] : 0.f; }
  for(int msub=0; msub<4; msub++){
    int m0 = blockIdx.y*1024 + msub*256;
    f32x4 acc[4][4];
    #pragma unroll
    for(int i=0;i<4;i++)
      #pragma unroll
      for(int j=0;j<4;j++) acc[i][j] = (f32x4){0.f,0.f,0.f,0.f};
    for(int k0=0;k0<EMBD;k0+=64){
      // stage A: 8 DMA calls/thread, 1KB per wave-call, chunk-swizzled on global side
      #pragma unroll
      for(int p=0;p<8;p++){
        int m = p*32 + w*8 + lr;
        int cg = lc ^ (m&7);
        gl_lds16(Wh + (size_t)(m0+m)*EMBD + k0 + cg*8, AsF + (p*32 + w*8)*64);
      }
      // stage B: 2 DMA calls/thread (Eh zero-padded to NPAD rows)
      #pragma unroll
      for(int p=0;p<2;p++){
        int n = p*32 + w*8 + lr;
        int cg = lc ^ (n&7);
        gl_lds16(Eh + (size_t)(n0+n)*EMBD + k0 + cg*8, BsF + (p*32 + w*8)*64);
      }
      __syncthreads();
      #pragma unroll
      for(int ks=0;ks<2;ks++){
        half8 af[4], bf[4];
        #pragma unroll
        for(int i=0;i<4;i++){
          int ml = w*64 + i*16 + l15;
          af[i] = *(half8*)(AsF + ml*64 + (((ks<<2)|quad) ^ (ml&7))*8);
        }
        #pragma unroll
        for(int j=0;j<4;j++){
          int nl = j*16 + l15;
          bf[j] = *(half8*)(BsF + nl*64 + (((ks<<2)|quad) ^ (nl&7))*8);
        }
        #pragma unroll
        for(int i=0;i<4;i++)
          #pragma unroll
          for(int j=0;j<4;j++)
            acc[i][j] = __builtin_amdgcn_mfma_f32_16x16x32_f16(af[i], bf[j], acc[i][j], 0,0,0);
      }
      __syncthreads();
    }
    // epilogue (registers only): loss -> z -> online lse over 64 cols, reduce 16 lanes/row
    #pragma unroll
    for(int i=0;i<4;i++){
      int mbase = m0 + w*64 + i*16 + quad*4;
      #pragma unroll
      for(int r=0;r<4;r++){
        int mg = mbase + r;
        int pi = mg & (B_PAIR-1);
        int lp = tp[2*pi], rp = tp[2*pi+1];
        float cv = cvec[mg], al = alpha[mg], be = betav[mg];
        float mx = -INFINITY, sm = 0.f;
        #pragma unroll
        for(int j=0;j<4;j++){
          if(jv[j] < N_ENT){
            float mask = 1.0f - (float)(jv[j]==lp) - (float)(jv[j]==rp);
            float loss = (cv - qv[j] + 2.0f*acc[i][j][r]) * mask;
            float z = al*loss + be;
            if(z > mx){ sm = sm*__expf(mx - z) + 1.f; mx = z; }
            else sm += __expf(z - mx);
          }
        }
        #pragma unroll
        for(int m=8;m>=1;m>>=1){
          float om = __shfl_xor(mx, m, 64), os = __shfl_xor(sm, m, 64);
          lseMerge(mx, sm, om, os);
        }
        if(l15==0){ pm[(size_t)mg*GB_NT + blockIdx.x] = mx; ps[(size_t)mg*GB_NT + blockIdx.x] = sm; }
      }
    }
  }
}

// ---- combine per-tile LSE partials: block per row ----
__global__ __launch_bounds__(256) void k_lse(const float* __restrict__ pm, const float* __restrict__ ps, float* lse){
  __shared__ float shm[256], shs[256];
  int row = blockIdx.x, tid = threadIdx.x;
  float mx = -INFINITY, sm = 0.f;
  for(int t=tid;t<GB_NT;t+=256) lseMerge(mx, sm, pm[(size_t)row*GB_NT+t], ps[(size_t)row*GB_NT+t]);
  shm[tid]=mx; shs[tid]=sm;
  __syncthreads();
  for(int w=128;w>0;w>>=1){
    if(tid<w){
      float m2=shm[tid], s2=shs[tid];
      lseMerge(m2, s2, shm[tid+w], shs[tid+w]);
      shm[tid]=m2; shs[tid]=s2;
    }
    __syncthreads();
  }
  if(tid==0) lse[row] = shm[0] + logf(shs[0]);
}

// ---- final mean ----
__global__ __launch_bounds__(256) void k_final(const float* __restrict__ lse, float* out){
  __shared__ double sh[256];
  int tid = threadIdx.x;
  double s = 0.0;
  for(int i=tid;i<B_PAIR;i+=256) s += (double)lse[i] + (double)lse[B_PAIR+i];
  sh[tid]=s; __syncthreads();
  for(int w=128;w>0;w>>=1){ if(tid<w) sh[tid]+=sh[tid+w]; __syncthreads(); }
  if(tid==0) out[0] = (float)(sh[0] / (double)B_PAIR);
}

extern "C" void kernel_launch(void* const* d_in, const int* in_sizes, int n_in,
                              void* d_out, int out_size, void* d_ws, size_t ws_size,
                              hipStream_t stream) {
  const float* ent_emb = (const float*)d_in[0];
  const float* rel_emb = (const float*)d_in[1];
  const float* attn_e  = (const float*)d_in[2];
  const float* attn_r  = (const float*)d_in[3];
  const int* adj     = (const int*)d_in[5];
  const int* r_index = (const int*)d_in[6];
  const int* ent_adj = (const int*)d_in[7];
  const int* rel_adj = (const int*)d_in[8];
  const int* tp      = (const int*)d_in[9];
  float* out = (float*)d_out;

  const int* adj_row = adj;
  const int* adj_col = adj + T_EDGE;
  const int* rid1    = r_index + T_EDGE;

  char* base = (char*)d_ws;
  size_t off = 0;
  auto A = [&](size_t b)->void*{ void* p = base + off; off = (off + b + 255) & ~(size_t)255; return p; };
  // zero region
  int*   cntA  = (int*)  A((size_t)N_ENT*4);
  int*   cntE  = (int*)  A((size_t)N_ENT*4);
  int*   cntR  = (int*)  A((size_t)N_ENT*4);
  float* G     = (float*)A((size_t)EMBD*EMBD*4);
  float* Svec  = (float*)A(EMBD*4);
  float* Pvec  = (float*)A(EMBD*4);
  float* QQ    = (float*)A(2*4);
  size_t zero_end = off;
  // plain buffers
  int* startA = (int*)A((size_t)(N_ENT+1)*4);
  int* startE = (int*)A((size_t)(N_ENT+1)*4);
  int* startR = (int*)A((size_t)(N_ENT+1)*4);
  int* curA   = (int*)A((size_t)N_ENT*4);
  int* curE   = (int*)A((size_t)N_ENT*4);
  int* curR   = (int*)A((size_t)N_ENT*4);
  int* scolA  = (int*)A((size_t)T_EDGE*4);
  int* sridA  = (int*)A((size_t)T_EDGE*4);
  int* scolE  = (int*)A((size_t)NNZ_E*4);
  int* scolR  = (int*)A((size_t)NNZ_E*4);
  _Float16* Eh = (_Float16*)A((size_t)NPAD*EMBD*2);   // padded rows zeroed below
  // region X: phase-aliased (featA/featB -> embT -> pm/ps)
  char* X = (char*)A((size_t)EMBD*NPAD*2);   // 46.1 MB
  float*    featA = (float*)X;
  float*    featB = (float*)(X + 16u*1024u*1024u);
  _Float16* embT  = (_Float16*)X;
  float*    pm    = (float*)X;
  float*    ps    = (float*)(X + 8u*1024u*1024u);
  float* relnorm = (float*)A((size_t)R_REL*128*4);
  float* attdot  = (float*)A(4*R_REL*4);
  float* Wm      = (float*)A((size_t)2*B_PAIR*EMBD*4);
  _Float16* Wh   = (_Float16*)A((size_t)2*B_PAIR*EMBD*2);
  float* Tm      = (float*)A((size_t)2*B_PAIR*EMBD*4);
  float* cvec    = (float*)A(2*B_PAIR*4);
  float* qn      = (float*)A((size_t)N_ENT*4);
  float* alpha   = (float*)A(2*B_PAIR*4);
  float* betav   = (float*)A(2*B_PAIR*4);
  float* lse     = (float*)A(2*B_PAIR*4);
  (void)ws_size; (void)in_sizes; (void)n_in; (void)out_size;

  hipMemsetAsync(d_ws, 0, zero_end, stream);
  hipMemsetAsync(Eh + (size_t)N_ENT*EMBD, 0, (size_t)(NPAD-N_ENT)*EMBD*2, stream);

  // ---- CSR builds ----
  k_count<<<(T_EDGE+255)/256, 256, 0, stream>>>(adj_row, cntA, T_EDGE);
  k_count<<<(NNZ_E+255)/256, 256, 0, stream>>>(ent_adj, cntE, NNZ_E);
  k_count<<<(NNZ_E+255)/256, 256, 0, stream>>>(rel_adj, cntR, NNZ_E);
  k_scan3<<<3, 1024, 0, stream>>>(cntA, startA, curA, cntE, startE, curE, cntR, startR, curR);
  k_scatter<<<(T_EDGE+255)/256, 256, 0, stream>>>(adj_row, adj_col, rid1, curA, scolA, sridA, T_EDGE);
  k_scatter<<<(NNZ_E+255)/256, 256, 0, stream>>>(ent_adj, ent_adj+NNZ_E, nullptr, curE, scolE, nullptr, NNZ_E);
  k_scatter<<<(NNZ_E+255)/256, 256, 0, stream>>>(rel_adj, rel_adj+NNZ_E, nullptr, curR, scolR, nullptr, NNZ_E);

  k_relnorm<<<R_REL/4, 256, 0, stream>>>(rel_emb, attn_e, attn_r, relnorm, attdot);

  // ---- two GAT stacks ----
  for(int call=0; call<2; ++call){
    const float* src  = call ? rel_emb : ent_emb;
    const int* startS = call ? startR : startE;
    const int* scolS  = call ? scolR : scolE;
    int koff = call ? 2 : 0;
    int coloff = call ? 384 : 0;
    k_avg_tanh<<<N_ENT/4, 256, 0, stream>>>(startS, scolS, src, featA, Eh, coloff);
    k_edge_csr<<<N_ENT/4, 256, 0, stream>>>(startA, scolA, sridA, relnorm, attdot + (koff+0)*R_REL,
                                            featA, featB, Eh, coloff + 128);
    k_edge_csr<<<N_ENT/4, 256, 0, stream>>>(startA, scolA, sridA, relnorm, attdot + (koff+1)*R_REL,
                                            featB, featA, Eh, coloff + 256);
  }

  // ---- align loss ----
  k_gather<<<B_PAIR, 256, 0, stream>>>(Eh, tp, Wm, Wh, cvec);
  k_qn<<<N_ENT/4, 256, 0, stream>>>(Eh, qn);
  k_embstats<<<(N_ENT+127)/128, 256, 0, stream>>>(Eh, qn, Svec, Pvec, QQ);
  dim3 gtr(469, 12);
  k_transp<<<gtr, 256, 0, stream>>>(Eh, embT);
  dim3 gsy(6, 6, 8);
  k_syrk<<<gsy, 256, 0, stream>>>(embT, G);
  dim3 gT(EMBD/64, 2*B_PAIR/64);
  k_gemmT<<<gT, 256, 0, stream>>>(Wm, G, Tm);
  k_rowstats<<<2*B_PAIR/4, 256, 0, stream>>>(Wm, Tm, Eh, qn, cvec, tp, Svec, Pvec, QQ, alpha, betav);
  dim3 gg(GB_NT, 2);
  k_gemmB<<<gg, 256, 0, stream>>>(Wh, Eh, cvec, qn, tp, alpha, betav, pm, ps);
  k_lse<<<2*B_PAIR, 256, 0, stream>>>(pm, ps, lse);
  k_final<<<1, 256, 0, stream>>>(lse, out);
}

// Round 5
// 1104.374 us; speedup vs baseline: 4.5391x; 1.0120x over previous
//
#include <hip/hip_runtime.h>
#include <math.h>

#define N_ENT 30000
#define R_REL 1000
#define T_EDGE 300000
#define B_PAIR 1024
#define NNZ_E 600000
#define GAMMAF 3.0f
#define EPSV 1e-12f
#define EMBD 768
#define NPAD 30016           // N_ENT padded to 64 (zeroed pad rows in Eh)
#define GB_NT 469            // ceil(30000/64) n-tiles for gemmB / lse partials

typedef _Float16 half8 __attribute__((ext_vector_type(8)));
typedef _Float16 half4v __attribute__((ext_vector_type(4)));
typedef _Float16 half2v __attribute__((ext_vector_type(2)));
typedef float f32x4 __attribute__((ext_vector_type(4)));

__device__ inline float waveRedSum(float v){
  #pragma unroll
  for(int m=32;m>=1;m>>=1) v += __shfl_xor(v, m, 64);
  return v;
}

__device__ inline float fast_tanh(float x){
  x = fminf(10.f, fmaxf(-10.f, x));
  float e = __expf(2.f*x);
  return (e-1.f)/(e+1.f);
}

// ---- edge-count ----
__global__ __launch_bounds__(256) void k_count(const int* __restrict__ row, int* cnt, int nE){
  int e = blockIdx.x*256 + threadIdx.x;
  if(e < nE) atomicAdd(&cnt[row[e]], 1);
}

// ---- 3 exclusive scans in one launch (block per list), wave-level scan ----
__global__ __launch_bounds__(1024) void k_scan3(const int* c0, int* s0, int* u0,
                                                const int* c1, int* s1, int* u1,
                                                const int* c2, int* s2, int* u2){
  const int* cnt = blockIdx.x==0 ? c0 : (blockIdx.x==1 ? c1 : c2);
  int* start     = blockIdx.x==0 ? s0 : (blockIdx.x==1 ? s1 : s2);
  int* cursor    = blockIdx.x==0 ? u0 : (blockIdx.x==1 ? u1 : u2);
  __shared__ int wsum[16];
  __shared__ int carry;
  int tid = threadIdx.x, lane = tid & 63, wid = tid >> 6;
  if(tid==0) carry = 0;
  __syncthreads();
  for(int base=0; base<N_ENT; base+=1024){
    int i = base + tid;
    int v = (i<N_ENT)? cnt[i] : 0;
    int x = v;
    #pragma unroll
    for(int off=1; off<64; off<<=1){ int t=__shfl_up(x,off,64); if(lane>=off) x+=t; }
    if(lane==63) wsum[wid]=x;
    __syncthreads();
    if(wid==0){
      int s = (lane<16)? wsum[lane] : 0;
      #pragma unroll
      for(int off=1; off<16; off<<=1){ int t=__shfl_up(s,off,64); if(lane>=off) s+=t; }
      if(lane<16) wsum[lane]=s;
    }
    __syncthreads();
    int wexcl = (wid==0)? 0 : wsum[wid-1];
    int excl = carry + wexcl + x - v;
    if(i<N_ENT){ start[i]=excl; cursor[i]=excl; }
    int tot = wsum[15];
    __syncthreads();
    if(tid==0) carry += tot;
    __syncthreads();
  }
  if(tid==0) start[N_ENT] = carry;
}

// ---- scatter edges into CSR order ----
__global__ __launch_bounds__(256) void k_scatter(const int* __restrict__ row, const int* __restrict__ col,
                        const int* __restrict__ rid, int* cursor, int* scol, int* srid, int nE){
  int e = blockIdx.x*256 + threadIdx.x;
  if(e >= nE) return;
  int p = atomicAdd(&cursor[row[e]], 1);
  scol[p] = col[e];
  if(rid) srid[p] = rid[e];
}

// ---- _avg via CSR gather, fused tanh; writes interleaved fp16 featC + Eh slice ----
__global__ __launch_bounds__(256) void k_avg_tanh(const int* __restrict__ start, const int* __restrict__ scol,
                        const float* __restrict__ src, _Float16* featC, _Float16* Eh, int pairOff, int coloff){
  int r = blockIdx.x*4 + (threadIdx.x>>6);
  int lane = threadIdx.x & 63;
  int s0 = start[r], s1 = start[r+1];
  float ax=0.f, ay=0.f;
  int e = s0;
  for(; e+1<s1; e+=2){
    int c0 = scol[e], c1 = scol[e+1];
    float2 v0 = *(const float2*)(src + (size_t)c0*128 + lane*2);
    float2 v1 = *(const float2*)(src + (size_t)c1*128 + lane*2);
    ax += v0.x + v1.x; ay += v0.y + v1.y;
  }
  if(e<s1){
    int c0 = scol[e];
    float2 v0 = *(const float2*)(src + (size_t)c0*128 + lane*2);
    ax += v0.x; ay += v0.y;
  }
  float inv = (s1>s0) ? 1.0f/(float)(s1-s0) : 0.f;
  float vx = fast_tanh(ax*inv), vy = fast_tanh(ay*inv);
  half2v hv = {(_Float16)vx, (_Float16)vy};
  *(half2v*)(featC + (size_t)r*256 + lane*4 + pairOff) = hv;
  *(half2v*)(Eh + (size_t)r*EMBD + coloff + lane*2) = hv;
}

// ---- normalized relation table (fp16) + exp(attention-dot) tables ----
__global__ __launch_bounds__(256) void k_relnorm(const float* __restrict__ rel, const float* __restrict__ ae,
                          const float* __restrict__ ar, _Float16* relnH, float* expdot){
  int r = (blockIdx.x*256 + threadIdx.x) >> 6;
  int lane = threadIdx.x & 63;
  if (r >= R_REL) return;
  float2 v = *(const float2*)(rel + (size_t)r*128 + lane*2);
  float ss = waveRedSum(v.x*v.x + v.y*v.y);
  float nrm = fmaxf(sqrtf(ss), EPSV);
  float2 u; u.x = v.x/nrm; u.y = v.y/nrm;
  half2v uh = {(_Float16)u.x, (_Float16)u.y};
  *(half2v*)(relnH + (size_t)r*128 + lane*2) = uh;
  const float* ks[4] = {ae, ae+128, ar, ar+128};   // ent l0, ent l1, rel l0, rel l1
  #pragma unroll
  for(int k=0;k<4;k++){
    float2 w = *(const float2*)(ks[k] + lane*2);
    float d = waveRedSum(u.x*w.x + u.y*w.y);
    if(lane==0) expdot[k*R_REL + r] = __expf(d);
  }
}

// ---- fused dual-stack GAT layer: one pass does ent+rel Householder+softmax ----
__global__ __launch_bounds__(256) void k_edge2(const int* __restrict__ start, const int* __restrict__ scol,
      const int* __restrict__ srid, const _Float16* __restrict__ relnH,
      const float* __restrict__ expE, const float* __restrict__ expR,
      const _Float16* __restrict__ featIn, _Float16* featOut, _Float16* Eh, int colEnt, int colRel){
  int r = blockIdx.x*4 + (threadIdx.x>>6);
  int lane = threadIdx.x & 63;
  int s0 = start[r], s1 = start[r+1];
  float aEx=0,aEy=0,aRx=0,aRy=0, swE=0, swR=0;
  int e = s0;
  for(; e+1<s1; e+=2){
    int c0=scol[e], q0=srid[e], c1=scol[e+1], q1=srid[e+1];
    float wE0=expE[q0], wR0=expR[q0], wE1=expE[q1], wR1=expR[q1];
    half2v u0h = *(const half2v*)(relnH + (size_t)q0*128 + lane*2);
    half2v u1h = *(const half2v*)(relnH + (size_t)q1*128 + lane*2);
    half4v h0 = *(const half4v*)(featIn + (size_t)c0*256 + lane*4);
    half4v h1 = *(const half4v*)(featIn + (size_t)c1*256 + lane*4);
    float u0x=(float)u0h[0], u0y=(float)u0h[1], u1x=(float)u1h[0], u1y=(float)u1h[1];
    float e0x=(float)h0[0], e0y=(float)h0[1], r0x=(float)h0[2], r0y=(float)h0[3];
    float e1x=(float)h1[0], e1y=(float)h1[1], r1x=(float)h1[2], r1y=(float)h1[3];
    float d0 = e0x*u0x + e0y*u0y;   // ent dot edge0
    float d1 = r0x*u0x + r0y*u0y;   // rel dot edge0
    float d2 = e1x*u1x + e1y*u1y;   // ent dot edge1
    float d3 = r1x*u1x + r1y*u1y;   // rel dot edge1
    #pragma unroll
    for(int m=32;m>=1;m>>=1){
      d0 += __shfl_xor(d0,m,64); d1 += __shfl_xor(d1,m,64);
      d2 += __shfl_xor(d2,m,64); d3 += __shfl_xor(d3,m,64);
    }
    aEx += wE0*(e0x - 2.f*d0*u0x) + wE1*(e1x - 2.f*d2*u1x);
    aEy += wE0*(e0y - 2.f*d0*u0y) + wE1*(e1y - 2.f*d2*u1y);
    aRx += wR0*(r0x - 2.f*d1*u0x) + wR1*(r1x - 2.f*d3*u1x);
    aRy += wR0*(r0y - 2.f*d1*u0y) + wR1*(r1y - 2.f*d3*u1y);
    swE += wE0+wE1; swR += wR0+wR1;
  }
  if(e<s1){
    int c0=scol[e], q0=srid[e];
    float wE0=expE[q0], wR0=expR[q0];
    half2v u0h = *(const half2v*)(relnH + (size_t)q0*128 + lane*2);
    half4v h0 = *(const half4v*)(featIn + (size_t)c0*256 + lane*4);
    float u0x=(float)u0h[0], u0y=(float)u0h[1];
    float e0x=(float)h0[0], e0y=(float)h0[1], r0x=(float)h0[2], r0y=(float)h0[3];
    float d0 = e0x*u0x + e0y*u0y;
    float d1 = r0x*u0x + r0y*u0y;
    #pragma unroll
    for(int m=32;m>=1;m>>=1){ d0 += __shfl_xor(d0,m,64); d1 += __shfl_xor(d1,m,64); }
    aEx += wE0*(e0x - 2.f*d0*u0x);
    aEy += wE0*(e0y - 2.f*d0*u0y);
    aRx += wR0*(r0x - 2.f*d1*u0x);
    aRy += wR0*(r0y - 2.f*d1*u0y);
    swE += wE0; swR += wR0;
  }
  float iE = (s1>s0) ? 1.f/swE : 0.f;
  float iR = (s1>s0) ? 1.f/swR : 0.f;
  float vEx = fast_tanh(aEx*iE), vEy = fast_tanh(aEy*iE);
  float vRx = fast_tanh(aRx*iR), vRy = fast_tanh(aRy*iR);
  half4v ov = {(_Float16)vEx,(_Float16)vEy,(_Float16)vRx,(_Float16)vRy};
  *(half4v*)(featOut + (size_t)r*256 + lane*4) = ov;
  half2v he = {(_Float16)vEx,(_Float16)vEy};
  half2v hr = {(_Float16)vRx,(_Float16)vRy};
  *(half2v*)(Eh + (size_t)r*EMBD + colEnt + lane*2) = he;
  *(half2v*)(Eh + (size_t)r*EMBD + colRel + lane*2) = hr;
}

// ---- gather pair rows from Eh -> Wh fp16, cvec ----
__global__ __launch_bounds__(256) void k_gather(const _Float16* __restrict__ Eh, const int* __restrict__ tp,
                         _Float16* Wh, float* cvec){
  int i = blockIdx.x; int tid = threadIdx.x;
  int l = tp[2*i], r = tp[2*i+1];
  float sl=0.f, sr=0.f, sp=0.f;
  for(int c=tid;c<EMBD;c+=256){
    _Float16 lh = Eh[(size_t)l*EMBD+c], rh = Eh[(size_t)r*EMBD+c];
    float le = (float)lh, re = (float)rh;
    Wh[(size_t)i*EMBD+c]=lh; Wh[(size_t)(B_PAIR+i)*EMBD+c]=rh;
    sl += le*le; sr += re*re; float d = le-re; sp += d*d;
  }
  __shared__ float s0[256], s1[256], s2[256];
  s0[tid]=sl; s1[tid]=sr; s2[tid]=sp;
  __syncthreads();
  for(int w=128;w>0;w>>=1){
    if(tid<w){ s0[tid]+=s0[tid+w]; s1[tid]+=s1[tid+w]; s2[tid]+=s2[tid+w]; }
    __syncthreads();
  }
  if(tid==0){
    float pos = s2[0];
    cvec[i]        = pos + GAMMAF - s0[0];
    cvec[B_PAIR+i] = pos + GAMMAF - s1[0];
  }
}

// ---- q_j = ||e_j||^2 from Eh, wave per node ----
__global__ __launch_bounds__(256) void k_qn(const _Float16* __restrict__ Eh, float* qn){
  int j = (blockIdx.x*256 + threadIdx.x) >> 6;
  int lane = threadIdx.x & 63;
  if(j >= N_ENT) return;
  float s=0.f;
  #pragma unroll
  for(int q=0;q<12;q++){ float v = (float)Eh[(size_t)j*EMBD + lane + 64*q]; s += v*v; }
  s = waveRedSum(s);
  if(lane==0) qn[j]=s;
}

// ---- S = sum_j e_j, P = sum_j q_j e_j, Q = sum q, Q2 = sum q^2 ----
__global__ __launch_bounds__(256) void k_embstats(const _Float16* __restrict__ Eh, const float* __restrict__ qn,
                           float* Svec, float* Pvec, float* QQ){
  int tid = threadIdx.x;
  int n0 = blockIdx.x*128;
  int nend = n0+128; if(nend > N_ENT) nend = N_ENT;
  float s[3]={0,0,0}, p[3]={0,0,0};
  float q1=0.f, q2=0.f;
  for(int n=n0;n<nend;n++){
    float qv = qn[n];
    if(tid==0){ q1 += qv; q2 += qv*qv; }
    #pragma unroll
    for(int k=0;k<3;k++){
      float v = (float)Eh[(size_t)n*EMBD + tid + k*256];
      s[k] += v; p[k] += qv*v;
    }
  }
  #pragma unroll
  for(int k=0;k<3;k++){
    unsafeAtomicAdd(&Svec[tid + k*256], s[k]);
    unsafeAtomicAdd(&Pvec[tid + k*256], p[k]);
  }
  if(tid==0){ unsafeAtomicAdd(&QQ[0], q1); unsafeAtomicAdd(&QQ[1], q2); }
}

// ---- transpose Eh (30000x768) -> embT (768 x NPAD), zero-padded ----
__global__ __launch_bounds__(256) void k_transp(const _Float16* __restrict__ Eh, _Float16* embT){
  __shared__ __align__(16) _Float16 til[64][72];
  int r0 = blockIdx.x*64, c0 = blockIdx.y*64;
  int t = threadIdx.x;
  int rr = t>>3, c8 = (t&7)*8;
  #pragma unroll
  for(int p=0;p<2;p++){
    int gr = r0 + rr + p*32;
    uint4 v = make_uint4(0u,0u,0u,0u);
    if(gr < N_ENT) v = *(const uint4*)(Eh + (size_t)gr*EMBD + c0 + c8);
    *(uint4*)&til[rr + p*32][c8] = v;
  }
  __syncthreads();
  #pragma unroll
  for(int p=0;p<2;p++){
    int cc = rr + p*32;
    __align__(16) _Float16 tmp[8];
    #pragma unroll
    for(int j=0;j<8;j++) tmp[j] = til[c8 + j][cc];
    *(uint4*)(embT + (size_t)(c0+cc)*NPAD + r0 + c8) = *(uint4*)tmp;
  }
}

// ---- G = E^T E via f16 MFMA on embT; 128x128 tiles, split-K atomics ----
__global__ __launch_bounds__(256) void k_syrk(const _Float16* __restrict__ embT, float* G){
  __shared__ __align__(16) _Float16 As[128][72];
  __shared__ __align__(16) _Float16 Bs[128][72];
  int tid = threadIdx.x;
  int w = tid>>6, lane = tid&63;
  int quad = lane>>4, l15 = lane&15;
  int wm = (w>>1)*64, wn = (w&1)*64;
  int m0 = blockIdx.y*128, n0 = blockIdx.x*128;
  int kbeg = blockIdx.z*3776;
  int kend = kbeg + 3776; if(kend > NPAD) kend = NPAD;
  int srow = tid>>3, scol = (tid&7)*8;
  f32x4 acc[4][4];
  #pragma unroll
  for(int i=0;i<4;i++)
    #pragma unroll
    for(int j=0;j<4;j++) acc[i][j] = (f32x4){0.f,0.f,0.f,0.f};
  for(int k0=kbeg;k0<kend;k0+=64){
    #pragma unroll
    for(int p=0;p<4;p++){
      int r = srow + p*32;
      *(uint4*)&As[r][scol] = *(const uint4*)(embT + (size_t)(m0+r)*NPAD + k0 + scol);
      *(uint4*)&Bs[r][scol] = *(const uint4*)(embT + (size_t)(n0+r)*NPAD + k0 + scol);
    }
    __syncthreads();
    #pragma unroll
    for(int ks=0;ks<2;ks++){
      int kc = ks*32 + quad*8;
      half8 af[4], bf[4];
      #pragma unroll
      for(int i=0;i<4;i++) af[i] = *(half8*)&As[wm + i*16 + l15][kc];
      #pragma unroll
      for(int j=0;j<4;j++) bf[j] = *(half8*)&Bs[wn + j*16 + l15][kc];
      #pragma unroll
      for(int i=0;i<4;i++)
        #pragma unroll
        for(int j=0;j<4;j++)
          acc[i][j] = __builtin_amdgcn_mfma_f32_16x16x32_f16(af[i], bf[j], acc[i][j], 0,0,0);
    }
    __syncthreads();
  }
  #pragma unroll
  for(int i=0;i<4;i++){
    #pragma unroll
    for(int r=0;r<4;r++){
      int m = m0 + wm + i*16 + quad*4 + r;
      #pragma unroll
      for(int j=0;j<4;j++){
        int n = n0 + wn + j*16 + l15;
        unsafeAtomicAdd(&G[(size_t)m*EMBD + n], acc[i][j][r]);
      }
    }
  }
}

// ---- G fp32 -> fp16 ----
__global__ __launch_bounds__(256) void k_cvtG(const float* __restrict__ G, _Float16* Gh){
  int i = blockIdx.x*256 + threadIdx.x;
  if(i < EMBD*EMBD) Gh[i] = (_Float16)G[i];
}

// ================== no-LDS 64x64 MFMA mainloop over K=768, pipelined frag loads ==================
__device__ inline void mfma_k768(const _Float16* __restrict__ Asrc, const _Float16* __restrict__ Bsrc,
                                 int m0, int n0, int l15, int quad, f32x4 acc[4][4]){
  const _Float16* aB[4]; const _Float16* bB[4];
  #pragma unroll
  for(int i=0;i<4;i++){
    aB[i] = Asrc + (size_t)(m0+i*16+l15)*EMBD + quad*8;
    bB[i] = Bsrc + (size_t)(n0+i*16+l15)*EMBD + quad*8;
  }
  half8 af[2][4], bf[2][4];
  #pragma unroll
  for(int i=0;i<4;i++){ af[0][i] = *(const half8*)(aB[i]); bf[0][i] = *(const half8*)(bB[i]); }
  #pragma unroll
  for(int ks=0; ks<24; ks++){
    int cur = ks&1, nxt = cur^1;
    if(ks<23){
      int ko = (ks+1)*32;
      #pragma unroll
      for(int i=0;i<4;i++){ af[nxt][i] = *(const half8*)(aB[i]+ko); bf[nxt][i] = *(const half8*)(bB[i]+ko); }
    }
    #pragma unroll
    for(int i=0;i<4;i++)
      #pragma unroll
      for(int j=0;j<4;j++)
        acc[i][j] = __builtin_amdgcn_mfma_f32_16x16x32_f16(af[cur][i], bf[cur][j], acc[cur?i:i][j] = acc[i][j], 0,0,0);
  }
}

// ---- T = Wh * Gh (G symmetric), no-LDS MFMA ----
__global__ __launch_bounds__(256) void k_gemmTh(const _Float16* __restrict__ Wh, const _Float16* __restrict__ Gh,
                                                float* Tm){
  int tid = threadIdx.x, w = tid>>6, lane = tid&63;
  int quad = lane>>4, l15 = lane&15;
  int n0 = blockIdx.x*64;
  #pragma unroll
  for(int half=0; half<2; half++){
    int mt = blockIdx.y*8 + half*4 + w;
    int m0 = mt*64;
    f32x4 acc[4][4];
    #pragma unroll
    for(int i=0;i<4;i++)
      #pragma unroll
      for(int j=0;j<4;j++) acc[i][j] = (f32x4){0.f,0.f,0.f,0.f};
    mfma_k768(Wh, Gh, m0, n0, l15, quad, acc);
    #pragma unroll
    for(int i=0;i<4;i++)
      #pragma unroll
      for(int r=0;r<4;r++){
        int mg = m0 + i*16 + quad*4 + r;
        #pragma unroll
        for(int j=0;j<4;j++)
          Tm[(size_t)mg*EMBD + n0 + j*16 + l15] = acc[i][j][r];
      }
  }
}

// ---- per-row closed-form stats ----
__global__ __launch_bounds__(256) void k_rowstats(const _Float16* __restrict__ Wh, const float* __restrict__ Tm,
      const _Float16* __restrict__ Eh, const float* __restrict__ qn, const float* __restrict__ cvec,
      const int* __restrict__ tp, const float* __restrict__ Svec, const float* __restrict__ Pvec,
      const float* __restrict__ QQ, float* alpha, float* betav){
  int row = blockIdx.x*4 + (threadIdx.x>>6);
  int lane = threadIdx.x & 63;
  if(row >= 2*B_PAIR) return;
  int pi = row & (B_PAIR-1);
  int lp = tp[2*pi], rp = tp[2*pi+1];
  float d1=0,d2=0,d3=0,dl=0,dr=0;
  #pragma unroll
  for(int k=0;k<12;k++){
    int d = lane + 64*k;
    float a = (float)Wh[(size_t)row*EMBD + d];
    d1 += a*Svec[d];
    d2 += a*Pvec[d];
    d3 += a*Tm[(size_t)row*EMBD + d];
    dl += a*(float)Eh[(size_t)lp*EMBD + d];
    dr += a*(float)Eh[(size_t)rp*EMBD + d];
  }
  d1=waveRedSum(d1); d2=waveRedSum(d2); d3=waveRedSum(d3);
  dl=waveRedSum(dl); dr=waveRedSum(dr);
  if(lane==0){
    double c = (double)cvec[row], Q = (double)QQ[0], Q2 = (double)QQ[1], Nn = (double)N_ENT;
    double su  = Nn*c - Q + 2.0*(double)d1;
    double su2 = Nn*c*c - 2.0*c*Q + Q2 + 4.0*(c*(double)d1 - (double)d2) + 4.0*(double)d3;
    double ul = c - (double)qn[lp] + 2.0*(double)dl;
    double ur = c - (double)qn[rp] + 2.0*(double)dr;
    su -= ul + ur;
    if(lp != rp) su2 -= ul*ul + ur*ur;
    double mu = su/Nn;
    double var = su2/Nn - mu*mu;
    double sd = sqrt(fmax(var, 0.0));
    double al = 20.0/sd;
    alpha[row] = (float)al;
    betav[row] = (float)(8.0 - al*mu);
  }
}

__device__ inline void lseMerge(float& mx, float& sm, float om, float os){
  if(om > mx){ sm = sm*expf(mx-om) + os; mx = om; }
  else if(om != -INFINITY){ sm += os*expf(om-mx); }
}

// ---- pass B: no-LDS f16 MFMA + fused z/lse epilogue; grid (469 n-tiles, 4 m-blocks) ----
__global__ __launch_bounds__(256) void k_gemmB(const _Float16* __restrict__ Wh, const _Float16* __restrict__ Eh,
    const float* __restrict__ cvec, const float* __restrict__ qn, const int* __restrict__ tp,
    const float* __restrict__ alpha, const float* __restrict__ betav, float* pm, float* ps){
  int tid = threadIdx.x, w = tid>>6, lane = tid&63;
  int quad = lane>>4, l15 = lane&15;
  int n0 = blockIdx.x*64;
  float qv[4]; int jv[4];
  #pragma unroll
  for(int j=0;j<4;j++){ jv[j] = n0 + j*16 + l15; qv[j] = (jv[j]<N_ENT)? qn[jv[j]] : 0.f; }
  #pragma unroll
  for(int half=0; half<2; half++){
    int mt = blockIdx.y*8 + half*4 + w;
    int m0 = mt*64;
    f32x4 acc[4][4];
    #pragma unroll
    for(int i=0;i<4;i++)
      #pragma unroll
      for(int j=0;j<4;j++) acc[i][j] = (f32x4){0.f,0.f,0.f,0.f};
    mfma_k768(Wh, Eh, m0, n0, l15, quad, acc);
    #pragma unroll
    for(int i=0;i<4;i++){
      int mbase = m0 + i*16 + quad*4;
      #pragma unroll
      for(int r=0;r<4;r++){
        int mg = mbase + r;
        int pi = mg & (B_PAIR-1);
        int lp = tp[2*pi], rp = tp[2*pi+1];
        float cv = cvec[mg], al = alpha[mg], be = betav[mg];
        float mx = -INFINITY, sm = 0.f;
        #pragma unroll
        for(int j=0;j<4;j++){
          if(jv[j] < N_ENT){
            float mask = 1.0f - (float)(jv[j]==lp) - (float)(jv[j]==rp);
            float loss = (cv - qv[j] + 2.0f*acc[i][j][r]) * mask;
            float z = al*loss + be;
            if(z > mx){ sm = sm*__expf(mx - z) + 1.f; mx = z; }
            else sm += __expf(z - mx);
          }
        }
        #pragma unroll
        for(int m=8;m>=1;m>>=1){
          float om = __shfl_xor(mx, m, 64), os = __shfl_xor(sm, m, 64);
          lseMerge(mx, sm, om, os);
        }
        if(l15==0){ pm[(size_t)mg*GB_NT + blockIdx.x] = mx; ps[(size_t)mg*GB_NT + blockIdx.x] = sm; }
      }
    }
  }
}

// ---- combine per-tile LSE partials: block per row ----
__global__ __launch_bounds__(256) void k_lse(const float* __restrict__ pm, const float* __restrict__ ps, float* lse){
  __shared__ float shm[256], shs[256];
  int row = blockIdx.x, tid = threadIdx.x;
  float mx = -INFINITY, sm = 0.f;
  for(int t=tid;t<GB_NT;t+=256) lseMerge(mx, sm, pm[(size_t)row*GB_NT+t], ps[(size_t)row*GB_NT+t]);
  shm[tid]=mx; shs[tid]=sm;
  __syncthreads();
  for(int w=128;w>0;w>>=1){
    if(tid<w){
      float m2=shm[tid], s2=shs[tid];
      lseMerge(m2, s2, shm[tid+w], shs[tid+w]);
      shm[tid]=m2; shs[tid]=s2;
    }
    __syncthreads();
  }
  if(tid==0) lse[row] = shm[0] + logf(shs[0]);
}

// ---- final mean ----
__global__ __launch_bounds__(256) void k_final(const float* __restrict__ lse, float* out){
  __shared__ double sh[256];
  int tid = threadIdx.x;
  double s = 0.0;
  for(int i=tid;i<B_PAIR;i+=256) s += (double)lse[i] + (double)lse[B_PAIR+i];
  sh[tid]=s; __syncthreads();
  for(int w=128;w>0;w>>=1){ if(tid<w) sh[tid]+=sh[tid+w]; __syncthreads(); }
  if(tid==0) out[0] = (float)(sh[0] / (double)B_PAIR);
}

extern "C" void kernel_launch(void* const* d_in, const int* in_sizes, int n_in,
                              void* d_out, int out_size, void* d_ws, size_t ws_size,
                              hipStream_t stream) {
  const float* ent_emb = (const float*)d_in[0];
  const float* rel_emb = (const float*)d_in[1];
  const float* attn_e  = (const float*)d_in[2];
  const float* attn_r  = (const float*)d_in[3];
  const int* adj     = (const int*)d_in[5];
  const int* r_index = (const int*)d_in[6];
  const int* ent_adj = (const int*)d_in[7];
  const int* rel_adj = (const int*)d_in[8];
  const int* tp      = (const int*)d_in[9];
  float* out = (float*)d_out;

  const int* adj_row = adj;
  const int* adj_col = adj + T_EDGE;
  const int* rid1    = r_index + T_EDGE;

  char* base = (char*)d_ws;
  size_t off = 0;
  auto A = [&](size_t b)->void*{ void* p = base + off; off = (off + b + 255) & ~(size_t)255; return p; };
  // zero region
  int*   cntA  = (int*)  A((size_t)N_ENT*4);
  int*   cntE  = (int*)  A((size_t)N_ENT*4);
  int*   cntR  = (int*)  A((size_t)N_ENT*4);
  float* G     = (float*)A((size_t)EMBD*EMBD*4);
  float* Svec  = (float*)A(EMBD*4);
  float* Pvec  = (float*)A(EMBD*4);
  float* QQ    = (float*)A(2*4);
  size_t zero_end = off;
  // plain buffers
  int* startA = (int*)A((size_t)(N_ENT+1)*4);
  int* startE = (int*)A((size_t)(N_ENT+1)*4);
  int* startR = (int*)A((size_t)(N_ENT+1)*4);
  int* curA   = (int*)A((size_t)N_ENT*4);
  int* curE   = (int*)A((size_t)N_ENT*4);
  int* curR   = (int*)A((size_t)N_ENT*4);
  int* scolA  = (int*)A((size_t)T_EDGE*4);
  int* sridA  = (int*)A((size_t)T_EDGE*4);
  int* scolE  = (int*)A((size_t)NNZ_E*4);
  int* scolR  = (int*)A((size_t)NNZ_E*4);
  _Float16* Eh = (_Float16*)A((size_t)NPAD*EMBD*2);   // padded rows zeroed below
  // region X: phase-aliased (featC0/featC1 -> embT -> pm/ps)
  char* X = (char*)A((size_t)EMBD*NPAD*2);   // 46.1 MB
  _Float16* featC0 = (_Float16*)X;                       // 15.4 MB
  _Float16* featC1 = (_Float16*)(X + 16u*1024u*1024u);   // 15.4 MB
  _Float16* embT   = (_Float16*)X;
  float*    pm     = (float*)X;
  float*    ps     = (float*)(X + 8u*1024u*1024u);
  _Float16* relnH  = (_Float16*)A((size_t)R_REL*128*2);
  float* expdot  = (float*)A(4*R_REL*4);
  _Float16* Wh   = (_Float16*)A((size_t)2*B_PAIR*EMBD*2);
  _Float16* Gh   = (_Float16*)A((size_t)EMBD*EMBD*2);
  float* Tm      = (float*)A((size_t)2*B_PAIR*EMBD*4);
  float* cvec    = (float*)A(2*B_PAIR*4);
  float* qn      = (float*)A((size_t)N_ENT*4);
  float* alpha   = (float*)A(2*B_PAIR*4);
  float* betav   = (float*)A(2*B_PAIR*4);
  float* lse     = (float*)A(2*B_PAIR*4);
  (void)ws_size; (void)in_sizes; (void)n_in; (void)out_size;

  hipMemsetAsync(d_ws, 0, zero_end, stream);
  hipMemsetAsync(Eh + (size_t)N_ENT*EMBD, 0, (size_t)(NPAD-N_ENT)*EMBD*2, stream);

  // ---- CSR builds ----
  k_count<<<(T_EDGE+255)/256, 256, 0, stream>>>(adj_row, cntA, T_EDGE);
  k_count<<<(NNZ_E+255)/256, 256, 0, stream>>>(ent_adj, cntE, NNZ_E);
  k_count<<<(NNZ_E+255)/256, 256, 0, stream>>>(rel_adj, cntR, NNZ_E);
  k_scan3<<<3, 1024, 0, stream>>>(cntA, startA, curA, cntE, startE, curE, cntR, startR, curR);
  k_scatter<<<(T_EDGE+255)/256, 256, 0, stream>>>(adj_row, adj_col, rid1, curA, scolA, sridA, T_EDGE);
  k_scatter<<<(NNZ_E+255)/256, 256, 0, stream>>>(ent_adj, ent_adj+NNZ_E, nullptr, curE, scolE, nullptr, NNZ_E);
  k_scatter<<<(NNZ_E+255)/256, 256, 0, stream>>>(rel_adj, rel_adj+NNZ_E, nullptr, curR, scolR, nullptr, NNZ_E);

  k_relnorm<<<R_REL/4, 256, 0, stream>>>(rel_emb, attn_e, attn_r, relnH, expdot);

  // ---- fused dual GAT stack: avg (ent|rel) -> layer0 -> layer1 ----
  k_avg_tanh<<<N_ENT/4, 256, 0, stream>>>(startE, scolE, ent_emb, featC0, Eh, 0, 0);
  k_avg_tanh<<<N_ENT/4, 256, 0, stream>>>(startR, scolR, rel_emb, featC0, Eh, 2, 384);
  k_edge2<<<N_ENT/4, 256, 0, stream>>>(startA, scolA, sridA, relnH, expdot + 0*R_REL, expdot + 2*R_REL,
                                       featC0, featC1, Eh, 128, 512);
  k_edge2<<<N_ENT/4, 256, 0, stream>>>(startA, scolA, sridA, relnH, expdot + 1*R_REL, expdot + 3*R_REL,
                                       featC1, featC0, Eh, 256, 640);

  // ---- align loss ----
  k_gather<<<B_PAIR, 256, 0, stream>>>(Eh, tp, Wh, cvec);
  k_qn<<<N_ENT/4, 256, 0, stream>>>(Eh, qn);
  k_embstats<<<(N_ENT+127)/128, 256, 0, stream>>>(Eh, qn, Svec, Pvec, QQ);
  dim3 gtr(469, 12);
  k_transp<<<gtr, 256, 0, stream>>>(Eh, embT);
  dim3 gsy(6, 6, 8);
  k_syrk<<<gsy, 256, 0, stream>>>(embT, G);
  k_cvtG<<<(EMBD*EMBD+255)/256, 256, 0, stream>>>(G, Gh);
  dim3 gT(EMBD/64, 4);
  k_gemmTh<<<gT, 256, 0, stream>>>(Wh, Gh, Tm);
  k_rowstats<<<2*B_PAIR/4, 256, 0, stream>>>(Wh, Tm, Eh, qn, cvec, tp, Svec, Pvec, QQ, alpha, betav);
  dim3 gg(GB_NT, 4);
  k_gemmB<<<gg, 256, 0, stream>>>(Wh, Eh, cvec, qn, tp, alpha, betav, pm, ps);
  k_lse<<<2*B_PAIR, 256, 0, stream>>>(pm, ps, lse);
  k_final<<<1, 256, 0, stream>>>(lse, out);
}

// Round 6
// 963.410 us; speedup vs baseline: 5.2033x; 1.1463x over previous
//
#include <hip/hip_runtime.h>
#include <math.h>

#define N_ENT 30000
#define R_REL 1000
#define T_EDGE 300000
#define B_PAIR 1024
#define NNZ_E 600000
#define GAMMAF 3.0f
#define EPSV 1e-12f
#define EMBD 768
#define NPAD 30080           // N_ENT padded to 128 (zeroed pad rows in Eh)
#define NT128 235            // n-tiles of 128 for gemmB
#define PTILES 470           // lse partial tiles per row (2 per 128-tile)

typedef _Float16 half8 __attribute__((ext_vector_type(8)));
typedef _Float16 half4v __attribute__((ext_vector_type(4)));
typedef _Float16 half2v __attribute__((ext_vector_type(2)));
typedef float f32x4 __attribute__((ext_vector_type(4)));

__device__ inline void gl_lds16(const _Float16* g, _Float16* l){
  __builtin_amdgcn_global_load_lds(
      (const __attribute__((address_space(1))) unsigned int*)g,
      (__attribute__((address_space(3))) unsigned int*)l, 16, 0, 0);
}

__device__ inline float waveRedSum(float v){
  #pragma unroll
  for(int m=32;m>=1;m>>=1) v += __shfl_xor(v, m, 64);
  return v;
}

__device__ inline float fast_tanh(float x){
  x = fminf(10.f, fmaxf(-10.f, x));
  float e = __expf(2.f*x);
  return (e-1.f)/(e+1.f);
}

// ---- edge-count: all three lists in one launch ----
__global__ __launch_bounds__(256) void k_count3(const int* __restrict__ rA, int* cA,
                                                const int* __restrict__ rE, int* cE,
                                                const int* __restrict__ rR, int* cR){
  int e = blockIdx.x*256 + threadIdx.x;
  if(e < T_EDGE) atomicAdd(&cA[rA[e]], 1);
  if(e < NNZ_E){ atomicAdd(&cE[rE[e]], 1); atomicAdd(&cR[rR[e]], 1); }
}

// ---- 3 exclusive scans in one launch (block per list), wave-level scan ----
__global__ __launch_bounds__(1024) void k_scan3(const int* c0, int* s0, int* u0,
                                                const int* c1, int* s1, int* u1,
                                                const int* c2, int* s2, int* u2){
  const int* cnt = blockIdx.x==0 ? c0 : (blockIdx.x==1 ? c1 : c2);
  int* start     = blockIdx.x==0 ? s0 : (blockIdx.x==1 ? s1 : s2);
  int* cursor    = blockIdx.x==0 ? u0 : (blockIdx.x==1 ? u1 : u2);
  __shared__ int wsum[16];
  __shared__ int carry;
  int tid = threadIdx.x, lane = tid & 63, wid = tid >> 6;
  if(tid==0) carry = 0;
  __syncthreads();
  for(int base=0; base<N_ENT; base+=1024){
    int i = base + tid;
    int v = (i<N_ENT)? cnt[i] : 0;
    int x = v;
    #pragma unroll
    for(int off=1; off<64; off<<=1){ int t=__shfl_up(x,off,64); if(lane>=off) x+=t; }
    if(lane==63) wsum[wid]=x;
    __syncthreads();
    if(wid==0){
      int s = (lane<16)? wsum[lane] : 0;
      #pragma unroll
      for(int off=1; off<16; off<<=1){ int t=__shfl_up(s,off,64); if(lane>=off) s+=t; }
      if(lane<16) wsum[lane]=s;
    }
    __syncthreads();
    int wexcl = (wid==0)? 0 : wsum[wid-1];
    int excl = carry + wexcl + x - v;
    if(i<N_ENT){ start[i]=excl; cursor[i]=excl; }
    int tot = wsum[15];
    __syncthreads();
    if(tid==0) carry += tot;
    __syncthreads();
  }
  if(tid==0) start[N_ENT] = carry;
}

// ---- scatter all three edge lists into CSR order, one launch ----
__global__ __launch_bounds__(256) void k_scatter3(
      const int* __restrict__ rA, const int* __restrict__ cAj, const int* __restrict__ rid,
      int* uA, int* scolA, int* sridA,
      const int* __restrict__ rE, const int* __restrict__ cEj, int* uE, int* scolE,
      const int* __restrict__ rR, const int* __restrict__ cRj, int* uR, int* scolR){
  int e = blockIdx.x*256 + threadIdx.x;
  if(e < T_EDGE){
    int p = atomicAdd(&uA[rA[e]], 1);
    scolA[p] = cAj[e];
    sridA[p] = rid[e];
  }
  if(e < NNZ_E){
    int p = atomicAdd(&uE[rE[e]], 1);
    scolE[p] = cEj[e];
    int q = atomicAdd(&uR[rR[e]], 1);
    scolR[q] = cRj[e];
  }
}

// ---- _avg via CSR gather, fused tanh; writes interleaved fp16 featC + Eh slice ----
__global__ __launch_bounds__(256) void k_avg_tanh(const int* __restrict__ start, const int* __restrict__ scol,
                        const float* __restrict__ src, _Float16* featC, _Float16* Eh, int pairOff, int coloff){
  int r = blockIdx.x*4 + (threadIdx.x>>6);
  int lane = threadIdx.x & 63;
  int s0 = start[r], s1 = start[r+1];
  float ax=0.f, ay=0.f;
  int e = s0;
  for(; e+1<s1; e+=2){
    int c0 = scol[e], c1 = scol[e+1];
    float2 v0 = *(const float2*)(src + (size_t)c0*128 + lane*2);
    float2 v1 = *(const float2*)(src + (size_t)c1*128 + lane*2);
    ax += v0.x + v1.x; ay += v0.y + v1.y;
  }
  if(e<s1){
    int c0 = scol[e];
    float2 v0 = *(const float2*)(src + (size_t)c0*128 + lane*2);
    ax += v0.x; ay += v0.y;
  }
  float inv = (s1>s0) ? 1.0f/(float)(s1-s0) : 0.f;
  float vx = fast_tanh(ax*inv), vy = fast_tanh(ay*inv);
  half2v hv = {(_Float16)vx, (_Float16)vy};
  *(half2v*)(featC + (size_t)r*256 + lane*4 + pairOff) = hv;
  *(half2v*)(Eh + (size_t)r*EMBD + coloff + lane*2) = hv;
}

// ---- normalized relation table (fp16) + exp(attention-dot) tables ----
__global__ __launch_bounds__(256) void k_relnorm(const float* __restrict__ rel, const float* __restrict__ ae,
                          const float* __restrict__ ar, _Float16* relnH, float* expdot){
  int r = (blockIdx.x*256 + threadIdx.x) >> 6;
  int lane = threadIdx.x & 63;
  if (r >= R_REL) return;
  float2 v = *(const float2*)(rel + (size_t)r*128 + lane*2);
  float ss = waveRedSum(v.x*v.x + v.y*v.y);
  float nrm = fmaxf(sqrtf(ss), EPSV);
  float2 u; u.x = v.x/nrm; u.y = v.y/nrm;
  half2v uh = {(_Float16)u.x, (_Float16)u.y};
  *(half2v*)(relnH + (size_t)r*128 + lane*2) = uh;
  const float* ks[4] = {ae, ae+128, ar, ar+128};   // ent l0, ent l1, rel l0, rel l1
  #pragma unroll
  for(int k=0;k<4;k++){
    float2 w = *(const float2*)(ks[k] + lane*2);
    float d = waveRedSum(u.x*w.x + u.y*w.y);
    if(lane==0) expdot[k*R_REL + r] = __expf(d);
  }
}

// ---- fused dual-stack GAT layer: one pass does ent+rel Householder+softmax ----
__global__ __launch_bounds__(256) void k_edge2(const int* __restrict__ start, const int* __restrict__ scol,
      const int* __restrict__ srid, const _Float16* __restrict__ relnH,
      const float* __restrict__ expE, const float* __restrict__ expR,
      const _Float16* __restrict__ featIn, _Float16* featOut, _Float16* Eh, int colEnt, int colRel){
  int r = blockIdx.x*4 + (threadIdx.x>>6);
  int lane = threadIdx.x & 63;
  int s0 = start[r], s1 = start[r+1];
  float aEx=0,aEy=0,aRx=0,aRy=0, swE=0, swR=0;
  int e = s0;
  for(; e+1<s1; e+=2){
    int c0=scol[e], q0=srid[e], c1=scol[e+1], q1=srid[e+1];
    float wE0=expE[q0], wR0=expR[q0], wE1=expE[q1], wR1=expR[q1];
    half2v u0h = *(const half2v*)(relnH + (size_t)q0*128 + lane*2);
    half2v u1h = *(const half2v*)(relnH + (size_t)q1*128 + lane*2);
    half4v h0 = *(const half4v*)(featIn + (size_t)c0*256 + lane*4);
    half4v h1 = *(const half4v*)(featIn + (size_t)c1*256 + lane*4);
    float u0x=(float)u0h[0], u0y=(float)u0h[1], u1x=(float)u1h[0], u1y=(float)u1h[1];
    float e0x=(float)h0[0], e0y=(float)h0[1], r0x=(float)h0[2], r0y=(float)h0[3];
    float e1x=(float)h1[0], e1y=(float)h1[1], r1x=(float)h1[2], r1y=(float)h1[3];
    float d0 = e0x*u0x + e0y*u0y;
    float d1 = r0x*u0x + r0y*u0y;
    float d2 = e1x*u1x + e1y*u1y;
    float d3 = r1x*u1x + r1y*u1y;
    #pragma unroll
    for(int m=32;m>=1;m>>=1){
      d0 += __shfl_xor(d0,m,64); d1 += __shfl_xor(d1,m,64);
      d2 += __shfl_xor(d2,m,64); d3 += __shfl_xor(d3,m,64);
    }
    aEx += wE0*(e0x - 2.f*d0*u0x) + wE1*(e1x - 2.f*d2*u1x);
    aEy += wE0*(e0y - 2.f*d0*u0y) + wE1*(e1y - 2.f*d2*u1y);
    aRx += wR0*(r0x - 2.f*d1*u0x) + wR1*(r1x - 2.f*d3*u1x);
    aRy += wR0*(r0y - 2.f*d1*u0y) + wR1*(r1y - 2.f*d3*u1y);
    swE += wE0+wE1; swR += wR0+wR1;
  }
  if(e<s1){
    int c0=scol[e], q0=srid[e];
    float wE0=expE[q0], wR0=expR[q0];
    half2v u0h = *(const half2v*)(relnH + (size_t)q0*128 + lane*2);
    half4v h0 = *(const half4v*)(featIn + (size_t)c0*256 + lane*4);
    float u0x=(float)u0h[0], u0y=(float)u0h[1];
    float e0x=(float)h0[0], e0y=(float)h0[1], r0x=(float)h0[2], r0y=(float)h0[3];
    float d0 = e0x*u0x + e0y*u0y;
    float d1 = r0x*u0x + r0y*u0y;
    #pragma unroll
    for(int m=32;m>=1;m>>=1){ d0 += __shfl_xor(d0,m,64); d1 += __shfl_xor(d1,m,64); }
    aEx += wE0*(e0x - 2.f*d0*u0x);
    aEy += wE0*(e0y - 2.f*d0*u0y);
    aRx += wR0*(r0x - 2.f*d1*u0x);
    aRy += wR0*(r0y - 2.f*d1*u0y);
    swE += wE0; swR += wR0;
  }
  float iE = (s1>s0) ? 1.f/swE : 0.f;
  float iR = (s1>s0) ? 1.f/swR : 0.f;
  float vEx = fast_tanh(aEx*iE), vEy = fast_tanh(aEy*iE);
  float vRx = fast_tanh(aRx*iR), vRy = fast_tanh(aRy*iR);
  half4v ov = {(_Float16)vEx,(_Float16)vEy,(_Float16)vRx,(_Float16)vRy};
  *(half4v*)(featOut + (size_t)r*256 + lane*4) = ov;
  half2v he = {(_Float16)vEx,(_Float16)vEy};
  half2v hr = {(_Float16)vRx,(_Float16)vRy};
  *(half2v*)(Eh + (size_t)r*EMBD + colEnt + lane*2) = he;
  *(half2v*)(Eh + (size_t)r*EMBD + colRel + lane*2) = hr;
}

// ---- gather pair rows from Eh -> Wh fp16, cvec ----
__global__ __launch_bounds__(256) void k_gather(const _Float16* __restrict__ Eh, const int* __restrict__ tp,
                         _Float16* Wh, float* cvec){
  int i = blockIdx.x; int tid = threadIdx.x;
  int l = tp[2*i], r = tp[2*i+1];
  float sl=0.f, sr=0.f, sp=0.f;
  for(int c=tid;c<EMBD;c+=256){
    _Float16 lh = Eh[(size_t)l*EMBD+c], rh = Eh[(size_t)r*EMBD+c];
    float le = (float)lh, re = (float)rh;
    Wh[(size_t)i*EMBD+c]=lh; Wh[(size_t)(B_PAIR+i)*EMBD+c]=rh;
    sl += le*le; sr += re*re; float d = le-re; sp += d*d;
  }
  __shared__ float s0[256], s1[256], s2[256];
  s0[tid]=sl; s1[tid]=sr; s2[tid]=sp;
  __syncthreads();
  for(int w=128;w>0;w>>=1){
    if(tid<w){ s0[tid]+=s0[tid+w]; s1[tid]+=s1[tid+w]; s2[tid]+=s2[tid+w]; }
    __syncthreads();
  }
  if(tid==0){
    float pos = s2[0];
    cvec[i]        = pos + GAMMAF - s0[0];
    cvec[B_PAIR+i] = pos + GAMMAF - s1[0];
  }
}

// ---- q_j = ||e_j||^2 from Eh, wave per node ----
__global__ __launch_bounds__(256) void k_qn(const _Float16* __restrict__ Eh, float* qn){
  int j = (blockIdx.x*256 + threadIdx.x) >> 6;
  int lane = threadIdx.x & 63;
  if(j >= N_ENT) return;
  float s=0.f;
  #pragma unroll
  for(int q=0;q<12;q++){ float v = (float)Eh[(size_t)j*EMBD + lane + 64*q]; s += v*v; }
  s = waveRedSum(s);
  if(lane==0) qn[j]=s;
}

// ---- S = sum_j e_j, P = sum_j q_j e_j, Q = sum q, Q2 = sum q^2 ----
__global__ __launch_bounds__(256) void k_embstats(const _Float16* __restrict__ Eh, const float* __restrict__ qn,
                           float* Svec, float* Pvec, float* QQ){
  int tid = threadIdx.x;
  int n0 = blockIdx.x*128;
  int nend = n0+128; if(nend > N_ENT) nend = N_ENT;
  float s[3]={0,0,0}, p[3]={0,0,0};
  float q1=0.f, q2=0.f;
  for(int n=n0;n<nend;n++){
    float qv = qn[n];
    if(tid==0){ q1 += qv; q2 += qv*qv; }
    #pragma unroll
    for(int k=0;k<3;k++){
      float v = (float)Eh[(size_t)n*EMBD + tid + k*256];
      s[k] += v; p[k] += qv*v;
    }
  }
  #pragma unroll
  for(int k=0;k<3;k++){
    unsafeAtomicAdd(&Svec[tid + k*256], s[k]);
    unsafeAtomicAdd(&Pvec[tid + k*256], p[k]);
  }
  if(tid==0){ unsafeAtomicAdd(&QQ[0], q1); unsafeAtomicAdd(&QQ[1], q2); }
}

// ---- transpose Eh (30000x768) -> embT (768 x NPAD), zero-padded ----
__global__ __launch_bounds__(256) void k_transp(const _Float16* __restrict__ Eh, _Float16* embT){
  __shared__ __align__(16) _Float16 til[64][72];
  int r0 = blockIdx.x*64, c0 = blockIdx.y*64;
  int t = threadIdx.x;
  int rr = t>>3, c8 = (t&7)*8;
  #pragma unroll
  for(int p=0;p<2;p++){
    int gr = r0 + rr + p*32;
    uint4 v = make_uint4(0u,0u,0u,0u);
    if(gr < N_ENT) v = *(const uint4*)(Eh + (size_t)gr*EMBD + c0 + c8);
    *(uint4*)&til[rr + p*32][c8] = v;
  }
  __syncthreads();
  #pragma unroll
  for(int p=0;p<2;p++){
    int cc = rr + p*32;
    __align__(16) _Float16 tmp[8];
    #pragma unroll
    for(int j=0;j<8;j++) tmp[j] = til[c8 + j][cc];
    *(uint4*)(embT + (size_t)(c0+cc)*NPAD + r0 + c8) = *(uint4*)tmp;
  }
}

// ---- G = E^T E via f16 MFMA on embT; 128x128 tiles, DMA staging + XOR swizzle, split-K atomics ----
__global__ __launch_bounds__(256) void k_syrk(const _Float16* __restrict__ embT, float* G){
  __shared__ __align__(16) _Float16 As[128*64];
  __shared__ __align__(16) _Float16 Bs[128*64];
  int tid = threadIdx.x;
  int w = tid>>6, lane = tid&63;
  int quad = lane>>4, l15 = lane&15;
  int lr = lane>>3, lc = lane&7;
  int wm = (w>>1)*64, wn = (w&1)*64;
  int m0 = blockIdx.y*128, n0 = blockIdx.x*128;
  int kbeg = blockIdx.z*3776;
  int kend = kbeg + 3776; if(kend > NPAD) kend = NPAD;
  f32x4 acc[4][4];
  #pragma unroll
  for(int i=0;i<4;i++)
    #pragma unroll
    for(int j=0;j<4;j++) acc[i][j] = (f32x4){0.f,0.f,0.f,0.f};
  for(int k0=kbeg;k0<kend;k0+=64){
    #pragma unroll
    for(int p=0;p<4;p++){
      int r = p*32 + w*8 + lr;
      int cg = lc ^ (r&7);
      gl_lds16(embT + (size_t)(m0+r)*NPAD + k0 + cg*8, As + (p*32 + w*8)*64);
      gl_lds16(embT + (size_t)(n0+r)*NPAD + k0 + cg*8, Bs + (p*32 + w*8)*64);
    }
    __syncthreads();
    #pragma unroll
    for(int ks=0;ks<2;ks++){
      half8 af[4], bf[4];
      #pragma unroll
      for(int i=0;i<4;i++){
        int ml = wm + i*16 + l15;
        af[i] = *(half8*)(As + ml*64 + (((ks<<2)|quad) ^ (ml&7))*8);
      }
      #pragma unroll
      for(int j=0;j<4;j++){
        int nl = wn + j*16 + l15;
        bf[j] = *(half8*)(Bs + nl*64 + (((ks<<2)|quad) ^ (nl&7))*8);
      }
      #pragma unroll
      for(int i=0;i<4;i++)
        #pragma unroll
        for(int j=0;j<4;j++)
          acc[i][j] = __builtin_amdgcn_mfma_f32_16x16x32_f16(af[i], bf[j], acc[i][j], 0,0,0);
    }
    __syncthreads();
  }
  #pragma unroll
  for(int i=0;i<4;i++){
    #pragma unroll
    for(int r=0;r<4;r++){
      int m = m0 + wm + i*16 + quad*4 + r;
      #pragma unroll
      for(int j=0;j<4;j++){
        int n = n0 + wn + j*16 + l15;
        unsafeAtomicAdd(&G[(size_t)m*EMBD + n], acc[i][j][r]);
      }
    }
  }
}

// ---- G fp32 -> fp16 ----
__global__ __launch_bounds__(256) void k_cvtG(const float* __restrict__ G, _Float16* Gh){
  int i = blockIdx.x*256 + threadIdx.x;
  if(i < EMBD*EMBD) Gh[i] = (_Float16)G[i];
}

// ================== no-LDS 64x64 MFMA mainloop over K=768 (small GEMM only) ==================
__device__ inline void mfma_k768(const _Float16* __restrict__ Asrc, const _Float16* __restrict__ Bsrc,
                                 int m0, int n0, int l15, int quad, f32x4 acc[4][4]){
  const _Float16* aB[4]; const _Float16* bB[4];
  #pragma unroll
  for(int i=0;i<4;i++){
    aB[i] = Asrc + (size_t)(m0+i*16+l15)*EMBD + quad*8;
    bB[i] = Bsrc + (size_t)(n0+i*16+l15)*EMBD + quad*8;
  }
  half8 af[2][4], bf[2][4];
  #pragma unroll
  for(int i=0;i<4;i++){ af[0][i] = *(const half8*)(aB[i]); bf[0][i] = *(const half8*)(bB[i]); }
  #pragma unroll
  for(int ks=0; ks<24; ks++){
    int cur = ks&1, nxt = cur^1;
    if(ks<23){
      int ko = (ks+1)*32;
      #pragma unroll
      for(int i=0;i<4;i++){ af[nxt][i] = *(const half8*)(aB[i]+ko); bf[nxt][i] = *(const half8*)(bB[i]+ko); }
    }
    #pragma unroll
    for(int i=0;i<4;i++)
      #pragma unroll
      for(int j=0;j<4;j++)
        acc[i][j] = __builtin_amdgcn_mfma_f32_16x16x32_f16(af[cur][i], bf[cur][j], acc[i][j], 0,0,0);
  }
}

// ---- T = Wh * Gh (G symmetric), no-LDS MFMA ----
__global__ __launch_bounds__(256) void k_gemmTh(const _Float16* __restrict__ Wh, const _Float16* __restrict__ Gh,
                                                float* Tm){
  int tid = threadIdx.x, w = tid>>6, lane = tid&63;
  int quad = lane>>4, l15 = lane&15;
  int n0 = blockIdx.x*64;
  #pragma unroll
  for(int half=0; half<2; half++){
    int mt = blockIdx.y*8 + half*4 + w;
    int m0 = mt*64;
    f32x4 acc[4][4];
    #pragma unroll
    for(int i=0;i<4;i++)
      #pragma unroll
      for(int j=0;j<4;j++) acc[i][j] = (f32x4){0.f,0.f,0.f,0.f};
    mfma_k768(Wh, Gh, m0, n0, l15, quad, acc);
    #pragma unroll
    for(int i=0;i<4;i++)
      #pragma unroll
      for(int r=0;r<4;r++){
        int mg = m0 + i*16 + quad*4 + r;
        #pragma unroll
        for(int j=0;j<4;j++)
          Tm[(size_t)mg*EMBD + n0 + j*16 + l15] = acc[i][j][r];
      }
  }
}

// ---- per-row closed-form stats ----
__global__ __launch_bounds__(256) void k_rowstats(const _Float16* __restrict__ Wh, const float* __restrict__ Tm,
      const _Float16* __restrict__ Eh, const float* __restrict__ qn, const float* __restrict__ cvec,
      const int* __restrict__ tp, const float* __restrict__ Svec, const float* __restrict__ Pvec,
      const float* __restrict__ QQ, float* alpha, float* betav){
  int row = blockIdx.x*4 + (threadIdx.x>>6);
  int lane = threadIdx.x & 63;
  if(row >= 2*B_PAIR) return;
  int pi = row & (B_PAIR-1);
  int lp = tp[2*pi], rp = tp[2*pi+1];
  float d1=0,d2=0,d3=0,dl=0,dr=0;
  #pragma unroll
  for(int k=0;k<12;k++){
    int d = lane + 64*k;
    float a = (float)Wh[(size_t)row*EMBD + d];
    d1 += a*Svec[d];
    d2 += a*Pvec[d];
    d3 += a*Tm[(size_t)row*EMBD + d];
    dl += a*(float)Eh[(size_t)lp*EMBD + d];
    dr += a*(float)Eh[(size_t)rp*EMBD + d];
  }
  d1=waveRedSum(d1); d2=waveRedSum(d2); d3=waveRedSum(d3);
  dl=waveRedSum(dl); dr=waveRedSum(dr);
  if(lane==0){
    double c = (double)cvec[row], Q = (double)QQ[0], Q2 = (double)QQ[1], Nn = (double)N_ENT;
    double su  = Nn*c - Q + 2.0*(double)d1;
    double su2 = Nn*c*c - 2.0*c*Q + Q2 + 4.0*(c*(double)d1 - (double)d2) + 4.0*(double)d3;
    double ul = c - (double)qn[lp] + 2.0*(double)dl;
    double ur = c - (double)qn[rp] + 2.0*(double)dr;
    su -= ul + ur;
    if(lp != rp) su2 -= ul*ul + ur*ur;
    double mu = su/Nn;
    double var = su2/Nn - mu*mu;
    double sd = sqrt(fmax(var, 0.0));
    double al = 20.0/sd;
    alpha[row] = (float)al;
    betav[row] = (float)(8.0 - al*mu);
  }
}

__device__ inline void lseMerge(float& mx, float& sm, float om, float os){
  if(om > mx){ sm = sm*expf(mx-om) + os; mx = om; }
  else if(om != -INFINITY){ sm += os*expf(om-mx); }
}

// ---- pass B: m97-style 128x128 f16 MFMA (DMA staging + XOR swizzle) + fused z/lse epilogue ----
//      grid (235 n-tiles, 16 m-tiles); 4 waves of 64x64; 2 lse partial tiles per block-col
__global__ __launch_bounds__(256) void k_gemmB(const _Float16* __restrict__ Wh, const _Float16* __restrict__ Eh,
    const float* __restrict__ cvec, const float* __restrict__ qn, const int* __restrict__ tp,
    const float* __restrict__ alpha, const float* __restrict__ betav, float* pm, float* ps){
  __shared__ __align__(16) _Float16 As[128*64];
  __shared__ __align__(16) _Float16 Bs[128*64];
  int tid = threadIdx.x;
  int w = tid>>6, lane = tid&63;
  int quad = lane>>4, l15 = lane&15;
  int lr = lane>>3, lc = lane&7;
  int wm = (w&1)*64, wn = (w>>1)*64;
  int m0 = blockIdx.y*128, n0 = blockIdx.x*128;
  f32x4 acc[4][4];
  #pragma unroll
  for(int i=0;i<4;i++)
    #pragma unroll
    for(int j=0;j<4;j++) acc[i][j] = (f32x4){0.f,0.f,0.f,0.f};
  for(int k0=0;k0<EMBD;k0+=64){
    #pragma unroll
    for(int p=0;p<4;p++){
      int r = p*32 + w*8 + lr;
      int cg = lc ^ (r&7);
      gl_lds16(Wh + (size_t)(m0+r)*EMBD + k0 + cg*8, As + (p*32 + w*8)*64);
      gl_lds16(Eh + (size_t)(n0+r)*EMBD + k0 + cg*8, Bs + (p*32 + w*8)*64);
    }
    __syncthreads();
    #pragma unroll
    for(int ks=0;ks<2;ks++){
      half8 af[4], bf[4];
      #pragma unroll
      for(int i=0;i<4;i++){
        int ml = wm + i*16 + l15;
        af[i] = *(half8*)(As + ml*64 + (((ks<<2)|quad) ^ (ml&7))*8);
      }
      #pragma unroll
      for(int j=0;j<4;j++){
        int nl = wn + j*16 + l15;
        bf[j] = *(half8*)(Bs + nl*64 + (((ks<<2)|quad) ^ (nl&7))*8);
      }
      #pragma unroll
      for(int i=0;i<4;i++)
        #pragma unroll
        for(int j=0;j<4;j++)
          acc[i][j] = __builtin_amdgcn_mfma_f32_16x16x32_f16(af[i], bf[j], acc[i][j], 0,0,0);
    }
    __syncthreads();
  }
  // epilogue: loss -> z -> online lse over this wave's 64 cols; reduce 16 lanes/row
  float qv[4]; int jv[4];
  #pragma unroll
  for(int j=0;j<4;j++){ jv[j] = n0 + wn + j*16 + l15; qv[j] = (jv[j]<N_ENT)? qn[jv[j]] : 0.f; }
  int ptile = blockIdx.x*2 + (w>>1);
  #pragma unroll
  for(int i=0;i<4;i++){
    int mbase = m0 + wm + i*16 + quad*4;
    #pragma unroll
    for(int r=0;r<4;r++){
      int mg = mbase + r;
      int pi = mg & (B_PAIR-1);
      int lp = tp[2*pi], rp = tp[2*pi+1];
      float cv = cvec[mg], al = alpha[mg], be = betav[mg];
      float mx = -INFINITY, sm = 0.f;
      #pragma unroll
      for(int j=0;j<4;j++){
        if(jv[j] < N_ENT){
          float mask = 1.0f - (float)(jv[j]==lp) - (float)(jv[j]==rp);
          float loss = (cv - qv[j] + 2.0f*acc[i][j][r]) * mask;
          float z = al*loss + be;
          if(z > mx){ sm = sm*__expf(mx - z) + 1.f; mx = z; }
          else sm += __expf(z - mx);
        }
      }
      #pragma unroll
      for(int m=8;m>=1;m>>=1){
        float om = __shfl_xor(mx, m, 64), os = __shfl_xor(sm, m, 64);
        lseMerge(mx, sm, om, os);
      }
      if(l15==0){ pm[(size_t)mg*PTILES + ptile] = mx; ps[(size_t)mg*PTILES + ptile] = sm; }
    }
  }
}

// ---- combine per-tile LSE partials: block per row ----
__global__ __launch_bounds__(256) void k_lse(const float* __restrict__ pm, const float* __restrict__ ps, float* lse){
  __shared__ float shm[256], shs[256];
  int row = blockIdx.x, tid = threadIdx.x;
  float mx = -INFINITY, sm = 0.f;
  for(int t=tid;t<PTILES;t+=256) lseMerge(mx, sm, pm[(size_t)row*PTILES+t], ps[(size_t)row*PTILES+t]);
  shm[tid]=mx; shs[tid]=sm;
  __syncthreads();
  for(int w=128;w>0;w>>=1){
    if(tid<w){
      float m2=shm[tid], s2=shs[tid];
      lseMerge(m2, s2, shm[tid+w], shs[tid+w]);
      shm[tid]=m2; shs[tid]=s2;
    }
    __syncthreads();
  }
  if(tid==0) lse[row] = shm[0] + logf(shs[0]);
}

// ---- final mean ----
__global__ __launch_bounds__(256) void k_final(const float* __restrict__ lse, float* out){
  __shared__ double sh[256];
  int tid = threadIdx.x;
  double s = 0.0;
  for(int i=tid;i<B_PAIR;i+=256) s += (double)lse[i] + (double)lse[B_PAIR+i];
  sh[tid]=s; __syncthreads();
  for(int w=128;w>0;w>>=1){ if(tid<w) sh[tid]+=sh[tid+w]; __syncthreads(); }
  if(tid==0) out[0] = (float)(sh[0] / (double)B_PAIR);
}

extern "C" void kernel_launch(void* const* d_in, const int* in_sizes, int n_in,
                              void* d_out, int out_size, void* d_ws, size_t ws_size,
                              hipStream_t stream) {
  const float* ent_emb = (const float*)d_in[0];
  const float* rel_emb = (const float*)d_in[1];
  const float* attn_e  = (const float*)d_in[2];
  const float* attn_r  = (const float*)d_in[3];
  const int* adj     = (const int*)d_in[5];
  const int* r_index = (const int*)d_in[6];
  const int* ent_adj = (const int*)d_in[7];
  const int* rel_adj = (const int*)d_in[8];
  const int* tp      = (const int*)d_in[9];
  float* out = (float*)d_out;

  const int* adj_row = adj;
  const int* adj_col = adj + T_EDGE;
  const int* rid1    = r_index + T_EDGE;

  char* base = (char*)d_ws;
  size_t off = 0;
  auto A = [&](size_t b)->void*{ void* p = base + off; off = (off + b + 255) & ~(size_t)255; return p; };
  // zero region
  int*   cntA  = (int*)  A((size_t)N_ENT*4);
  int*   cntE  = (int*)  A((size_t)N_ENT*4);
  int*   cntR  = (int*)  A((size_t)N_ENT*4);
  float* G     = (float*)A((size_t)EMBD*EMBD*4);
  float* Svec  = (float*)A(EMBD*4);
  float* Pvec  = (float*)A(EMBD*4);
  float* QQ    = (float*)A(2*4);
  size_t zero_end = off;
  // plain buffers
  int* startA = (int*)A((size_t)(N_ENT+1)*4);
  int* startE = (int*)A((size_t)(N_ENT+1)*4);
  int* startR = (int*)A((size_t)(N_ENT+1)*4);
  int* curA   = (int*)A((size_t)N_ENT*4);
  int* curE   = (int*)A((size_t)N_ENT*4);
  int* curR   = (int*)A((size_t)N_ENT*4);
  int* scolA  = (int*)A((size_t)T_EDGE*4);
  int* sridA  = (int*)A((size_t)T_EDGE*4);
  int* scolE  = (int*)A((size_t)NNZ_E*4);
  int* scolR  = (int*)A((size_t)NNZ_E*4);
  _Float16* Eh = (_Float16*)A((size_t)NPAD*EMBD*2);   // padded rows zeroed below
  // region X: phase-aliased (featC0/featC1 -> embT -> pm/ps)
  char* X = (char*)A((size_t)EMBD*NPAD*2);   // 46.2 MB
  _Float16* featC0 = (_Float16*)X;                       // 15.4 MB
  _Float16* featC1 = (_Float16*)(X + 16u*1024u*1024u);   // 15.4 MB
  _Float16* embT   = (_Float16*)X;
  float*    pm     = (float*)X;                          // 2048*470*4 = 3.85 MB
  float*    ps     = (float*)(X + 8u*1024u*1024u);
  _Float16* relnH  = (_Float16*)A((size_t)R_REL*128*2);
  float* expdot  = (float*)A(4*R_REL*4);
  _Float16* Wh   = (_Float16*)A((size_t)2*B_PAIR*EMBD*2);
  _Float16* Gh   = (_Float16*)A((size_t)EMBD*EMBD*2);
  float* Tm      = (float*)A((size_t)2*B_PAIR*EMBD*4);
  float* cvec    = (float*)A(2*B_PAIR*4);
  float* qn      = (float*)A((size_t)N_ENT*4);
  float* alpha   = (float*)A(2*B_PAIR*4);
  float* betav   = (float*)A(2*B_PAIR*4);
  float* lse     = (float*)A(2*B_PAIR*4);
  (void)ws_size; (void)in_sizes; (void)n_in; (void)out_size;

  hipMemsetAsync(d_ws, 0, zero_end, stream);
  hipMemsetAsync(Eh + (size_t)N_ENT*EMBD, 0, (size_t)(NPAD-N_ENT)*EMBD*2, stream);

  // ---- CSR builds (fused launches) ----
  k_count3<<<(NNZ_E+255)/256, 256, 0, stream>>>(adj_row, cntA, ent_adj, cntE, rel_adj, cntR);
  k_scan3<<<3, 1024, 0, stream>>>(cntA, startA, curA, cntE, startE, curE, cntR, startR, curR);
  k_scatter3<<<(NNZ_E+255)/256, 256, 0, stream>>>(adj_row, adj_col, rid1, curA, scolA, sridA,
                                                  ent_adj, ent_adj+NNZ_E, curE, scolE,
                                                  rel_adj, rel_adj+NNZ_E, curR, scolR);

  k_relnorm<<<R_REL/4, 256, 0, stream>>>(rel_emb, attn_e, attn_r, relnH, expdot);

  // ---- fused dual GAT stack: avg (ent|rel) -> layer0 -> layer1 ----
  k_avg_tanh<<<N_ENT/4, 256, 0, stream>>>(startE, scolE, ent_emb, featC0, Eh, 0, 0);
  k_avg_tanh<<<N_ENT/4, 256, 0, stream>>>(startR, scolR, rel_emb, featC0, Eh, 2, 384);
  k_edge2<<<N_ENT/4, 256, 0, stream>>>(startA, scolA, sridA, relnH, expdot + 0*R_REL, expdot + 2*R_REL,
                                       featC0, featC1, Eh, 128, 512);
  k_edge2<<<N_ENT/4, 256, 0, stream>>>(startA, scolA, sridA, relnH, expdot + 1*R_REL, expdot + 3*R_REL,
                                       featC1, featC0, Eh, 256, 640);

  // ---- align loss ----
  k_gather<<<B_PAIR, 256, 0, stream>>>(Eh, tp, Wh, cvec);
  k_qn<<<N_ENT/4, 256, 0, stream>>>(Eh, qn);
  k_embstats<<<(N_ENT+127)/128, 256, 0, stream>>>(Eh, qn, Svec, Pvec, QQ);
  dim3 gtr(NPAD/64, 12);
  k_transp<<<gtr, 256, 0, stream>>>(Eh, embT);
  dim3 gsy(6, 6, 8);
  k_syrk<<<gsy, 256, 0, stream>>>(embT, G);
  k_cvtG<<<(EMBD*EMBD+255)/256, 256, 0, stream>>>(G, Gh);
  dim3 gT(EMBD/64, 4);
  k_gemmTh<<<gT, 256, 0, stream>>>(Wh, Gh, Tm);
  k_rowstats<<<2*B_PAIR/4, 256, 0, stream>>>(Wh, Tm, Eh, qn, cvec, tp, Svec, Pvec, QQ, alpha, betav);
  dim3 gg(NT128, 16);
  k_gemmB<<<gg, 256, 0, stream>>>(Wh, Eh, cvec, qn, tp, alpha, betav, pm, ps);
  k_lse<<<2*B_PAIR, 256, 0, stream>>>(pm, ps, lse);
  k_final<<<1, 256, 0, stream>>>(lse, out);
}

// Round 8
// 949.394 us; speedup vs baseline: 5.2801x; 1.0148x over previous
//
#include <hip/hip_runtime.h>
#include <math.h>

#define N_ENT 30000
#define R_REL 1000
#define T_EDGE 300000
#define B_PAIR 1024
#define NNZ_E 600000
#define GAMMAF 3.0f
#define EPSV 1e-12f
#define EMBD 768
#define NPAD 30720           // N_ENT padded to 240 tiles of 128 (zeroed pad rows in Eh; qn[pad]=1e30)
#define NT128 240            // n-tiles of 128 for gemmB
#define PTILES 480           // lse partial tiles per row (2 per 128-tile)

typedef _Float16 half8 __attribute__((ext_vector_type(8)));
typedef _Float16 half4v __attribute__((ext_vector_type(4)));
typedef _Float16 half2v __attribute__((ext_vector_type(2)));
typedef float f32x4 __attribute__((ext_vector_type(4)));

__device__ inline void gl_lds16(const _Float16* g, _Float16* l){
  __builtin_amdgcn_global_load_lds(
      (const __attribute__((address_space(1))) unsigned int*)g,
      (__attribute__((address_space(3))) unsigned int*)l, 16, 0, 0);
}

__device__ inline float waveRedSum(float v){
  #pragma unroll
  for(int m=32;m>=1;m>>=1) v += __shfl_xor(v, m, 64);
  return v;
}

__device__ inline float fast_tanh(float x){
  x = fminf(10.f, fmaxf(-10.f, x));
  float e = __expf(2.f*x);
  return (e-1.f)/(e+1.f);
}

// ---- edge-count: all three lists in one launch ----
__global__ __launch_bounds__(256) void k_count3(const int* __restrict__ rA, int* cA,
                                                const int* __restrict__ rE, int* cE,
                                                const int* __restrict__ rR, int* cR){
  int e = blockIdx.x*256 + threadIdx.x;
  if(e < T_EDGE) atomicAdd(&cA[rA[e]], 1);
  if(e < NNZ_E){ atomicAdd(&cE[rE[e]], 1); atomicAdd(&cR[rR[e]], 1); }
}

// ---- 3 exclusive scans in one launch (block per list), wave-level scan ----
__global__ __launch_bounds__(1024) void k_scan3(const int* c0, int* s0, int* u0,
                                                const int* c1, int* s1, int* u1,
                                                const int* c2, int* s2, int* u2){
  const int* cnt = blockIdx.x==0 ? c0 : (blockIdx.x==1 ? c1 : c2);
  int* start     = blockIdx.x==0 ? s0 : (blockIdx.x==1 ? s1 : s2);
  int* cursor    = blockIdx.x==0 ? u0 : (blockIdx.x==1 ? u1 : u2);
  __shared__ int wsum[16];
  __shared__ int carry;
  int tid = threadIdx.x, lane = tid & 63, wid = tid >> 6;
  if(tid==0) carry = 0;
  __syncthreads();
  for(int base=0; base<N_ENT; base+=1024){
    int i = base + tid;
    int v = (i<N_ENT)? cnt[i] : 0;
    int x = v;
    #pragma unroll
    for(int off=1; off<64; off<<=1){ int t=__shfl_up(x,off,64); if(lane>=off) x+=t; }
    if(lane==63) wsum[wid]=x;
    __syncthreads();
    if(wid==0){
      int s = (lane<16)? wsum[lane] : 0;
      #pragma unroll
      for(int off=1; off<16; off<<=1){ int t=__shfl_up(s,off,64); if(lane>=off) s+=t; }
      if(lane<16) wsum[lane]=s;
    }
    __syncthreads();
    int wexcl = (wid==0)? 0 : wsum[wid-1];
    int excl = carry + wexcl + x - v;
    if(i<N_ENT){ start[i]=excl; cursor[i]=excl; }
    int tot = wsum[15];
    __syncthreads();
    if(tid==0) carry += tot;
    __syncthreads();
  }
  if(tid==0) start[N_ENT] = carry;
}

// ---- scatter all three edge lists into CSR order, one launch ----
__global__ __launch_bounds__(256) void k_scatter3(
      const int* __restrict__ rA, const int* __restrict__ cAj, const int* __restrict__ rid,
      int* uA, int* scolA, int* sridA,
      const int* __restrict__ rE, const int* __restrict__ cEj, int* uE, int* scolE,
      const int* __restrict__ rR, const int* __restrict__ cRj, int* uR, int* scolR){
  int e = blockIdx.x*256 + threadIdx.x;
  if(e < T_EDGE){
    int p = atomicAdd(&uA[rA[e]], 1);
    scolA[p] = cAj[e];
    sridA[p] = rid[e];
  }
  if(e < NNZ_E){
    int p = atomicAdd(&uE[rE[e]], 1);
    scolE[p] = cEj[e];
    int q = atomicAdd(&uR[rR[e]], 1);
    scolR[q] = cRj[e];
  }
}

// ---- _avg via CSR gather, fused tanh; writes interleaved fp16 featC + Eh slice ----
__global__ __launch_bounds__(256) void k_avg_tanh(const int* __restrict__ start, const int* __restrict__ scol,
                        const float* __restrict__ src, _Float16* featC, _Float16* Eh, int pairOff, int coloff){
  int r = blockIdx.x*4 + (threadIdx.x>>6);
  int lane = threadIdx.x & 63;
  int s0 = start[r], s1 = start[r+1];
  float ax=0.f, ay=0.f;
  int e = s0;
  for(; e+1<s1; e+=2){
    int c0 = scol[e], c1 = scol[e+1];
    float2 v0 = *(const float2*)(src + (size_t)c0*128 + lane*2);
    float2 v1 = *(const float2*)(src + (size_t)c1*128 + lane*2);
    ax += v0.x + v1.x; ay += v0.y + v1.y;
  }
  if(e<s1){
    int c0 = scol[e];
    float2 v0 = *(const float2*)(src + (size_t)c0*128 + lane*2);
    ax += v0.x; ay += v0.y;
  }
  float inv = (s1>s0) ? 1.0f/(float)(s1-s0) : 0.f;
  float vx = fast_tanh(ax*inv), vy = fast_tanh(ay*inv);
  half2v hv = {(_Float16)vx, (_Float16)vy};
  *(half2v*)(featC + (size_t)r*256 + lane*4 + pairOff) = hv;
  *(half2v*)(Eh + (size_t)r*EMBD + coloff + lane*2) = hv;
}

// ---- normalized relation table (fp16) + exp(attention-dot) tables ----
__global__ __launch_bounds__(256) void k_relnorm(const float* __restrict__ rel, const float* __restrict__ ae,
                          const float* __restrict__ ar, _Float16* relnH, float* expdot){
  int r = (blockIdx.x*256 + threadIdx.x) >> 6;
  int lane = threadIdx.x & 63;
  if (r >= R_REL) return;
  float2 v = *(const float2*)(rel + (size_t)r*128 + lane*2);
  float ss = waveRedSum(v.x*v.x + v.y*v.y);
  float nrm = fmaxf(sqrtf(ss), EPSV);
  float2 u; u.x = v.x/nrm; u.y = v.y/nrm;
  half2v uh = {(_Float16)u.x, (_Float16)u.y};
  *(half2v*)(relnH + (size_t)r*128 + lane*2) = uh;
  const float* ks[4] = {ae, ae+128, ar, ar+128};   // ent l0, ent l1, rel l0, rel l1
  #pragma unroll
  for(int k=0;k<4;k++){
    float2 w = *(const float2*)(ks[k] + lane*2);
    float d = waveRedSum(u.x*w.x + u.y*w.y);
    if(lane==0) expdot[k*R_REL + r] = __expf(d);
  }
}

// ---- fused dual-stack GAT layer: one pass does ent+rel Householder+softmax ----
__global__ __launch_bounds__(256) void k_edge2(const int* __restrict__ start, const int* __restrict__ scol,
      const int* __restrict__ srid, const _Float16* __restrict__ relnH,
      const float* __restrict__ expE, const float* __restrict__ expR,
      const _Float16* __restrict__ featIn, _Float16* featOut, _Float16* Eh, int colEnt, int colRel){
  int r = blockIdx.x*4 + (threadIdx.x>>6);
  int lane = threadIdx.x & 63;
  int s0 = start[r], s1 = start[r+1];
  float aEx=0,aEy=0,aRx=0,aRy=0, swE=0, swR=0;
  int e = s0;
  for(; e+1<s1; e+=2){
    int c0=scol[e], q0=srid[e], c1=scol[e+1], q1=srid[e+1];
    float wE0=expE[q0], wR0=expR[q0], wE1=expE[q1], wR1=expR[q1];
    half2v u0h = *(const half2v*)(relnH + (size_t)q0*128 + lane*2);
    half2v u1h = *(const half2v*)(relnH + (size_t)q1*128 + lane*2);
    half4v h0 = *(const half4v*)(featIn + (size_t)c0*256 + lane*4);
    half4v h1 = *(const half4v*)(featIn + (size_t)c1*256 + lane*4);
    float u0x=(float)u0h[0], u0y=(float)u0h[1], u1x=(float)u1h[0], u1y=(float)u1h[1];
    float e0x=(float)h0[0], e0y=(float)h0[1], r0x=(float)h0[2], r0y=(float)h0[3];
    float e1x=(float)h1[0], e1y=(float)h1[1], r1x=(float)h1[2], r1y=(float)h1[3];
    float d0 = e0x*u0x + e0y*u0y;
    float d1 = r0x*u0x + r0y*u0y;
    float d2 = e1x*u1x + e1y*u1y;
    float d3 = r1x*u1x + r1y*u1y;
    #pragma unroll
    for(int m=32;m>=1;m>>=1){
      d0 += __shfl_xor(d0,m,64); d1 += __shfl_xor(d1,m,64);
      d2 += __shfl_xor(d2,m,64); d3 += __shfl_xor(d3,m,64);
    }
    aEx += wE0*(e0x - 2.f*d0*u0x) + wE1*(e1x - 2.f*d2*u1x);
    aEy += wE0*(e0y - 2.f*d0*u0y) + wE1*(e1y - 2.f*d2*u1y);
    aRx += wR0*(r0x - 2.f*d1*u0x) + wR1*(r1x - 2.f*d3*u1x);
    aRy += wR0*(r0y - 2.f*d1*u0y) + wR1*(r1y - 2.f*d3*u1y);
    swE += wE0+wE1; swR += wR0+wR1;
  }
  if(e<s1){
    int c0=scol[e], q0=srid[e];
    float wE0=expE[q0], wR0=expR[q0];
    half2v u0h = *(const half2v*)(relnH + (size_t)q0*128 + lane*2);
    half4v h0 = *(const half4v*)(featIn + (size_t)c0*256 + lane*4);
    float u0x=(float)u0h[0], u0y=(float)u0h[1];
    float e0x=(float)h0[0], e0y=(float)h0[1], r0x=(float)h0[2], r0y=(float)h0[3];
    float d0 = e0x*u0x + e0y*u0y;
    float d1 = r0x*u0x + r0y*u0y;
    #pragma unroll
    for(int m=32;m>=1;m>>=1){ d0 += __shfl_xor(d0,m,64); d1 += __shfl_xor(d1,m,64); }
    aEx += wE0*(e0x - 2.f*d0*u0x);
    aEy += wE0*(e0y - 2.f*d0*u0y);
    aRx += wR0*(r0x - 2.f*d1*u0x);
    aRy += wR0*(r0y - 2.f*d1*u0y);
    swE += wE0; swR += wR0;
  }
  float iE = (s1>s0) ? 1.f/swE : 0.f;
  float iR = (s1>s0) ? 1.f/swR : 0.f;
  float vEx = fast_tanh(aEx*iE), vEy = fast_tanh(aEy*iE);
  float vRx = fast_tanh(aRx*iR), vRy = fast_tanh(aRy*iR);
  half4v ov = {(_Float16)vEx,(_Float16)vEy,(_Float16)vRx,(_Float16)vRy};
  *(half4v*)(featOut + (size_t)r*256 + lane*4) = ov;
  half2v he = {(_Float16)vEx,(_Float16)vEy};
  half2v hr = {(_Float16)vRx,(_Float16)vRy};
  *(half2v*)(Eh + (size_t)r*EMBD + colEnt + lane*2) = he;
  *(half2v*)(Eh + (size_t)r*EMBD + colRel + lane*2) = hr;
}

// ---- gather pair rows from Eh -> Wh fp16, cvec ----
__global__ __launch_bounds__(256) void k_gather(const _Float16* __restrict__ Eh, const int* __restrict__ tp,
                         _Float16* Wh, float* cvec){
  int i = blockIdx.x; int tid = threadIdx.x;
  int l = tp[2*i], r = tp[2*i+1];
  float sl=0.f, sr=0.f, sp=0.f;
  for(int c=tid;c<EMBD;c+=256){
    _Float16 lh = Eh[(size_t)l*EMBD+c], rh = Eh[(size_t)r*EMBD+c];
    float le = (float)lh, re = (float)rh;
    Wh[(size_t)i*EMBD+c]=lh; Wh[(size_t)(B_PAIR+i)*EMBD+c]=rh;
    sl += le*le; sr += re*re; float d = le-re; sp += d*d;
  }
  __shared__ float s0[256], s1[256], s2[256];
  s0[tid]=sl; s1[tid]=sr; s2[tid]=sp;
  __syncthreads();
  for(int w=128;w>0;w>>=1){
    if(tid<w){ s0[tid]+=s0[tid+w]; s1[tid]+=s1[tid+w]; s2[tid]+=s2[tid+w]; }
    __syncthreads();
  }
  if(tid==0){
    float pos = s2[0];
    cvec[i]        = pos + GAMMAF - s0[0];
    cvec[B_PAIR+i] = pos + GAMMAF - s1[0];
  }
}

// ---- q_j = ||e_j||^2 from Eh; pad rows get 1e30 (kills pad columns in gemmB epilogue) ----
__global__ __launch_bounds__(256) void k_qn(const _Float16* __restrict__ Eh, float* qn){
  int j = (blockIdx.x*256 + threadIdx.x) >> 6;
  int lane = threadIdx.x & 63;
  if(j >= NPAD) return;
  if(j >= N_ENT){ if(lane==0) qn[j] = 1e30f; return; }
  float s=0.f;
  #pragma unroll
  for(int q=0;q<12;q++){ float v = (float)Eh[(size_t)j*EMBD + lane + 64*q]; s += v*v; }
  s = waveRedSum(s);
  if(lane==0) qn[j]=s;
}

// ---- S = sum_j e_j, P = sum_j q_j e_j, Q = sum q, Q2 = sum q^2 (32 rows per block) ----
__global__ __launch_bounds__(256) void k_embstats(const _Float16* __restrict__ Eh, const float* __restrict__ qn,
                           float* Svec, float* Pvec, float* QQ){
  int tid = threadIdx.x;
  int n0 = blockIdx.x*32;
  int nend = n0+32; if(nend > N_ENT) nend = N_ENT;
  float s[3]={0,0,0}, p[3]={0,0,0};
  float q1=0.f, q2=0.f;
  for(int n=n0;n<nend;n++){
    float qv = qn[n];
    if(tid==0){ q1 += qv; q2 += qv*qv; }
    #pragma unroll
    for(int k=0;k<3;k++){
      float v = (float)Eh[(size_t)n*EMBD + tid + k*256];
      s[k] += v; p[k] += qv*v;
    }
  }
  #pragma unroll
  for(int k=0;k<3;k++){
    unsafeAtomicAdd(&Svec[tid + k*256], s[k]);
    unsafeAtomicAdd(&Pvec[tid + k*256], p[k]);
  }
  if(tid==0){ unsafeAtomicAdd(&QQ[0], q1); unsafeAtomicAdd(&QQ[1], q2); }
}

// ---- transpose Eh (30000x768) -> embT (768 x NPAD), zero-padded ----
__global__ __launch_bounds__(256) void k_transp(const _Float16* __restrict__ Eh, _Float16* embT){
  __shared__ __align__(16) _Float16 til[64][72];
  int r0 = blockIdx.x*64, c0 = blockIdx.y*64;
  int t = threadIdx.x;
  int rr = t>>3, c8 = (t&7)*8;
  #pragma unroll
  for(int p=0;p<2;p++){
    int gr = r0 + rr + p*32;
    uint4 v = make_uint4(0u,0u,0u,0u);
    if(gr < N_ENT) v = *(const uint4*)(Eh + (size_t)gr*EMBD + c0 + c8);
    *(uint4*)&til[rr + p*32][c8] = v;
  }
  __syncthreads();
  #pragma unroll
  for(int p=0;p<2;p++){
    int cc = rr + p*32;
    __align__(16) _Float16 tmp[8];
    #pragma unroll
    for(int j=0;j<8;j++) tmp[j] = til[c8 + j][cc];
    *(uint4*)(embT + (size_t)(c0+cc)*NPAD + r0 + c8) = *(uint4*)tmp;
  }
}

// ---- G = E^T E via f16 MFMA on embT; 128x128 tiles, DMA staging + XOR swizzle, split-K atomics ----
__global__ __launch_bounds__(256) void k_syrk(const _Float16* __restrict__ embT, float* G){
  __shared__ __align__(16) _Float16 As[128*64];
  __shared__ __align__(16) _Float16 Bs[128*64];
  int tid = threadIdx.x;
  int w = tid>>6, lane = tid&63;
  int quad = lane>>4, l15 = lane&15;
  int lr = lane>>3, lc = lane&7;
  int wm = (w>>1)*64, wn = (w&1)*64;
  int m0 = blockIdx.y*128, n0 = blockIdx.x*128;
  int kbeg = blockIdx.z*3840;
  int kend = kbeg + 3840; if(kend > NPAD) kend = NPAD;
  f32x4 acc[4][4];
  #pragma unroll
  for(int i=0;i<4;i++)
    #pragma unroll
    for(int j=0;j<4;j++) acc[i][j] = (f32x4){0.f,0.f,0.f,0.f};
  for(int k0=kbeg;k0<kend;k0+=64){
    #pragma unroll
    for(int p=0;p<4;p++){
      int r = p*32 + w*8 + lr;
      int cg = lc ^ (r&7);
      gl_lds16(embT + (size_t)(m0+r)*NPAD + k0 + cg*8, As + (p*32 + w*8)*64);
      gl_lds16(embT + (size_t)(n0+r)*NPAD + k0 + cg*8, Bs + (p*32 + w*8)*64);
    }
    __syncthreads();
    #pragma unroll
    for(int ks=0;ks<2;ks++){
      half8 af[4], bf[4];
      #pragma unroll
      for(int i=0;i<4;i++){
        int ml = wm + i*16 + l15;
        af[i] = *(half8*)(As + ml*64 + (((ks<<2)|quad) ^ (ml&7))*8);
      }
      #pragma unroll
      for(int j=0;j<4;j++){
        int nl = wn + j*16 + l15;
        bf[j] = *(half8*)(Bs + nl*64 + (((ks<<2)|quad) ^ (nl&7))*8);
      }
      #pragma unroll
      for(int i=0;i<4;i++)
        #pragma unroll
        for(int j=0;j<4;j++)
          acc[i][j] = __builtin_amdgcn_mfma_f32_16x16x32_f16(af[i], bf[j], acc[i][j], 0,0,0);
    }
    __syncthreads();
  }
  #pragma unroll
  for(int i=0;i<4;i++){
    #pragma unroll
    for(int r=0;r<4;r++){
      int m = m0 + wm + i*16 + quad*4 + r;
      #pragma unroll
      for(int j=0;j<4;j++){
        int n = n0 + wn + j*16 + l15;
        unsafeAtomicAdd(&G[(size_t)m*EMBD + n], acc[i][j][r]);
      }
    }
  }
}

// ---- G fp32 -> fp16 ----
__global__ __launch_bounds__(256) void k_cvtG(const float* __restrict__ G, _Float16* Gh){
  int i = blockIdx.x*256 + threadIdx.x;
  if(i < EMBD*EMBD) Gh[i] = (_Float16)G[i];
}

// ================== no-LDS 64x64 MFMA mainloop over K=768 (small GEMM only) ==================
__device__ inline void mfma_k768(const _Float16* __restrict__ Asrc, const _Float16* __restrict__ Bsrc,
                                 int m0, int n0, int l15, int quad, f32x4 acc[4][4]){
  const _Float16* aB[4]; const _Float16* bB[4];
  #pragma unroll
  for(int i=0;i<4;i++){
    aB[i] = Asrc + (size_t)(m0+i*16+l15)*EMBD + quad*8;
    bB[i] = Bsrc + (size_t)(n0+i*16+l15)*EMBD + quad*8;
  }
  half8 af[2][4], bf[2][4];
  #pragma unroll
  for(int i=0;i<4;i++){ af[0][i] = *(const half8*)(aB[i]); bf[0][i] = *(const half8*)(bB[i]); }
  #pragma unroll
  for(int ks=0; ks<24; ks++){
    int cur = ks&1, nxt = cur^1;
    if(ks<23){
      int ko = (ks+1)*32;
      #pragma unroll
      for(int i=0;i<4;i++){ af[nxt][i] = *(const half8*)(aB[i]+ko); bf[nxt][i] = *(const half8*)(bB[i]+ko); }
    }
    #pragma unroll
    for(int i=0;i<4;i++)
      #pragma unroll
      for(int j=0;j<4;j++)
        acc[i][j] = __builtin_amdgcn_mfma_f32_16x16x32_f16(af[cur][i], bf[cur][j], acc[i][j], 0,0,0);
  }
}

// ---- T = Wh * Gh (G symmetric), no-LDS MFMA ----
__global__ __launch_bounds__(256) void k_gemmTh(const _Float16* __restrict__ Wh, const _Float16* __restrict__ Gh,
                                                float* Tm){
  int tid = threadIdx.x, w = tid>>6, lane = tid&63;
  int quad = lane>>4, l15 = lane&15;
  int n0 = blockIdx.x*64;
  #pragma unroll
  for(int half=0; half<2; half++){
    int mt = blockIdx.y*8 + half*4 + w;
    int m0 = mt*64;
    f32x4 acc[4][4];
    #pragma unroll
    for(int i=0;i<4;i++)
      #pragma unroll
      for(int j=0;j<4;j++) acc[i][j] = (f32x4){0.f,0.f,0.f,0.f};
    mfma_k768(Wh, Gh, m0, n0, l15, quad, acc);
    #pragma unroll
    for(int i=0;i<4;i++)
      #pragma unroll
      for(int r=0;r<4;r++){
        int mg = m0 + i*16 + quad*4 + r;
        #pragma unroll
        for(int j=0;j<4;j++)
          Tm[(size_t)mg*EMBD + n0 + j*16 + l15] = acc[i][j][r];
      }
  }
}

// ---- per-row closed-form stats ----
__global__ __launch_bounds__(256) void k_rowstats(const _Float16* __restrict__ Wh, const float* __restrict__ Tm,
      const _Float16* __restrict__ Eh, const float* __restrict__ qn, const float* __restrict__ cvec,
      const int* __restrict__ tp, const float* __restrict__ Svec, const float* __restrict__ Pvec,
      const float* __restrict__ QQ, float* alpha, float* betav){
  int row = blockIdx.x*4 + (threadIdx.x>>6);
  int lane = threadIdx.x & 63;
  if(row >= 2*B_PAIR) return;
  int pi = row & (B_PAIR-1);
  int lp = tp[2*pi], rp = tp[2*pi+1];
  float d1=0,d2=0,d3=0,dl=0,dr=0;
  #pragma unroll
  for(int k=0;k<12;k++){
    int d = lane + 64*k;
    float a = (float)Wh[(size_t)row*EMBD + d];
    d1 += a*Svec[d];
    d2 += a*Pvec[d];
    d3 += a*Tm[(size_t)row*EMBD + d];
    dl += a*(float)Eh[(size_t)lp*EMBD + d];
    dr += a*(float)Eh[(size_t)rp*EMBD + d];
  }
  d1=waveRedSum(d1); d2=waveRedSum(d2); d3=waveRedSum(d3);
  dl=waveRedSum(dl); dr=waveRedSum(dr);
  if(lane==0){
    double c = (double)cvec[row], Q = (double)QQ[0], Q2 = (double)QQ[1], Nn = (double)N_ENT;
    double su  = Nn*c - Q + 2.0*(double)d1;
    double su2 = Nn*c*c - 2.0*c*Q + Q2 + 4.0*(c*(double)d1 - (double)d2) + 4.0*(double)d3;
    double ul = c - (double)qn[lp] + 2.0*(double)dl;
    double ur = c - (double)qn[rp] + 2.0*(double)dr;
    su -= ul + ur;
    if(lp != rp) su2 -= ul*ul + ur*ur;
    double mu = su/Nn;
    double var = su2/Nn - mu*mu;
    double sd = sqrt(fmax(var, 0.0));
    double al = 20.0/sd;
    alpha[row] = (float)al;
    betav[row] = (float)(8.0 - al*mu);
  }
}

__device__ inline void lseMerge(float& mx, float& sm, float om, float os){
  if(om > mx){ sm = sm*expf(mx-om) + os; mx = om; }
  else if(om != -INFINITY){ sm += os*expf(om-mx); }
}

// ---- pass B: 128x128 f16 MFMA (DMA staging + XOR swizzle), in-loop masked online-lse epilogue ----
//      1D grid 3840, XCD-ownership swizzle: id = xcd + 8*m + 128*tt -> ntile = xcd + 8*tt
__global__ __launch_bounds__(256) void k_gemmB(const _Float16* __restrict__ Wh, const _Float16* __restrict__ Eh,
    const float* __restrict__ cvec, const float* __restrict__ qn, const int* __restrict__ tp,
    const float* __restrict__ alpha, const float* __restrict__ betav, float* pm, float* ps){
  __shared__ __align__(16) _Float16 As[128*64];
  __shared__ __align__(16) _Float16 Bs[128*64];
  int id = blockIdx.x;
  int ntile = (id & 7) + ((id >> 7) << 3);
  int m0 = ((id >> 3) & 15) * 128;
  int n0 = ntile * 128;
  int tid = threadIdx.x;
  int w = tid>>6, lane = tid&63;
  int quad = lane>>4, l15 = lane&15;
  int lr = lane>>3, lc = lane&7;
  int wm = (w&1)*64, wn = (w>>1)*64;
  f32x4 acc[4][4];
  #pragma unroll
  for(int i=0;i<4;i++)
    #pragma unroll
    for(int j=0;j<4;j++) acc[i][j] = (f32x4){0.f,0.f,0.f,0.f};
  for(int k0=0;k0<EMBD;k0+=64){
    #pragma unroll
    for(int p=0;p<4;p++){
      int r = p*32 + w*8 + lr;
      int cg = lc ^ (r&7);
      gl_lds16(Wh + (size_t)(m0+r)*EMBD + k0 + cg*8, As + (p*32 + w*8)*64);
      gl_lds16(Eh + (size_t)(n0+r)*EMBD + k0 + cg*8, Bs + (p*32 + w*8)*64);
    }
    __syncthreads();
    #pragma unroll
    for(int ks=0;ks<2;ks++){
      half8 af[4], bf[4];
      #pragma unroll
      for(int i=0;i<4;i++){
        int ml = wm + i*16 + l15;
        af[i] = *(half8*)(As + ml*64 + (((ks<<2)|quad) ^ (ml&7))*8);
      }
      #pragma unroll
      for(int j=0;j<4;j++){
        int nl = wn + j*16 + l15;
        bf[j] = *(half8*)(Bs + nl*64 + (((ks<<2)|quad) ^ (nl&7))*8);
      }
      #pragma unroll
      for(int i=0;i<4;i++)
        #pragma unroll
        for(int j=0;j<4;j++)
          acc[i][j] = __builtin_amdgcn_mfma_f32_16x16x32_f16(af[i], bf[j], acc[i][j], 0,0,0);
    }
    __syncthreads();
  }
  // epilogue: masked loss -> z -> online lse over this wave's 64 cols; reduce 16 lanes/row.
  // pad cols have qn=1e30 -> z ~ -1e31 -> harmless in online merge (finite, never max vs real).
  float qv[4]; int jv[4];
  #pragma unroll
  for(int j=0;j<4;j++){ jv[j] = n0 + wn + j*16 + l15; qv[j] = qn[jv[j]]; }
  int ptile = ntile*2 + (w>>1);
  #pragma unroll
  for(int i=0;i<4;i++){
    int mbase = m0 + wm + i*16 + quad*4;
    #pragma unroll
    for(int r=0;r<4;r++){
      int mg = mbase + r;
      int pi = mg & (B_PAIR-1);
      int lp = tp[2*pi], rp = tp[2*pi+1];
      float cv = cvec[mg], al = alpha[mg], be = betav[mg];
      float mx = -INFINITY, sm = 0.f;
      #pragma unroll
      for(int j=0;j<4;j++){
        float u = fmaf(2.f, acc[i][j][r], cv - qv[j]);
        float z = fmaf(al, u, be);
        if(jv[j]==lp || jv[j]==rp) z = (lp==rp) ? fmaf(-al, u, be) : be;
        if(z > mx){ sm = sm*__expf(mx - z) + 1.f; mx = z; }
        else sm += __expf(z - mx);
      }
      #pragma unroll
      for(int m=8;m>=1;m>>=1){
        float om = __shfl_xor(mx, m, 64), os = __shfl_xor(sm, m, 64);
        lseMerge(mx, sm, om, os);
      }
      if(l15==0){ pm[(size_t)mg*PTILES + ptile] = mx; ps[(size_t)mg*PTILES + ptile] = sm; }
    }
  }
}

// ---- combine per-tile LSE partials: block per row ----
__global__ __launch_bounds__(256) void k_lse(const float* __restrict__ pm, const float* __restrict__ ps, float* lse){
  __shared__ float shm[256], shs[256];
  int row = blockIdx.x, tid = threadIdx.x;
  float mx = -INFINITY, sm = 0.f;
  for(int t=tid;t<PTILES;t+=256) lseMerge(mx, sm, pm[(size_t)row*PTILES+t], ps[(size_t)row*PTILES+t]);
  shm[tid]=mx; shs[tid]=sm;
  __syncthreads();
  for(int w=128;w>0;w>>=1){
    if(tid<w){
      float m2=shm[tid], s2=shs[tid];
      lseMerge(m2, s2, shm[tid+w], shs[tid+w]);
      shm[tid]=m2; shs[tid]=s2;
    }
    __syncthreads();
  }
  if(tid==0) lse[row] = shm[0] + logf(shs[0]);
}

// ---- final mean ----
__global__ __launch_bounds__(256) void k_final(const float* __restrict__ lse, float* out){
  __shared__ double sh[256];
  int tid = threadIdx.x;
  double s = 0.0;
  for(int i=tid;i<B_PAIR;i+=256) s += (double)lse[i] + (double)lse[B_PAIR+i];
  sh[tid]=s; __syncthreads();
  for(int w=128;w>0;w>>=1){ if(tid<w) sh[tid]+=sh[tid+w]; __syncthreads(); }
  if(tid==0) out[0] = (float)(sh[0] / (double)B_PAIR);
}

extern "C" void kernel_launch(void* const* d_in, const int* in_sizes, int n_in,
                              void* d_out, int out_size, void* d_ws, size_t ws_size,
                              hipStream_t stream) {
  const float* ent_emb = (const float*)d_in[0];
  const float* rel_emb = (const float*)d_in[1];
  const float* attn_e  = (const float*)d_in[2];
  const float* attn_r  = (const float*)d_in[3];
  const int* adj     = (const int*)d_in[5];
  const int* r_index = (const int*)d_in[6];
  const int* ent_adj = (const int*)d_in[7];
  const int* rel_adj = (const int*)d_in[8];
  const int* tp      = (const int*)d_in[9];
  float* out = (float*)d_out;

  const int* adj_row = adj;
  const int* adj_col = adj + T_EDGE;
  const int* rid1    = r_index + T_EDGE;

  char* base = (char*)d_ws;
  size_t off = 0;
  auto A = [&](size_t b)->void*{ void* p = base + off; off = (off + b + 255) & ~(size_t)255; return p; };
  // zero region
  int*   cntA  = (int*)  A((size_t)N_ENT*4);
  int*   cntE  = (int*)  A((size_t)N_ENT*4);
  int*   cntR  = (int*)  A((size_t)N_ENT*4);
  float* G     = (float*)A((size_t)EMBD*EMBD*4);
  float* Svec  = (float*)A(EMBD*4);
  float* Pvec  = (float*)A(EMBD*4);
  float* QQ    = (float*)A(2*4);
  size_t zero_end = off;
  // plain buffers
  int* startA = (int*)A((size_t)(N_ENT+1)*4);
  int* startE = (int*)A((size_t)(N_ENT+1)*4);
  int* startR = (int*)A((size_t)(N_ENT+1)*4);
  int* curA   = (int*)A((size_t)N_ENT*4);
  int* curE   = (int*)A((size_t)N_ENT*4);
  int* curR   = (int*)A((size_t)N_ENT*4);
  int* scolA  = (int*)A((size_t)T_EDGE*4);
  int* sridA  = (int*)A((size_t)T_EDGE*4);
  int* scolE  = (int*)A((size_t)NNZ_E*4);
  int* scolR  = (int*)A((size_t)NNZ_E*4);
  _Float16* Eh = (_Float16*)A((size_t)NPAD*EMBD*2);   // padded rows zeroed below
  // region X: phase-aliased (featC0/featC1 -> embT -> pm/ps)
  char* X = (char*)A((size_t)EMBD*NPAD*2);   // 47.2 MB
  _Float16* featC0 = (_Float16*)X;                       // 15.4 MB
  _Float16* featC1 = (_Float16*)(X + 16u*1024u*1024u);   // 15.4 MB
  _Float16* embT   = (_Float16*)X;
  float*    pm     = (float*)X;                          // 2048*480*4 = 3.93 MB
  float*    ps     = (float*)(X + 8u*1024u*1024u);
  _Float16* relnH  = (_Float16*)A((size_t)R_REL*128*2);
  float* expdot  = (float*)A(4*R_REL*4);
  _Float16* Wh   = (_Float16*)A((size_t)2*B_PAIR*EMBD*2);
  _Float16* Gh   = (_Float16*)A((size_t)EMBD*EMBD*2);
  float* Tm      = (float*)A((size_t)2*B_PAIR*EMBD*4);
  float* cvec    = (float*)A(2*B_PAIR*4);
  float* qn      = (float*)A((size_t)NPAD*4);
  float* alpha   = (float*)A(2*B_PAIR*4);
  float* betav   = (float*)A(2*B_PAIR*4);
  float* lse     = (float*)A(2*B_PAIR*4);
  (void)ws_size; (void)in_sizes; (void)n_in; (void)out_size;

  hipMemsetAsync(d_ws, 0, zero_end, stream);
  hipMemsetAsync(Eh + (size_t)N_ENT*EMBD, 0, (size_t)(NPAD-N_ENT)*EMBD*2, stream);

  // ---- CSR builds (fused launches) ----
  k_count3<<<(NNZ_E+255)/256, 256, 0, stream>>>(adj_row, cntA, ent_adj, cntE, rel_adj, cntR);
  k_scan3<<<3, 1024, 0, stream>>>(cntA, startA, curA, cntE, startE, curE, cntR, startR, curR);
  k_scatter3<<<(NNZ_E+255)/256, 256, 0, stream>>>(adj_row, adj_col, rid1, curA, scolA, sridA,
                                                  ent_adj, ent_adj+NNZ_E, curE, scolE,
                                                  rel_adj, rel_adj+NNZ_E, curR, scolR);

  k_relnorm<<<R_REL/4, 256, 0, stream>>>(rel_emb, attn_e, attn_r, relnH, expdot);

  // ---- fused dual GAT stack: avg (ent|rel) -> layer0 -> layer1 ----
  k_avg_tanh<<<N_ENT/4, 256, 0, stream>>>(startE, scolE, ent_emb, featC0, Eh, 0, 0);
  k_avg_tanh<<<N_ENT/4, 256, 0, stream>>>(startR, scolR, rel_emb, featC0, Eh, 2, 384);
  k_edge2<<<N_ENT/4, 256, 0, stream>>>(startA, scolA, sridA, relnH, expdot + 0*R_REL, expdot + 2*R_REL,
                                       featC0, featC1, Eh, 128, 512);
  k_edge2<<<N_ENT/4, 256, 0, stream>>>(startA, scolA, sridA, relnH, expdot + 1*R_REL, expdot + 3*R_REL,
                                       featC1, featC0, Eh, 256, 640);

  // ---- align loss ----
  k_gather<<<B_PAIR, 256, 0, stream>>>(Eh, tp, Wh, cvec);
  k_qn<<<NPAD/4, 256, 0, stream>>>(Eh, qn);
  k_embstats<<<(N_ENT+31)/32, 256, 0, stream>>>(Eh, qn, Svec, Pvec, QQ);
  dim3 gtr(NPAD/64, 12);
  k_transp<<<gtr, 256, 0, stream>>>(Eh, embT);
  dim3 gsy(6, 6, 8);
  k_syrk<<<gsy, 256, 0, stream>>>(embT, G);
  k_cvtG<<<(EMBD*EMBD+255)/256, 256, 0, stream>>>(G, Gh);
  dim3 gT(EMBD/64, 4);
  k_gemmTh<<<gT, 256, 0, stream>>>(Wh, Gh, Tm);
  k_rowstats<<<2*B_PAIR/4, 256, 0, stream>>>(Wh, Tm, Eh, qn, cvec, tp, Svec, Pvec, QQ, alpha, betav);
  k_gemmB<<<NT128*16, 256, 0, stream>>>(Wh, Eh, cvec, qn, tp, alpha, betav, pm, ps);
  k_lse<<<2*B_PAIR, 256, 0, stream>>>(pm, ps, lse);
  k_final<<<1, 256, 0, stream>>>(lse, out);
}

// Round 9
// 915.174 us; speedup vs baseline: 5.4775x; 1.0374x over previous
//
#include <hip/hip_runtime.h>
#include <math.h>

#define N_ENT 30000
#define R_REL 1000
#define T_EDGE 300000
#define B_PAIR 1024
#define NNZ_E 600000
#define GAMMAF 3.0f
#define EPSV 1e-12f
#define EMBD 768
#define NPAD 30720           // N_ENT padded to 240 tiles of 128 (zeroed pad rows in Eh; qn[pad]=1e30)
#define NT128 240            // n-tiles of 128 for gemmB
#define PTILES 480           // lse partial tiles per row (2 per 128-tile)

typedef _Float16 half8 __attribute__((ext_vector_type(8)));
typedef _Float16 half4v __attribute__((ext_vector_type(4)));
typedef _Float16 half2v __attribute__((ext_vector_type(2)));
typedef float f32x4 __attribute__((ext_vector_type(4)));

__device__ inline void gl_lds16(const _Float16* g, _Float16* l){
  __builtin_amdgcn_global_load_lds(
      (const __attribute__((address_space(1))) unsigned int*)g,
      (__attribute__((address_space(3))) unsigned int*)l, 16, 0, 0);
}

__device__ inline float waveRedSum(float v){
  #pragma unroll
  for(int m=32;m>=1;m>>=1) v += __shfl_xor(v, m, 64);
  return v;
}

__device__ inline float fast_tanh(float x){
  x = fminf(10.f, fmaxf(-10.f, x));
  float e = __expf(2.f*x);
  return (e-1.f)/(e+1.f);
}

// ---- edge-count: all three lists in one launch ----
__global__ __launch_bounds__(256) void k_count3(const int* __restrict__ rA, int* cA,
                                                const int* __restrict__ rE, int* cE,
                                                const int* __restrict__ rR, int* cR){
  int e = blockIdx.x*256 + threadIdx.x;
  if(e < T_EDGE) atomicAdd(&cA[rA[e]], 1);
  if(e < NNZ_E){ atomicAdd(&cE[rE[e]], 1); atomicAdd(&cR[rR[e]], 1); }
}

// ---- 3 exclusive scans in one launch (block per list), wave-level scan ----
__global__ __launch_bounds__(1024) void k_scan3(const int* c0, int* s0, int* u0,
                                                const int* c1, int* s1, int* u1,
                                                const int* c2, int* s2, int* u2){
  const int* cnt = blockIdx.x==0 ? c0 : (blockIdx.x==1 ? c1 : c2);
  int* start     = blockIdx.x==0 ? s0 : (blockIdx.x==1 ? s1 : s2);
  int* cursor    = blockIdx.x==0 ? u0 : (blockIdx.x==1 ? u1 : u2);
  __shared__ int wsum[16];
  __shared__ int carry;
  int tid = threadIdx.x, lane = tid & 63, wid = tid >> 6;
  if(tid==0) carry = 0;
  __syncthreads();
  for(int base=0; base<N_ENT; base+=1024){
    int i = base + tid;
    int v = (i<N_ENT)? cnt[i] : 0;
    int x = v;
    #pragma unroll
    for(int off=1; off<64; off<<=1){ int t=__shfl_up(x,off,64); if(lane>=off) x+=t; }
    if(lane==63) wsum[wid]=x;
    __syncthreads();
    if(wid==0){
      int s = (lane<16)? wsum[lane] : 0;
      #pragma unroll
      for(int off=1; off<16; off<<=1){ int t=__shfl_up(s,off,64); if(lane>=off) s+=t; }
      if(lane<16) wsum[lane]=s;
    }
    __syncthreads();
    int wexcl = (wid==0)? 0 : wsum[wid-1];
    int excl = carry + wexcl + x - v;
    if(i<N_ENT){ start[i]=excl; cursor[i]=excl; }
    int tot = wsum[15];
    __syncthreads();
    if(tid==0) carry += tot;
    __syncthreads();
  }
  if(tid==0) start[N_ENT] = carry;
}

// ---- scatter all three edge lists into CSR order, one launch ----
__global__ __launch_bounds__(256) void k_scatter3(
      const int* __restrict__ rA, const int* __restrict__ cAj, const int* __restrict__ rid,
      int* uA, int* scolA, int* sridA,
      const int* __restrict__ rE, const int* __restrict__ cEj, int* uE, int* scolE,
      const int* __restrict__ rR, const int* __restrict__ cRj, int* uR, int* scolR){
  int e = blockIdx.x*256 + threadIdx.x;
  if(e < T_EDGE){
    int p = atomicAdd(&uA[rA[e]], 1);
    scolA[p] = cAj[e];
    sridA[p] = rid[e];
  }
  if(e < NNZ_E){
    int p = atomicAdd(&uE[rE[e]], 1);
    scolE[p] = cEj[e];
    int q = atomicAdd(&uR[rR[e]], 1);
    scolR[q] = cRj[e];
  }
}

// ---- fp32 -> fp16 conversion of raw embeddings (ent then rel) ----
__global__ __launch_bounds__(256) void k_cvtemb(const float* __restrict__ ent, const float* __restrict__ rel,
                                                _Float16* ehE, _Float16* ehR){
  int i = blockIdx.x*256 + threadIdx.x;
  if(i < N_ENT*128) ehE[i] = (_Float16)ent[i];
  if(i < R_REL*128) ehR[i] = (_Float16)rel[i];
}

// ---- _avg via CSR gather from fp16 src (ent: y=0, rel: y=1), fused tanh ----
__global__ __launch_bounds__(256) void k_avg2(const int* __restrict__ startE, const int* __restrict__ scolE,
                        const _Float16* __restrict__ srcE,
                        const int* __restrict__ startR, const int* __restrict__ scolR,
                        const _Float16* __restrict__ srcR,
                        _Float16* featC, _Float16* Eh){
  int which = blockIdx.y;
  const int* start = which? startR : startE;
  const int* scol  = which? scolR : scolE;
  const _Float16* src = which? srcR : srcE;
  int pairOff = which? 2 : 0;
  int coloff  = which? 384 : 0;
  int r = blockIdx.x*4 + (threadIdx.x>>6);
  int lane = threadIdx.x & 63;
  int s0 = start[r], s1 = start[r+1];
  float ax=0.f, ay=0.f;
  int e = s0;
  for(; e+1<s1; e+=2){
    int c0 = scol[e], c1 = scol[e+1];
    half2v v0 = *(const half2v*)(src + (size_t)c0*128 + lane*2);
    half2v v1 = *(const half2v*)(src + (size_t)c1*128 + lane*2);
    ax += (float)v0[0] + (float)v1[0]; ay += (float)v0[1] + (float)v1[1];
  }
  if(e<s1){
    int c0 = scol[e];
    half2v v0 = *(const half2v*)(src + (size_t)c0*128 + lane*2);
    ax += (float)v0[0]; ay += (float)v0[1];
  }
  float inv = (s1>s0) ? 1.0f/(float)(s1-s0) : 0.f;
  float vx = fast_tanh(ax*inv), vy = fast_tanh(ay*inv);
  half2v hv = {(_Float16)vx, (_Float16)vy};
  *(half2v*)(featC + (size_t)r*256 + lane*4 + pairOff) = hv;
  *(half2v*)(Eh + (size_t)r*EMBD + coloff + lane*2) = hv;
}

// ---- normalized relation table (fp16) + exp(attention-dot) tables ----
__global__ __launch_bounds__(256) void k_relnorm(const float* __restrict__ rel, const float* __restrict__ ae,
                          const float* __restrict__ ar, _Float16* relnH, float* expdot){
  int r = (blockIdx.x*256 + threadIdx.x) >> 6;
  int lane = threadIdx.x & 63;
  if (r >= R_REL) return;
  float2 v = *(const float2*)(rel + (size_t)r*128 + lane*2);
  float ss = waveRedSum(v.x*v.x + v.y*v.y);
  float nrm = fmaxf(sqrtf(ss), EPSV);
  float2 u; u.x = v.x/nrm; u.y = v.y/nrm;
  half2v uh = {(_Float16)u.x, (_Float16)u.y};
  *(half2v*)(relnH + (size_t)r*128 + lane*2) = uh;
  const float* ks[4] = {ae, ae+128, ar, ar+128};   // ent l0, ent l1, rel l0, rel l1
  #pragma unroll
  for(int k=0;k<4;k++){
    float2 w = *(const float2*)(ks[k] + lane*2);
    float d = waveRedSum(u.x*w.x + u.y*w.y);
    if(lane==0) expdot[k*R_REL + r] = __expf(d);
  }
}

// ---- fused dual-stack GAT layer: one pass does ent+rel Householder+softmax ----
__global__ __launch_bounds__(256) void k_edge2(const int* __restrict__ start, const int* __restrict__ scol,
      const int* __restrict__ srid, const _Float16* __restrict__ relnH,
      const float* __restrict__ expE, const float* __restrict__ expR,
      const _Float16* __restrict__ featIn, _Float16* featOut, _Float16* Eh, int colEnt, int colRel){
  int r = blockIdx.x*4 + (threadIdx.x>>6);
  int lane = threadIdx.x & 63;
  int s0 = start[r], s1 = start[r+1];
  float aEx=0,aEy=0,aRx=0,aRy=0, swE=0, swR=0;
  int e = s0;
  for(; e+1<s1; e+=2){
    int c0=scol[e], q0=srid[e], c1=scol[e+1], q1=srid[e+1];
    float wE0=expE[q0], wR0=expR[q0], wE1=expE[q1], wR1=expR[q1];
    half2v u0h = *(const half2v*)(relnH + (size_t)q0*128 + lane*2);
    half2v u1h = *(const half2v*)(relnH + (size_t)q1*128 + lane*2);
    half4v h0 = *(const half4v*)(featIn + (size_t)c0*256 + lane*4);
    half4v h1 = *(const half4v*)(featIn + (size_t)c1*256 + lane*4);
    float u0x=(float)u0h[0], u0y=(float)u0h[1], u1x=(float)u1h[0], u1y=(float)u1h[1];
    float e0x=(float)h0[0], e0y=(float)h0[1], r0x=(float)h0[2], r0y=(float)h0[3];
    float e1x=(float)h1[0], e1y=(float)h1[1], r1x=(float)h1[2], r1y=(float)h1[3];
    float d0 = e0x*u0x + e0y*u0y;
    float d1 = r0x*u0x + r0y*u0y;
    float d2 = e1x*u1x + e1y*u1y;
    float d3 = r1x*u1x + r1y*u1y;
    #pragma unroll
    for(int m=32;m>=1;m>>=1){
      d0 += __shfl_xor(d0,m,64); d1 += __shfl_xor(d1,m,64);
      d2 += __shfl_xor(d2,m,64); d3 += __shfl_xor(d3,m,64);
    }
    aEx += wE0*(e0x - 2.f*d0*u0x) + wE1*(e1x - 2.f*d2*u1x);
    aEy += wE0*(e0y - 2.f*d0*u0y) + wE1*(e1y - 2.f*d2*u1y);
    aRx += wR0*(r0x - 2.f*d1*u0x) + wR1*(r1x - 2.f*d3*u1x);
    aRy += wR0*(r0y - 2.f*d1*u0y) + wR1*(r1y - 2.f*d3*u1y);
    swE += wE0+wE1; swR += wR0+wR1;
  }
  if(e<s1){
    int c0=scol[e], q0=srid[e];
    float wE0=expE[q0], wR0=expR[q0];
    half2v u0h = *(const half2v*)(relnH + (size_t)q0*128 + lane*2);
    half4v h0 = *(const half4v*)(featIn + (size_t)c0*256 + lane*4);
    float u0x=(float)u0h[0], u0y=(float)u0h[1];
    float e0x=(float)h0[0], e0y=(float)h0[1], r0x=(float)h0[2], r0y=(float)h0[3];
    float d0 = e0x*u0x + e0y*u0y;
    float d1 = r0x*u0x + r0y*u0y;
    #pragma unroll
    for(int m=32;m>=1;m>>=1){ d0 += __shfl_xor(d0,m,64); d1 += __shfl_xor(d1,m,64); }
    aEx += wE0*(e0x - 2.f*d0*u0x);
    aEy += wE0*(e0y - 2.f*d0*u0y);
    aRx += wR0*(r0x - 2.f*d1*u0x);
    aRy += wR0*(r0y - 2.f*d1*u0y);
    swE += wE0; swR += wR0;
  }
  float iE = (s1>s0) ? 1.f/swE : 0.f;
  float iR = (s1>s0) ? 1.f/swR : 0.f;
  float vEx = fast_tanh(aEx*iE), vEy = fast_tanh(aEy*iE);
  float vRx = fast_tanh(aRx*iR), vRy = fast_tanh(aRy*iR);
  half4v ov = {(_Float16)vEx,(_Float16)vEy,(_Float16)vRx,(_Float16)vRy};
  *(half4v*)(featOut + (size_t)r*256 + lane*4) = ov;
  half2v he = {(_Float16)vEx,(_Float16)vEy};
  half2v hr = {(_Float16)vRx,(_Float16)vRy};
  *(half2v*)(Eh + (size_t)r*EMBD + colEnt + lane*2) = he;
  *(half2v*)(Eh + (size_t)r*EMBD + colRel + lane*2) = hr;
}

// ---- gather pair rows from Eh -> Wh fp16, cvec ----
__global__ __launch_bounds__(256) void k_gather(const _Float16* __restrict__ Eh, const int* __restrict__ tp,
                         _Float16* Wh, float* cvec){
  int i = blockIdx.x; int tid = threadIdx.x;
  int l = tp[2*i], r = tp[2*i+1];
  float sl=0.f, sr=0.f, sp=0.f;
  for(int c=tid;c<EMBD;c+=256){
    _Float16 lh = Eh[(size_t)l*EMBD+c], rh = Eh[(size_t)r*EMBD+c];
    float le = (float)lh, re = (float)rh;
    Wh[(size_t)i*EMBD+c]=lh; Wh[(size_t)(B_PAIR+i)*EMBD+c]=rh;
    sl += le*le; sr += re*re; float d = le-re; sp += d*d;
  }
  __shared__ float s0[256], s1[256], s2[256];
  s0[tid]=sl; s1[tid]=sr; s2[tid]=sp;
  __syncthreads();
  for(int w=128;w>0;w>>=1){
    if(tid<w){ s0[tid]+=s0[tid+w]; s1[tid]+=s1[tid+w]; s2[tid]+=s2[tid+w]; }
    __syncthreads();
  }
  if(tid==0){
    float pos = s2[0];
    cvec[i]        = pos + GAMMAF - s0[0];
    cvec[B_PAIR+i] = pos + GAMMAF - s1[0];
  }
}

// ---- q_j = ||e_j||^2 from Eh; pad rows get 1e30 (kills pad columns in gemmB epilogue) ----
__global__ __launch_bounds__(256) void k_qn(const _Float16* __restrict__ Eh, float* qn){
  int j = (blockIdx.x*256 + threadIdx.x) >> 6;
  int lane = threadIdx.x & 63;
  if(j >= NPAD) return;
  if(j >= N_ENT){ if(lane==0) qn[j] = 1e30f; return; }
  float s=0.f;
  #pragma unroll
  for(int q=0;q<12;q++){ float v = (float)Eh[(size_t)j*EMBD + lane + 64*q]; s += v*v; }
  s = waveRedSum(s);
  if(lane==0) qn[j]=s;
}

// ---- S = sum_j e_j, P = sum_j q_j e_j, Q = sum q, Q2 = sum q^2 (32 rows per block) ----
__global__ __launch_bounds__(256) void k_embstats(const _Float16* __restrict__ Eh, const float* __restrict__ qn,
                           float* Svec, float* Pvec, float* QQ){
  int tid = threadIdx.x;
  int n0 = blockIdx.x*32;
  int nend = n0+32; if(nend > N_ENT) nend = N_ENT;
  float s[3]={0,0,0}, p[3]={0,0,0};
  float q1=0.f, q2=0.f;
  for(int n=n0;n<nend;n++){
    float qv = qn[n];
    if(tid==0){ q1 += qv; q2 += qv*qv; }
    #pragma unroll
    for(int k=0;k<3;k++){
      float v = (float)Eh[(size_t)n*EMBD + tid + k*256];
      s[k] += v; p[k] += qv*v;
    }
  }
  #pragma unroll
  for(int k=0;k<3;k++){
    unsafeAtomicAdd(&Svec[tid + k*256], s[k]);
    unsafeAtomicAdd(&Pvec[tid + k*256], p[k]);
  }
  if(tid==0){ unsafeAtomicAdd(&QQ[0], q1); unsafeAtomicAdd(&QQ[1], q2); }
}

// ---- transpose Eh (30000x768) -> embT (768 x NPAD), zero-padded ----
__global__ __launch_bounds__(256) void k_transp(const _Float16* __restrict__ Eh, _Float16* embT){
  __shared__ __align__(16) _Float16 til[64][72];
  int r0 = blockIdx.x*64, c0 = blockIdx.y*64;
  int t = threadIdx.x;
  int rr = t>>3, c8 = (t&7)*8;
  #pragma unroll
  for(int p=0;p<2;p++){
    int gr = r0 + rr + p*32;
    uint4 v = make_uint4(0u,0u,0u,0u);
    if(gr < N_ENT) v = *(const uint4*)(Eh + (size_t)gr*EMBD + c0 + c8);
    *(uint4*)&til[rr + p*32][c8] = v;
  }
  __syncthreads();
  #pragma unroll
  for(int p=0;p<2;p++){
    int cc = rr + p*32;
    __align__(16) _Float16 tmp[8];
    #pragma unroll
    for(int j=0;j<8;j++) tmp[j] = til[c8 + j][cc];
    *(uint4*)(embT + (size_t)(c0+cc)*NPAD + r0 + c8) = *(uint4*)tmp;
  }
}

// ---- G = E^T E via f16 MFMA on embT; 128x128 tiles, DMA staging + XOR swizzle, split-K atomics ----
__global__ __launch_bounds__(256) void k_syrk(const _Float16* __restrict__ embT, float* G){
  __shared__ __align__(16) _Float16 As[128*64];
  __shared__ __align__(16) _Float16 Bs[128*64];
  int tid = threadIdx.x;
  int w = tid>>6, lane = tid&63;
  int quad = lane>>4, l15 = lane&15;
  int lr = lane>>3, lc = lane&7;
  int wm = (w>>1)*64, wn = (w&1)*64;
  int m0 = blockIdx.y*128, n0 = blockIdx.x*128;
  int kbeg = blockIdx.z*3840;
  int kend = kbeg + 3840; if(kend > NPAD) kend = NPAD;
  f32x4 acc[4][4];
  #pragma unroll
  for(int i=0;i<4;i++)
    #pragma unroll
    for(int j=0;j<4;j++) acc[i][j] = (f32x4){0.f,0.f,0.f,0.f};
  for(int k0=kbeg;k0<kend;k0+=64){
    #pragma unroll
    for(int p=0;p<4;p++){
      int r = p*32 + w*8 + lr;
      int cg = lc ^ (r&7);
      gl_lds16(embT + (size_t)(m0+r)*NPAD + k0 + cg*8, As + (p*32 + w*8)*64);
      gl_lds16(embT + (size_t)(n0+r)*NPAD + k0 + cg*8, Bs + (p*32 + w*8)*64);
    }
    __syncthreads();
    #pragma unroll
    for(int ks=0;ks<2;ks++){
      half8 af[4], bf[4];
      #pragma unroll
      for(int i=0;i<4;i++){
        int ml = wm + i*16 + l15;
        af[i] = *(half8*)(As + ml*64 + (((ks<<2)|quad) ^ (ml&7))*8);
      }
      #pragma unroll
      for(int j=0;j<4;j++){
        int nl = wn + j*16 + l15;
        bf[j] = *(half8*)(Bs + nl*64 + (((ks<<2)|quad) ^ (nl&7))*8);
      }
      #pragma unroll
      for(int i=0;i<4;i++)
        #pragma unroll
        for(int j=0;j<4;j++)
          acc[i][j] = __builtin_amdgcn_mfma_f32_16x16x32_f16(af[i], bf[j], acc[i][j], 0,0,0);
    }
    __syncthreads();
  }
  #pragma unroll
  for(int i=0;i<4;i++){
    #pragma unroll
    for(int r=0;r<4;r++){
      int m = m0 + wm + i*16 + quad*4 + r;
      #pragma unroll
      for(int j=0;j<4;j++){
        int n = n0 + wn + j*16 + l15;
        unsafeAtomicAdd(&G[(size_t)m*EMBD + n], acc[i][j][r]);
      }
    }
  }
}

// ---- G fp32 -> fp16 ----
__global__ __launch_bounds__(256) void k_cvtG(const float* __restrict__ G, _Float16* Gh){
  int i = blockIdx.x*256 + threadIdx.x;
  if(i < EMBD*EMBD) Gh[i] = (_Float16)G[i];
}

// ================== no-LDS 64x64 MFMA mainloop over K=768 (small GEMM only) ==================
__device__ inline void mfma_k768(const _Float16* __restrict__ Asrc, const _Float16* __restrict__ Bsrc,
                                 int m0, int n0, int l15, int quad, f32x4 acc[4][4]){
  const _Float16* aB[4]; const _Float16* bB[4];
  #pragma unroll
  for(int i=0;i<4;i++){
    aB[i] = Asrc + (size_t)(m0+i*16+l15)*EMBD + quad*8;
    bB[i] = Bsrc + (size_t)(n0+i*16+l15)*EMBD + quad*8;
  }
  half8 af[2][4], bf[2][4];
  #pragma unroll
  for(int i=0;i<4;i++){ af[0][i] = *(const half8*)(aB[i]); bf[0][i] = *(const half8*)(bB[i]); }
  #pragma unroll
  for(int ks=0; ks<24; ks++){
    int cur = ks&1, nxt = cur^1;
    if(ks<23){
      int ko = (ks+1)*32;
      #pragma unroll
      for(int i=0;i<4;i++){ af[nxt][i] = *(const half8*)(aB[i]+ko); bf[nxt][i] = *(const half8*)(bB[i]+ko); }
    }
    #pragma unroll
    for(int i=0;i<4;i++)
      #pragma unroll
      for(int j=0;j<4;j++)
        acc[i][j] = __builtin_amdgcn_mfma_f32_16x16x32_f16(af[cur][i], bf[cur][j], acc[i][j], 0,0,0);
  }
}

// ---- T = Wh * Gh (G symmetric), no-LDS MFMA ----
__global__ __launch_bounds__(256) void k_gemmTh(const _Float16* __restrict__ Wh, const _Float16* __restrict__ Gh,
                                                float* Tm){
  int tid = threadIdx.x, w = tid>>6, lane = tid&63;
  int quad = lane>>4, l15 = lane&15;
  int n0 = blockIdx.x*64;
  #pragma unroll
  for(int half=0; half<2; half++){
    int mt = blockIdx.y*8 + half*4 + w;
    int m0 = mt*64;
    f32x4 acc[4][4];
    #pragma unroll
    for(int i=0;i<4;i++)
      #pragma unroll
      for(int j=0;j<4;j++) acc[i][j] = (f32x4){0.f,0.f,0.f,0.f};
    mfma_k768(Wh, Gh, m0, n0, l15, quad, acc);
    #pragma unroll
    for(int i=0;i<4;i++)
      #pragma unroll
      for(int r=0;r<4;r++){
        int mg = m0 + i*16 + quad*4 + r;
        #pragma unroll
        for(int j=0;j<4;j++)
          Tm[(size_t)mg*EMBD + n0 + j*16 + l15] = acc[i][j][r];
      }
  }
}

// ---- per-row closed-form stats ----
__global__ __launch_bounds__(256) void k_rowstats(const _Float16* __restrict__ Wh, const float* __restrict__ Tm,
      const _Float16* __restrict__ Eh, const float* __restrict__ qn, const float* __restrict__ cvec,
      const int* __restrict__ tp, const float* __restrict__ Svec, const float* __restrict__ Pvec,
      const float* __restrict__ QQ, float* alpha, float* betav){
  int row = blockIdx.x*4 + (threadIdx.x>>6);
  int lane = threadIdx.x & 63;
  if(row >= 2*B_PAIR) return;
  int pi = row & (B_PAIR-1);
  int lp = tp[2*pi], rp = tp[2*pi+1];
  float d1=0,d2=0,d3=0,dl=0,dr=0;
  #pragma unroll
  for(int k=0;k<12;k++){
    int d = lane + 64*k;
    float a = (float)Wh[(size_t)row*EMBD + d];
    d1 += a*Svec[d];
    d2 += a*Pvec[d];
    d3 += a*Tm[(size_t)row*EMBD + d];
    dl += a*(float)Eh[(size_t)lp*EMBD + d];
    dr += a*(float)Eh[(size_t)rp*EMBD + d];
  }
  d1=waveRedSum(d1); d2=waveRedSum(d2); d3=waveRedSum(d3);
  dl=waveRedSum(dl); dr=waveRedSum(dr);
  if(lane==0){
    double c = (double)cvec[row], Q = (double)QQ[0], Q2 = (double)QQ[1], Nn = (double)N_ENT;
    double su  = Nn*c - Q + 2.0*(double)d1;
    double su2 = Nn*c*c - 2.0*c*Q + Q2 + 4.0*(c*(double)d1 - (double)d2) + 4.0*(double)d3;
    double ul = c - (double)qn[lp] + 2.0*(double)dl;
    double ur = c - (double)qn[rp] + 2.0*(double)dr;
    su -= ul + ur;
    if(lp != rp) su2 -= ul*ul + ur*ur;
    double mu = su/Nn;
    double var = su2/Nn - mu*mu;
    double sd = sqrt(fmax(var, 0.0));
    double al = 20.0/sd;
    alpha[row] = (float)al;
    betav[row] = (float)(8.0 - al*mu);
  }
}

__device__ inline void lseMerge(float& mx, float& sm, float om, float os){
  if(om > mx){ sm = sm*expf(mx-om) + os; mx = om; }
  else if(om != -INFINITY){ sm += os*expf(om-mx); }
}

// ---- pass B: 256x128 f16 MFMA tile (wave=128x64, acc 8x4), DMA staging + XOR swizzle,
//      in-loop masked online-lse epilogue.
//      1D grid 1920, XCD-ownership: id = xcd + 8*mt + 64*tt -> ntile = xcd + 8*tt, m0 = mt*256
__global__ __launch_bounds__(256,2) void k_gemmB(const _Float16* __restrict__ Wh, const _Float16* __restrict__ Eh,
    const float* __restrict__ cvec, const float* __restrict__ qn, const int* __restrict__ tp,
    const float* __restrict__ alpha, const float* __restrict__ betav, float* pm, float* ps){
  __shared__ __align__(16) _Float16 As[256*64];
  __shared__ __align__(16) _Float16 Bs[128*64];
  int id = blockIdx.x;
  int ntile = (id & 7) + ((id >> 6) << 3);
  int m0 = ((id >> 3) & 7) * 256;
  int n0 = ntile * 128;
  int tid = threadIdx.x;
  int w = tid>>6, lane = tid&63;
  int quad = lane>>4, l15 = lane&15;
  int lr = lane>>3, lc = lane&7;
  int wm = (w&1)*128, wn = (w>>1)*64;
  f32x4 acc[8][4];
  #pragma unroll
  for(int i=0;i<8;i++)
    #pragma unroll
    for(int j=0;j<4;j++) acc[i][j] = (f32x4){0.f,0.f,0.f,0.f};
  for(int k0=0;k0<EMBD;k0+=64){
    #pragma unroll
    for(int p=0;p<8;p++){
      int r = p*32 + w*8 + lr;
      int cg = lc ^ (r&7);
      gl_lds16(Wh + (size_t)(m0+r)*EMBD + k0 + cg*8, As + (p*32 + w*8)*64);
    }
    #pragma unroll
    for(int p=0;p<4;p++){
      int r = p*32 + w*8 + lr;
      int cg = lc ^ (r&7);
      gl_lds16(Eh + (size_t)(n0+r)*EMBD + k0 + cg*8, Bs + (p*32 + w*8)*64);
    }
    __syncthreads();
    #pragma unroll
    for(int ks=0;ks<2;ks++){
      half8 af[8], bf[4];
      #pragma unroll
      for(int i=0;i<8;i++){
        int ml = wm + i*16 + l15;
        af[i] = *(half8*)(As + ml*64 + (((ks<<2)|quad) ^ (ml&7))*8);
      }
      #pragma unroll
      for(int j=0;j<4;j++){
        int nl = wn + j*16 + l15;
        bf[j] = *(half8*)(Bs + nl*64 + (((ks<<2)|quad) ^ (nl&7))*8);
      }
      #pragma unroll
      for(int i=0;i<8;i++)
        #pragma unroll
        for(int j=0;j<4;j++)
          acc[i][j] = __builtin_amdgcn_mfma_f32_16x16x32_f16(af[i], bf[j], acc[i][j], 0,0,0);
    }
    __syncthreads();
  }
  // epilogue: masked loss -> z -> online lse over this wave's 64 cols; reduce 16 lanes/row.
  float qv[4]; int jv[4];
  #pragma unroll
  for(int j=0;j<4;j++){ jv[j] = n0 + wn + j*16 + l15; qv[j] = qn[jv[j]]; }
  int ptile = ntile*2 + (w>>1);
  #pragma unroll
  for(int i=0;i<8;i++){
    int mbase = m0 + wm + i*16 + quad*4;
    #pragma unroll
    for(int r=0;r<4;r++){
      int mg = mbase + r;
      int pi = mg & (B_PAIR-1);
      int lp = tp[2*pi], rp = tp[2*pi+1];
      float cv = cvec[mg], al = alpha[mg], be = betav[mg];
      float mx = -INFINITY, sm = 0.f;
      #pragma unroll
      for(int j=0;j<4;j++){
        float u = fmaf(2.f, acc[i][j][r], cv - qv[j]);
        float z = fmaf(al, u, be);
        if(jv[j]==lp || jv[j]==rp) z = (lp==rp) ? fmaf(-al, u, be) : be;
        if(z > mx){ sm = sm*__expf(mx - z) + 1.f; mx = z; }
        else sm += __expf(z - mx);
      }
      #pragma unroll
      for(int m=8;m>=1;m>>=1){
        float om = __shfl_xor(mx, m, 64), os = __shfl_xor(sm, m, 64);
        lseMerge(mx, sm, om, os);
      }
      if(l15==0){ pm[(size_t)mg*PTILES + ptile] = mx; ps[(size_t)mg*PTILES + ptile] = sm; }
    }
  }
}

// ---- combine per-tile LSE partials: block per row ----
__global__ __launch_bounds__(256) void k_lse(const float* __restrict__ pm, const float* __restrict__ ps, float* lse){
  __shared__ float shm[256], shs[256];
  int row = blockIdx.x, tid = threadIdx.x;
  float mx = -INFINITY, sm = 0.f;
  for(int t=tid;t<PTILES;t+=256) lseMerge(mx, sm, pm[(size_t)row*PTILES+t], ps[(size_t)row*PTILES+t]);
  shm[tid]=mx; shs[tid]=sm;
  __syncthreads();
  for(int w=128;w>0;w>>=1){
    if(tid<w){
      float m2=shm[tid], s2=shs[tid];
      lseMerge(m2, s2, shm[tid+w], shs[tid+w]);
      shm[tid]=m2; shs[tid]=s2;
    }
    __syncthreads();
  }
  if(tid==0) lse[row] = shm[0] + logf(shs[0]);
}

// ---- final mean ----
__global__ __launch_bounds__(256) void k_final(const float* __restrict__ lse, float* out){
  __shared__ double sh[256];
  int tid = threadIdx.x;
  double s = 0.0;
  for(int i=tid;i<B_PAIR;i+=256) s += (double)lse[i] + (double)lse[B_PAIR+i];
  sh[tid]=s; __syncthreads();
  for(int w=128;w>0;w>>=1){ if(tid<w) sh[tid]+=sh[tid+w]; __syncthreads(); }
  if(tid==0) out[0] = (float)(sh[0] / (double)B_PAIR);
}

extern "C" void kernel_launch(void* const* d_in, const int* in_sizes, int n_in,
                              void* d_out, int out_size, void* d_ws, size_t ws_size,
                              hipStream_t stream) {
  const float* ent_emb = (const float*)d_in[0];
  const float* rel_emb = (const float*)d_in[1];
  const float* attn_e  = (const float*)d_in[2];
  const float* attn_r  = (const float*)d_in[3];
  const int* adj     = (const int*)d_in[5];
  const int* r_index = (const int*)d_in[6];
  const int* ent_adj = (const int*)d_in[7];
  const int* rel_adj = (const int*)d_in[8];
  const int* tp      = (const int*)d_in[9];
  float* out = (float*)d_out;

  const int* adj_row = adj;
  const int* adj_col = adj + T_EDGE;
  const int* rid1    = r_index + T_EDGE;

  char* base = (char*)d_ws;
  size_t off = 0;
  auto A = [&](size_t b)->void*{ void* p = base + off; off = (off + b + 255) & ~(size_t)255; return p; };
  // zero region
  int*   cntA  = (int*)  A((size_t)N_ENT*4);
  int*   cntE  = (int*)  A((size_t)N_ENT*4);
  int*   cntR  = (int*)  A((size_t)N_ENT*4);
  float* G     = (float*)A((size_t)EMBD*EMBD*4);
  float* Svec  = (float*)A(EMBD*4);
  float* Pvec  = (float*)A(EMBD*4);
  float* QQ    = (float*)A(2*4);
  size_t zero_end = off;
  // plain buffers
  int* startA = (int*)A((size_t)(N_ENT+1)*4);
  int* startE = (int*)A((size_t)(N_ENT+1)*4);
  int* startR = (int*)A((size_t)(N_ENT+1)*4);
  int* curA   = (int*)A((size_t)N_ENT*4);
  int* curE   = (int*)A((size_t)N_ENT*4);
  int* curR   = (int*)A((size_t)N_ENT*4);
  int* scolA  = (int*)A((size_t)T_EDGE*4);
  int* sridA  = (int*)A((size_t)T_EDGE*4);
  int* scolE  = (int*)A((size_t)NNZ_E*4);
  int* scolR  = (int*)A((size_t)NNZ_E*4);
  _Float16* Eh = (_Float16*)A((size_t)NPAD*EMBD*2);   // padded rows zeroed below
  // region X: phase-aliased (featC0/featC1 -> embT -> pm/ps)
  char* X = (char*)A((size_t)EMBD*NPAD*2);   // 47.2 MB
  _Float16* featC0 = (_Float16*)X;                       // 15.4 MB
  _Float16* featC1 = (_Float16*)(X + 16u*1024u*1024u);   // 15.4 MB
  _Float16* embT   = (_Float16*)X;
  float*    pm     = (float*)X;                          // 2048*480*4 = 3.93 MB
  float*    ps     = (float*)(X + 8u*1024u*1024u);
  _Float16* relnH  = (_Float16*)A((size_t)R_REL*128*2);
  _Float16* ehE   = (_Float16*)A((size_t)N_ENT*128*2);
  _Float16* ehR   = (_Float16*)A((size_t)R_REL*128*2);
  float* expdot  = (float*)A(4*R_REL*4);
  _Float16* Wh   = (_Float16*)A((size_t)2*B_PAIR*EMBD*2);
  _Float16* Gh   = (_Float16*)A((size_t)EMBD*EMBD*2);
  float* Tm      = (float*)A((size_t)2*B_PAIR*EMBD*4);
  float* cvec    = (float*)A(2*B_PAIR*4);
  float* qn      = (float*)A((size_t)NPAD*4);
  float* alpha   = (float*)A(2*B_PAIR*4);
  float* betav   = (float*)A(2*B_PAIR*4);
  float* lse     = (float*)A(2*B_PAIR*4);
  (void)ws_size; (void)in_sizes; (void)n_in; (void)out_size;

  hipMemsetAsync(d_ws, 0, zero_end, stream);
  hipMemsetAsync(Eh + (size_t)N_ENT*EMBD, 0, (size_t)(NPAD-N_ENT)*EMBD*2, stream);

  // ---- CSR builds (fused launches) ----
  k_count3<<<(NNZ_E+255)/256, 256, 0, stream>>>(adj_row, cntA, ent_adj, cntE, rel_adj, cntR);
  k_scan3<<<3, 1024, 0, stream>>>(cntA, startA, curA, cntE, startE, curE, cntR, startR, curR);
  k_scatter3<<<(NNZ_E+255)/256, 256, 0, stream>>>(adj_row, adj_col, rid1, curA, scolA, sridA,
                                                  ent_adj, ent_adj+NNZ_E, curE, scolE,
                                                  rel_adj, rel_adj+NNZ_E, curR, scolR);

  k_cvtemb<<<(N_ENT*128+255)/256, 256, 0, stream>>>(ent_emb, rel_emb, ehE, ehR);
  k_relnorm<<<R_REL/4, 256, 0, stream>>>(rel_emb, attn_e, attn_r, relnH, expdot);

  // ---- fused dual GAT stack: avg (ent|rel merged) -> layer0 -> layer1 ----
  dim3 gavg(N_ENT/4, 2);
  k_avg2<<<gavg, 256, 0, stream>>>(startE, scolE, ehE, startR, scolR, ehR, featC0, Eh);
  k_edge2<<<N_ENT/4, 256, 0, stream>>>(startA, scolA, sridA, relnH, expdot + 0*R_REL, expdot + 2*R_REL,
                                       featC0, featC1, Eh, 128, 512);
  k_edge2<<<N_ENT/4, 256, 0, stream>>>(startA, scolA, sridA, relnH, expdot + 1*R_REL, expdot + 3*R_REL,
                                       featC1, featC0, Eh, 256, 640);

  // ---- align loss ----
  k_gather<<<B_PAIR, 256, 0, stream>>>(Eh, tp, Wh, cvec);
  k_qn<<<NPAD/4, 256, 0, stream>>>(Eh, qn);
  k_embstats<<<(N_ENT+31)/32, 256, 0, stream>>>(Eh, qn, Svec, Pvec, QQ);
  dim3 gtr(NPAD/64, 12);
  k_transp<<<gtr, 256, 0, stream>>>(Eh, embT);
  dim3 gsy(6, 6, 8);
  k_syrk<<<gsy, 256, 0, stream>>>(embT, G);
  k_cvtG<<<(EMBD*EMBD+255)/256, 256, 0, stream>>>(G, Gh);
  dim3 gT(EMBD/64, 4);
  k_gemmTh<<<gT, 256, 0, stream>>>(Wh, Gh, Tm);
  k_rowstats<<<2*B_PAIR/4, 256, 0, stream>>>(Wh, Tm, Eh, qn, cvec, tp, Svec, Pvec, QQ, alpha, betav);
  k_gemmB<<<NT128*8, 256, 0, stream>>>(Wh, Eh, cvec, qn, tp, alpha, betav, pm, ps);
  k_lse<<<2*B_PAIR, 256, 0, stream>>>(pm, ps, lse);
  k_final<<<1, 256, 0, stream>>>(lse, out);
}

// Round 10
// 889.393 us; speedup vs baseline: 5.6363x; 1.0290x over previous
//
#include <hip/hip_runtime.h>
#include <math.h>

#define N_ENT 30000
#define R_REL 1000
#define T_EDGE 300000
#define B_PAIR 1024
#define NNZ_E 600000
#define GAMMAF 3.0f
#define EPSV 1e-12f
#define EMBD 768
#define NPAD 30720           // N_ENT padded to 240 tiles of 128 (zeroed pad rows in Eh; qn[pad]=1e30)
#define NT128 240            // n-tiles of 128 for gemmB
#define PTILES 480           // lse partial tiles per row (2 per 128-tile)

typedef _Float16 half8 __attribute__((ext_vector_type(8)));
typedef _Float16 half4v __attribute__((ext_vector_type(4)));
typedef _Float16 half2v __attribute__((ext_vector_type(2)));
typedef float f32x4 __attribute__((ext_vector_type(4)));

__device__ inline void gl_lds16(const _Float16* g, _Float16* l){
  __builtin_amdgcn_global_load_lds(
      (const __attribute__((address_space(1))) unsigned int*)g,
      (__attribute__((address_space(3))) unsigned int*)l, 16, 0, 0);
}

__device__ inline float waveRedSum(float v){
  #pragma unroll
  for(int m=32;m>=1;m>>=1) v += __shfl_xor(v, m, 64);
  return v;
}

__device__ inline float fast_tanh(float x){
  x = fminf(10.f, fmaxf(-10.f, x));
  float e = __expf(2.f*x);
  return (e-1.f)/(e+1.f);
}

// ---- edge-count: all three lists in one launch ----
__global__ __launch_bounds__(256) void k_count3(const int* __restrict__ rA, int* cA,
                                                const int* __restrict__ rE, int* cE,
                                                const int* __restrict__ rR, int* cR){
  int e = blockIdx.x*256 + threadIdx.x;
  if(e < T_EDGE) atomicAdd(&cA[rA[e]], 1);
  if(e < NNZ_E){ atomicAdd(&cE[rE[e]], 1); atomicAdd(&cR[rR[e]], 1); }
}

// ---- 3 exclusive scans in one launch (block per list), wave-level scan ----
__global__ __launch_bounds__(1024) void k_scan3(const int* c0, int* s0, int* u0,
                                                const int* c1, int* s1, int* u1,
                                                const int* c2, int* s2, int* u2){
  const int* cnt = blockIdx.x==0 ? c0 : (blockIdx.x==1 ? c1 : c2);
  int* start     = blockIdx.x==0 ? s0 : (blockIdx.x==1 ? s1 : s2);
  int* cursor    = blockIdx.x==0 ? u0 : (blockIdx.x==1 ? u1 : u2);
  __shared__ int wsum[16];
  __shared__ int carry;
  int tid = threadIdx.x, lane = tid & 63, wid = tid >> 6;
  if(tid==0) carry = 0;
  __syncthreads();
  for(int base=0; base<N_ENT; base+=1024){
    int i = base + tid;
    int v = (i<N_ENT)? cnt[i] : 0;
    int x = v;
    #pragma unroll
    for(int off=1; off<64; off<<=1){ int t=__shfl_up(x,off,64); if(lane>=off) x+=t; }
    if(lane==63) wsum[wid]=x;
    __syncthreads();
    if(wid==0){
      int s = (lane<16)? wsum[lane] : 0;
      #pragma unroll
      for(int off=1; off<16; off<<=1){ int t=__shfl_up(s,off,64); if(lane>=off) s+=t; }
      if(lane<16) wsum[lane]=s;
    }
    __syncthreads();
    int wexcl = (wid==0)? 0 : wsum[wid-1];
    int excl = carry + wexcl + x - v;
    if(i<N_ENT){ start[i]=excl; cursor[i]=excl; }
    int tot = wsum[15];
    __syncthreads();
    if(tid==0) carry += tot;
    __syncthreads();
  }
  if(tid==0) start[N_ENT] = carry;
}

// ---- scatter all three edge lists into CSR order, one launch ----
__global__ __launch_bounds__(256) void k_scatter3(
      const int* __restrict__ rA, const int* __restrict__ cAj, const int* __restrict__ rid,
      int* uA, int* scolA, int* sridA,
      const int* __restrict__ rE, const int* __restrict__ cEj, int* uE, int* scolE,
      const int* __restrict__ rR, const int* __restrict__ cRj, int* uR, int* scolR){
  int e = blockIdx.x*256 + threadIdx.x;
  if(e < T_EDGE){
    int p = atomicAdd(&uA[rA[e]], 1);
    scolA[p] = cAj[e];
    sridA[p] = rid[e];
  }
  if(e < NNZ_E){
    int p = atomicAdd(&uE[rE[e]], 1);
    scolE[p] = cEj[e];
    int q = atomicAdd(&uR[rR[e]], 1);
    scolR[q] = cRj[e];
  }
}

// ---- fused prep: fp16 convert embeddings + zero Eh pad rows + relnorm/expdot tables ----
__global__ __launch_bounds__(256) void k_prep(const float* __restrict__ ent, const float* __restrict__ rel,
      const float* __restrict__ ae, const float* __restrict__ ar,
      _Float16* ehE, _Float16* ehR, _Float16* Eh, _Float16* relnH, float* expdot){
  int i = blockIdx.x*256 + threadIdx.x;
  if(i < N_ENT*128) ehE[i] = (_Float16)ent[i];
  if(i < R_REL*128) ehR[i] = (_Float16)rel[i];
  if(i < (NPAD-N_ENT)*EMBD) Eh[(size_t)N_ENT*EMBD + i] = (_Float16)0.f;
  int r = i >> 6;
  if(r < R_REL){
    int lane = i & 63;
    float2 v = *(const float2*)(rel + (size_t)r*128 + lane*2);
    float ss = waveRedSum(v.x*v.x + v.y*v.y);
    float nrm = fmaxf(sqrtf(ss), EPSV);
    float2 u; u.x = v.x/nrm; u.y = v.y/nrm;
    half2v uh = {(_Float16)u.x, (_Float16)u.y};
    *(half2v*)(relnH + (size_t)r*128 + lane*2) = uh;
    const float* ks[4] = {ae, ae+128, ar, ar+128};   // ent l0, ent l1, rel l0, rel l1
    #pragma unroll
    for(int k=0;k<4;k++){
      float2 w = *(const float2*)(ks[k] + lane*2);
      float d = waveRedSum(u.x*w.x + u.y*w.y);
      if(lane==0) expdot[k*R_REL + r] = __expf(d);
    }
  }
}

// ---- _avg via CSR gather from fp16 src (ent: y=0, rel: y=1), fused tanh ----
__global__ __launch_bounds__(256) void k_avg2(const int* __restrict__ startE, const int* __restrict__ scolE,
                        const _Float16* __restrict__ srcE,
                        const int* __restrict__ startR, const int* __restrict__ scolR,
                        const _Float16* __restrict__ srcR,
                        _Float16* featC, _Float16* Eh){
  int which = blockIdx.y;
  const int* start = which? startR : startE;
  const int* scol  = which? scolR : scolE;
  const _Float16* src = which? srcR : srcE;
  int pairOff = which? 2 : 0;
  int coloff  = which? 384 : 0;
  int r = blockIdx.x*4 + (threadIdx.x>>6);
  int lane = threadIdx.x & 63;
  int s0 = start[r], s1 = start[r+1];
  float ax=0.f, ay=0.f;
  int e = s0;
  for(; e+1<s1; e+=2){
    int c0 = scol[e], c1 = scol[e+1];
    half2v v0 = *(const half2v*)(src + (size_t)c0*128 + lane*2);
    half2v v1 = *(const half2v*)(src + (size_t)c1*128 + lane*2);
    ax += (float)v0[0] + (float)v1[0]; ay += (float)v0[1] + (float)v1[1];
  }
  if(e<s1){
    int c0 = scol[e];
    half2v v0 = *(const half2v*)(src + (size_t)c0*128 + lane*2);
    ax += (float)v0[0]; ay += (float)v0[1];
  }
  float inv = (s1>s0) ? 1.0f/(float)(s1-s0) : 0.f;
  float vx = fast_tanh(ax*inv), vy = fast_tanh(ay*inv);
  half2v hv = {(_Float16)vx, (_Float16)vy};
  *(half2v*)(featC + (size_t)r*256 + lane*4 + pairOff) = hv;
  *(half2v*)(Eh + (size_t)r*EMBD + coloff + lane*2) = hv;
}

// ---- fused dual-stack GAT layer: one pass does ent+rel Householder+softmax ----
__global__ __launch_bounds__(256) void k_edge2(const int* __restrict__ start, const int* __restrict__ scol,
      const int* __restrict__ srid, const _Float16* __restrict__ relnH,
      const float* __restrict__ expE, const float* __restrict__ expR,
      const _Float16* __restrict__ featIn, _Float16* featOut, _Float16* Eh, int colEnt, int colRel){
  int r = blockIdx.x*4 + (threadIdx.x>>6);
  int lane = threadIdx.x & 63;
  int s0 = start[r], s1 = start[r+1];
  float aEx=0,aEy=0,aRx=0,aRy=0, swE=0, swR=0;
  int e = s0;
  for(; e+1<s1; e+=2){
    int c0=scol[e], q0=srid[e], c1=scol[e+1], q1=srid[e+1];
    float wE0=expE[q0], wR0=expR[q0], wE1=expE[q1], wR1=expR[q1];
    half2v u0h = *(const half2v*)(relnH + (size_t)q0*128 + lane*2);
    half2v u1h = *(const half2v*)(relnH + (size_t)q1*128 + lane*2);
    half4v h0 = *(const half4v*)(featIn + (size_t)c0*256 + lane*4);
    half4v h1 = *(const half4v*)(featIn + (size_t)c1*256 + lane*4);
    float u0x=(float)u0h[0], u0y=(float)u0h[1], u1x=(float)u1h[0], u1y=(float)u1h[1];
    float e0x=(float)h0[0], e0y=(float)h0[1], r0x=(float)h0[2], r0y=(float)h0[3];
    float e1x=(float)h1[0], e1y=(float)h1[1], r1x=(float)h1[2], r1y=(float)h1[3];
    float d0 = e0x*u0x + e0y*u0y;
    float d1 = r0x*u0x + r0y*u0y;
    float d2 = e1x*u1x + e1y*u1y;
    float d3 = r1x*u1x + r1y*u1y;
    #pragma unroll
    for(int m=32;m>=1;m>>=1){
      d0 += __shfl_xor(d0,m,64); d1 += __shfl_xor(d1,m,64);
      d2 += __shfl_xor(d2,m,64); d3 += __shfl_xor(d3,m,64);
    }
    aEx += wE0*(e0x - 2.f*d0*u0x) + wE1*(e1x - 2.f*d2*u1x);
    aEy += wE0*(e0y - 2.f*d0*u0y) + wE1*(e1y - 2.f*d2*u1y);
    aRx += wR0*(r0x - 2.f*d1*u0x) + wR1*(r1x - 2.f*d3*u1x);
    aRy += wR0*(r0y - 2.f*d1*u0y) + wR1*(r1y - 2.f*d3*u1y);
    swE += wE0+wE1; swR += wR0+wR1;
  }
  if(e<s1){
    int c0=scol[e], q0=srid[e];
    float wE0=expE[q0], wR0=expR[q0];
    half2v u0h = *(const half2v*)(relnH + (size_t)q0*128 + lane*2);
    half4v h0 = *(const half4v*)(featIn + (size_t)c0*256 + lane*4);
    float u0x=(float)u0h[0], u0y=(float)u0h[1];
    float e0x=(float)h0[0], e0y=(float)h0[1], r0x=(float)h0[2], r0y=(float)h0[3];
    float d0 = e0x*u0x + e0y*u0y;
    float d1 = r0x*u0x + r0y*u0y;
    #pragma unroll
    for(int m=32;m>=1;m>>=1){ d0 += __shfl_xor(d0,m,64); d1 += __shfl_xor(d1,m,64); }
    aEx += wE0*(e0x - 2.f*d0*u0x);
    aEy += wE0*(e0y - 2.f*d0*u0y);
    aRx += wR0*(r0x - 2.f*d1*u0x);
    aRy += wR0*(r0y - 2.f*d1*u0y);
    swE += wE0; swR += wR0;
  }
  float iE = (s1>s0) ? 1.f/swE : 0.f;
  float iR = (s1>s0) ? 1.f/swR : 0.f;
  float vEx = fast_tanh(aEx*iE), vEy = fast_tanh(aEy*iE);
  float vRx = fast_tanh(aRx*iR), vRy = fast_tanh(aRy*iR);
  half4v ov = {(_Float16)vEx,(_Float16)vEy,(_Float16)vRx,(_Float16)vRy};
  *(half4v*)(featOut + (size_t)r*256 + lane*4) = ov;
  half2v he = {(_Float16)vEx,(_Float16)vEy};
  half2v hr = {(_Float16)vRx,(_Float16)vRy};
  *(half2v*)(Eh + (size_t)r*EMBD + colEnt + lane*2) = he;
  *(half2v*)(Eh + (size_t)r*EMBD + colRel + lane*2) = hr;
}

// ---- gather pair rows from Eh -> Wh fp16, cvec ----
__global__ __launch_bounds__(256) void k_gather(const _Float16* __restrict__ Eh, const int* __restrict__ tp,
                         _Float16* Wh, float* cvec){
  int i = blockIdx.x; int tid = threadIdx.x;
  int l = tp[2*i], r = tp[2*i+1];
  float sl=0.f, sr=0.f, sp=0.f;
  for(int c=tid;c<EMBD;c+=256){
    _Float16 lh = Eh[(size_t)l*EMBD+c], rh = Eh[(size_t)r*EMBD+c];
    float le = (float)lh, re = (float)rh;
    Wh[(size_t)i*EMBD+c]=lh; Wh[(size_t)(B_PAIR+i)*EMBD+c]=rh;
    sl += le*le; sr += re*re; float d = le-re; sp += d*d;
  }
  __shared__ float s0[256], s1[256], s2[256];
  s0[tid]=sl; s1[tid]=sr; s2[tid]=sp;
  __syncthreads();
  for(int w=128;w>0;w>>=1){
    if(tid<w){ s0[tid]+=s0[tid+w]; s1[tid]+=s1[tid+w]; s2[tid]+=s2[tid+w]; }
    __syncthreads();
  }
  if(tid==0){
    float pos = s2[0];
    cvec[i]        = pos + GAMMAF - s0[0];
    cvec[B_PAIR+i] = pos + GAMMAF - s1[0];
  }
}

// ---- fused qn + embstats: wave per row (strided), one 46 MB pass ----
// qn[j]=||e_j||^2 (pad rows 1e30); Svec=sum e; Pvec=sum q e; QQ={sum q, sum q^2}
__global__ __launch_bounds__(256) void k_qnstats(const _Float16* __restrict__ Eh, float* qn,
                           float* Svec, float* Pvec, float* QQ){
  int wid = threadIdx.x>>6, lane = threadIdx.x&63;
  int gw = blockIdx.x*4 + wid;   // 960 waves total
  float s[12], p[12];
  #pragma unroll
  for(int q=0;q<12;q++){ s[q]=0.f; p[q]=0.f; }
  float q1=0.f, q2=0.f;
  for(int r=gw; r<NPAD; r+=960){
    if(r >= N_ENT){ if(lane==0) qn[r] = 1e30f; continue; }
    float v[12]; float ss=0.f;
    #pragma unroll
    for(int q=0;q<12;q++){ v[q] = (float)Eh[(size_t)r*EMBD + lane + 64*q]; ss += v[q]*v[q]; }
    ss = waveRedSum(ss);
    if(lane==0){ qn[r] = ss; q1 += ss; q2 += ss*ss; }
    #pragma unroll
    for(int q=0;q<12;q++){ s[q] += v[q]; p[q] += ss*v[q]; }
  }
  #pragma unroll
  for(int q=0;q<12;q++){
    unsafeAtomicAdd(&Svec[lane + 64*q], s[q]);
    unsafeAtomicAdd(&Pvec[lane + 64*q], p[q]);
  }
  if(lane==0){ unsafeAtomicAdd(&QQ[0], q1); unsafeAtomicAdd(&QQ[1], q2); }
}

// ---- transpose Eh (30000x768) -> embT (768 x NPAD), zero-padded ----
__global__ __launch_bounds__(256) void k_transp(const _Float16* __restrict__ Eh, _Float16* embT){
  __shared__ __align__(16) _Float16 til[64][72];
  int r0 = blockIdx.x*64, c0 = blockIdx.y*64;
  int t = threadIdx.x;
  int rr = t>>3, c8 = (t&7)*8;
  #pragma unroll
  for(int p=0;p<2;p++){
    int gr = r0 + rr + p*32;
    uint4 v = make_uint4(0u,0u,0u,0u);
    if(gr < N_ENT) v = *(const uint4*)(Eh + (size_t)gr*EMBD + c0 + c8);
    *(uint4*)&til[rr + p*32][c8] = v;
  }
  __syncthreads();
  #pragma unroll
  for(int p=0;p<2;p++){
    int cc = rr + p*32;
    __align__(16) _Float16 tmp[8];
    #pragma unroll
    for(int j=0;j<8;j++) tmp[j] = til[c8 + j][cc];
    *(uint4*)(embT + (size_t)(c0+cc)*NPAD + r0 + c8) = *(uint4*)tmp;
  }
}

// ---- G = E^T E via f16 MFMA on embT; 128x128 tiles, DMA staging + XOR swizzle, split-K atomics ----
__global__ __launch_bounds__(256) void k_syrk(const _Float16* __restrict__ embT, float* G){
  __shared__ __align__(16) _Float16 As[128*64];
  __shared__ __align__(16) _Float16 Bs[128*64];
  int tid = threadIdx.x;
  int w = tid>>6, lane = tid&63;
  int quad = lane>>4, l15 = lane&15;
  int lr = lane>>3, lc = lane&7;
  int wm = (w>>1)*64, wn = (w&1)*64;
  int m0 = blockIdx.y*128, n0 = blockIdx.x*128;
  int kbeg = blockIdx.z*3840;
  int kend = kbeg + 3840; if(kend > NPAD) kend = NPAD;
  f32x4 acc[4][4];
  #pragma unroll
  for(int i=0;i<4;i++)
    #pragma unroll
    for(int j=0;j<4;j++) acc[i][j] = (f32x4){0.f,0.f,0.f,0.f};
  for(int k0=kbeg;k0<kend;k0+=64){
    #pragma unroll
    for(int p=0;p<4;p++){
      int r = p*32 + w*8 + lr;
      int cg = lc ^ (r&7);
      gl_lds16(embT + (size_t)(m0+r)*NPAD + k0 + cg*8, As + (p*32 + w*8)*64);
      gl_lds16(embT + (size_t)(n0+r)*NPAD + k0 + cg*8, Bs + (p*32 + w*8)*64);
    }
    __syncthreads();
    #pragma unroll
    for(int ks=0;ks<2;ks++){
      half8 af[4], bf[4];
      #pragma unroll
      for(int i=0;i<4;i++){
        int ml = wm + i*16 + l15;
        af[i] = *(half8*)(As + ml*64 + (((ks<<2)|quad) ^ (ml&7))*8);
      }
      #pragma unroll
      for(int j=0;j<4;j++){
        int nl = wn + j*16 + l15;
        bf[j] = *(half8*)(Bs + nl*64 + (((ks<<2)|quad) ^ (nl&7))*8);
      }
      #pragma unroll
      for(int i=0;i<4;i++)
        #pragma unroll
        for(int j=0;j<4;j++)
          acc[i][j] = __builtin_amdgcn_mfma_f32_16x16x32_f16(af[i], bf[j], acc[i][j], 0,0,0);
    }
    __syncthreads();
  }
  #pragma unroll
  for(int i=0;i<4;i++){
    #pragma unroll
    for(int r=0;r<4;r++){
      int m = m0 + wm + i*16 + quad*4 + r;
      #pragma unroll
      for(int j=0;j<4;j++){
        int n = n0 + wn + j*16 + l15;
        unsafeAtomicAdd(&G[(size_t)m*EMBD + n], acc[i][j][r]);
      }
    }
  }
}

// ---- T = Wh * G (G symmetric, fp32; convert inline), no-LDS MFMA ----
__global__ __launch_bounds__(256) void k_gemmTh(const _Float16* __restrict__ Wh, const float* __restrict__ G,
                                                float* Tm){
  int tid = threadIdx.x, w = tid>>6, lane = tid&63;
  int quad = lane>>4, l15 = lane&15;
  int n0 = blockIdx.x*64;
  #pragma unroll
  for(int half=0; half<2; half++){
    int m0 = (blockIdx.y*8 + half*4 + w)*64;
    f32x4 acc[4][4];
    #pragma unroll
    for(int i=0;i<4;i++)
      #pragma unroll
      for(int j=0;j<4;j++) acc[i][j] = (f32x4){0.f,0.f,0.f,0.f};
    const _Float16* aB[4]; const float* bB[4];
    #pragma unroll
    for(int i=0;i<4;i++){
      aB[i] = Wh + (size_t)(m0+i*16+l15)*EMBD + quad*8;
      bB[i] = G  + (size_t)(n0+i*16+l15)*EMBD + quad*8;
    }
    for(int ks=0; ks<24; ks++){
      half8 af[4], bf[4];
      #pragma unroll
      for(int i=0;i<4;i++) af[i] = *(const half8*)(aB[i] + ks*32);
      #pragma unroll
      for(int j=0;j<4;j++){
        float4 f0 = *(const float4*)(bB[j] + ks*32);
        float4 f1 = *(const float4*)(bB[j] + ks*32 + 4);
        half8 h = {(_Float16)f0.x,(_Float16)f0.y,(_Float16)f0.z,(_Float16)f0.w,
                   (_Float16)f1.x,(_Float16)f1.y,(_Float16)f1.z,(_Float16)f1.w};
        bf[j] = h;
      }
      #pragma unroll
      for(int i=0;i<4;i++)
        #pragma unroll
        for(int j=0;j<4;j++)
          acc[i][j] = __builtin_amdgcn_mfma_f32_16x16x32_f16(af[i], bf[j], acc[i][j], 0,0,0);
    }
    #pragma unroll
    for(int i=0;i<4;i++)
      #pragma unroll
      for(int r=0;r<4;r++){
        int mg = m0 + i*16 + quad*4 + r;
        #pragma unroll
        for(int j=0;j<4;j++)
          Tm[(size_t)mg*EMBD + n0 + j*16 + l15] = acc[i][j][r];
      }
  }
}

// ---- per-row closed-form stats ----
__global__ __launch_bounds__(256) void k_rowstats(const _Float16* __restrict__ Wh, const float* __restrict__ Tm,
      const _Float16* __restrict__ Eh, const float* __restrict__ qn, const float* __restrict__ cvec,
      const int* __restrict__ tp, const float* __restrict__ Svec, const float* __restrict__ Pvec,
      const float* __restrict__ QQ, float* alpha, float* betav){
  int row = blockIdx.x*4 + (threadIdx.x>>6);
  int lane = threadIdx.x & 63;
  if(row >= 2*B_PAIR) return;
  int pi = row & (B_PAIR-1);
  int lp = tp[2*pi], rp = tp[2*pi+1];
  float d1=0,d2=0,d3=0,dl=0,dr=0;
  #pragma unroll
  for(int k=0;k<12;k++){
    int d = lane + 64*k;
    float a = (float)Wh[(size_t)row*EMBD + d];
    d1 += a*Svec[d];
    d2 += a*Pvec[d];
    d3 += a*Tm[(size_t)row*EMBD + d];
    dl += a*(float)Eh[(size_t)lp*EMBD + d];
    dr += a*(float)Eh[(size_t)rp*EMBD + d];
  }
  d1=waveRedSum(d1); d2=waveRedSum(d2); d3=waveRedSum(d3);
  dl=waveRedSum(dl); dr=waveRedSum(dr);
  if(lane==0){
    double c = (double)cvec[row], Q = (double)QQ[0], Q2 = (double)QQ[1], Nn = (double)N_ENT;
    double su  = Nn*c - Q + 2.0*(double)d1;
    double su2 = Nn*c*c - 2.0*c*Q + Q2 + 4.0*(c*(double)d1 - (double)d2) + 4.0*(double)d3;
    double ul = c - (double)qn[lp] + 2.0*(double)dl;
    double ur = c - (double)qn[rp] + 2.0*(double)dr;
    su -= ul + ur;
    if(lp != rp) su2 -= ul*ul + ur*ur;
    double mu = su/Nn;
    double var = su2/Nn - mu*mu;
    double sd = sqrt(fmax(var, 0.0));
    double al = 20.0/sd;
    alpha[row] = (float)al;
    betav[row] = (float)(8.0 - al*mu);
  }
}

__device__ inline void lseMerge(float& mx, float& sm, float om, float os){
  if(om > mx){ sm = sm*expf(mx-om) + os; mx = om; }
  else if(om != -INFINITY){ sm += os*expf(om-mx); }
}

// ---- pass B: 128x128 f16 MFMA (DMA staging + XOR swizzle), in-loop masked online-lse epilogue.
//      1D grid 3840, XCD-ownership: id = xcd + 8*m + 128*tt -> ntile = xcd + 8*tt.
//      __launch_bounds__(256,3): request 3 waves/EU (3 blocks/CU) to overlap the barrier drains.
__global__ __launch_bounds__(256,3) void k_gemmB(const _Float16* __restrict__ Wh, const _Float16* __restrict__ Eh,
    const float* __restrict__ cvec, const float* __restrict__ qn, const int* __restrict__ tp,
    const float* __restrict__ alpha, const float* __restrict__ betav, float* pm, float* ps){
  __shared__ __align__(16) _Float16 As[128*64];
  __shared__ __align__(16) _Float16 Bs[128*64];
  int id = blockIdx.x;
  int ntile = (id & 7) + ((id >> 7) << 3);
  int m0 = ((id >> 3) & 15) * 128;
  int n0 = ntile * 128;
  int tid = threadIdx.x;
  int w = tid>>6, lane = tid&63;
  int quad = lane>>4, l15 = lane&15;
  int lr = lane>>3, lc = lane&7;
  int wm = (w&1)*64, wn = (w>>1)*64;
  f32x4 acc[4][4];
  #pragma unroll
  for(int i=0;i<4;i++)
    #pragma unroll
    for(int j=0;j<4;j++) acc[i][j] = (f32x4){0.f,0.f,0.f,0.f};
  for(int k0=0;k0<EMBD;k0+=64){
    #pragma unroll
    for(int p=0;p<4;p++){
      int r = p*32 + w*8 + lr;
      int cg = lc ^ (r&7);
      gl_lds16(Wh + (size_t)(m0+r)*EMBD + k0 + cg*8, As + (p*32 + w*8)*64);
      gl_lds16(Eh + (size_t)(n0+r)*EMBD + k0 + cg*8, Bs + (p*32 + w*8)*64);
    }
    __syncthreads();
    #pragma unroll
    for(int ks=0;ks<2;ks++){
      half8 af[4], bf[4];
      #pragma unroll
      for(int i=0;i<4;i++){
        int ml = wm + i*16 + l15;
        af[i] = *(half8*)(As + ml*64 + (((ks<<2)|quad) ^ (ml&7))*8);
      }
      #pragma unroll
      for(int j=0;j<4;j++){
        int nl = wn + j*16 + l15;
        bf[j] = *(half8*)(Bs + nl*64 + (((ks<<2)|quad) ^ (nl&7))*8);
      }
      #pragma unroll
      for(int i=0;i<4;i++)
        #pragma unroll
        for(int j=0;j<4;j++)
          acc[i][j] = __builtin_amdgcn_mfma_f32_16x16x32_f16(af[i], bf[j], acc[i][j], 0,0,0);
    }
    __syncthreads();
  }
  // epilogue: masked loss -> z -> online lse over this wave's 64 cols; reduce 16 lanes/row.
  float qv[4]; int jv[4];
  #pragma unroll
  for(int j=0;j<4;j++){ jv[j] = n0 + wn + j*16 + l15; qv[j] = qn[jv[j]]; }
  int ptile = ntile*2 + (w>>1);
  #pragma unroll
  for(int i=0;i<4;i++){
    int mbase = m0 + wm + i*16 + quad*4;
    #pragma unroll
    for(int r=0;r<4;r++){
      int mg = mbase + r;
      int pi = mg & (B_PAIR-1);
      int lp = tp[2*pi], rp = tp[2*pi+1];
      float cv = cvec[mg], al = alpha[mg], be = betav[mg];
      float mx = -INFINITY, sm = 0.f;
      #pragma unroll
      for(int j=0;j<4;j++){
        float u = fmaf(2.f, acc[i][j][r], cv - qv[j]);
        float z = fmaf(al, u, be);
        if(jv[j]==lp || jv[j]==rp) z = (lp==rp) ? fmaf(-al, u, be) : be;
        if(z > mx){ sm = sm*__expf(mx - z) + 1.f; mx = z; }
        else sm += __expf(z - mx);
      }
      #pragma unroll
      for(int m=8;m>=1;m>>=1){
        float om = __shfl_xor(mx, m, 64), os = __shfl_xor(sm, m, 64);
        lseMerge(mx, sm, om, os);
      }
      if(l15==0){ pm[(size_t)mg*PTILES + ptile] = mx; ps[(size_t)mg*PTILES + ptile] = sm; }
    }
  }
}

// ---- combine per-tile LSE partials + fused final mean via atomic ticket: block per row ----
__global__ __launch_bounds__(256) void k_lse2(const float* __restrict__ pm, const float* __restrict__ ps,
                        float* accum, int* done, float* out){
  __shared__ float shm[256], shs[256];
  int row = blockIdx.x, tid = threadIdx.x;
  float mx = -INFINITY, sm = 0.f;
  for(int t=tid;t<PTILES;t+=256) lseMerge(mx, sm, pm[(size_t)row*PTILES+t], ps[(size_t)row*PTILES+t]);
  shm[tid]=mx; shs[tid]=sm;
  __syncthreads();
  for(int w=128;w>0;w>>=1){
    if(tid<w){
      float m2=shm[tid], s2=shs[tid];
      lseMerge(m2, s2, shm[tid+w], shs[tid+w]);
      shm[tid]=m2; shs[tid]=s2;
    }
    __syncthreads();
  }
  if(tid==0){
    float l = shm[0] + logf(shs[0]);
    atomicAdd(accum, l);
    __threadfence();
    int t = atomicAdd(done, 1);
    if(t == 2*B_PAIR - 1){
      __threadfence();
      float total = atomicAdd(accum, 0.0f);   // atomic read includes all adds
      out[0] = total / (float)B_PAIR;
    }
  }
}

extern "C" void kernel_launch(void* const* d_in, const int* in_sizes, int n_in,
                              void* d_out, int out_size, void* d_ws, size_t ws_size,
                              hipStream_t stream) {
  const float* ent_emb = (const float*)d_in[0];
  const float* rel_emb = (const float*)d_in[1];
  const float* attn_e  = (const float*)d_in[2];
  const float* attn_r  = (const float*)d_in[3];
  const int* adj     = (const int*)d_in[5];
  const int* r_index = (const int*)d_in[6];
  const int* ent_adj = (const int*)d_in[7];
  const int* rel_adj = (const int*)d_in[8];
  const int* tp      = (const int*)d_in[9];
  float* out = (float*)d_out;

  const int* adj_row = adj;
  const int* adj_col = adj + T_EDGE;
  const int* rid1    = r_index + T_EDGE;

  char* base = (char*)d_ws;
  size_t off = 0;
  auto A = [&](size_t b)->void*{ void* p = base + off; off = (off + b + 255) & ~(size_t)255; return p; };
  // zero region
  int*   cntA  = (int*)  A((size_t)N_ENT*4);
  int*   cntE  = (int*)  A((size_t)N_ENT*4);
  int*   cntR  = (int*)  A((size_t)N_ENT*4);
  float* G     = (float*)A((size_t)EMBD*EMBD*4);
  float* Svec  = (float*)A(EMBD*4);
  float* Pvec  = (float*)A(EMBD*4);
  float* QQ    = (float*)A(2*4);
  float* accum = (float*)A(4);
  int*   done  = (int*)  A(4);
  size_t zero_end = off;
  // plain buffers
  int* startA = (int*)A((size_t)(N_ENT+1)*4);
  int* startE = (int*)A((size_t)(N_ENT+1)*4);
  int* startR = (int*)A((size_t)(N_ENT+1)*4);
  int* curA   = (int*)A((size_t)N_ENT*4);
  int* curE   = (int*)A((size_t)N_ENT*4);
  int* curR   = (int*)A((size_t)N_ENT*4);
  int* scolA  = (int*)A((size_t)T_EDGE*4);
  int* sridA  = (int*)A((size_t)T_EDGE*4);
  int* scolE  = (int*)A((size_t)NNZ_E*4);
  int* scolR  = (int*)A((size_t)NNZ_E*4);
  _Float16* Eh = (_Float16*)A((size_t)NPAD*EMBD*2);   // pad rows zeroed in k_prep
  // region X: phase-aliased (featC0/featC1 -> embT -> pm/ps)
  char* X = (char*)A((size_t)EMBD*NPAD*2);   // 47.2 MB
  _Float16* featC0 = (_Float16*)X;                       // 15.4 MB
  _Float16* featC1 = (_Float16*)(X + 16u*1024u*1024u);   // 15.4 MB
  _Float16* embT   = (_Float16*)X;
  float*    pm     = (float*)X;                          // 2048*480*4 = 3.93 MB
  float*    ps     = (float*)(X + 8u*1024u*1024u);
  _Float16* relnH  = (_Float16*)A((size_t)R_REL*128*2);
  _Float16* ehE   = (_Float16*)A((size_t)N_ENT*128*2);
  _Float16* ehR   = (_Float16*)A((size_t)R_REL*128*2);
  float* expdot  = (float*)A(4*R_REL*4);
  _Float16* Wh   = (_Float16*)A((size_t)2*B_PAIR*EMBD*2);
  float* Tm      = (float*)A((size_t)2*B_PAIR*EMBD*4);
  float* cvec    = (float*)A(2*B_PAIR*4);
  float* qn      = (float*)A((size_t)NPAD*4);
  float* alpha   = (float*)A(2*B_PAIR*4);
  float* betav   = (float*)A(2*B_PAIR*4);
  (void)ws_size; (void)in_sizes; (void)n_in; (void)out_size;

  hipMemsetAsync(d_ws, 0, zero_end, stream);

  // ---- CSR builds (fused launches) ----
  k_count3<<<(NNZ_E+255)/256, 256, 0, stream>>>(adj_row, cntA, ent_adj, cntE, rel_adj, cntR);
  k_scan3<<<3, 1024, 0, stream>>>(cntA, startA, curA, cntE, startE, curE, cntR, startR, curR);
  k_scatter3<<<(NNZ_E+255)/256, 256, 0, stream>>>(adj_row, adj_col, rid1, curA, scolA, sridA,
                                                  ent_adj, ent_adj+NNZ_E, curE, scolE,
                                                  rel_adj, rel_adj+NNZ_E, curR, scolR);

  // ---- fused prep: emb fp16 conversion + Eh pad zero + relnorm/expdot ----
  k_prep<<<(N_ENT*128+255)/256, 256, 0, stream>>>(ent_emb, rel_emb, attn_e, attn_r,
                                                  ehE, ehR, Eh, relnH, expdot);

  // ---- fused dual GAT stack: avg (ent|rel merged) -> layer0 -> layer1 ----
  dim3 gavg(N_ENT/4, 2);
  k_avg2<<<gavg, 256, 0, stream>>>(startE, scolE, ehE, startR, scolR, ehR, featC0, Eh);
  k_edge2<<<N_ENT/4, 256, 0, stream>>>(startA, scolA, sridA, relnH, expdot + 0*R_REL, expdot + 2*R_REL,
                                       featC0, featC1, Eh, 128, 512);
  k_edge2<<<N_ENT/4, 256, 0, stream>>>(startA, scolA, sridA, relnH, expdot + 1*R_REL, expdot + 3*R_REL,
                                       featC1, featC0, Eh, 256, 640);

  // ---- align loss ----
  k_gather<<<B_PAIR, 256, 0, stream>>>(Eh, tp, Wh, cvec);
  k_qnstats<<<240, 256, 0, stream>>>(Eh, qn, Svec, Pvec, QQ);
  dim3 gtr(NPAD/64, 12);
  k_transp<<<gtr, 256, 0, stream>>>(Eh, embT);
  dim3 gsy(6, 6, 8);
  k_syrk<<<gsy, 256, 0, stream>>>(embT, G);
  dim3 gT(EMBD/64, 4);
  k_gemmTh<<<gT, 256, 0, stream>>>(Wh, G, Tm);
  k_rowstats<<<2*B_PAIR/4, 256, 0, stream>>>(Wh, Tm, Eh, qn, cvec, tp, Svec, Pvec, QQ, alpha, betav);
  k_gemmB<<<NT128*16, 256, 0, stream>>>(Wh, Eh, cvec, qn, tp, alpha, betav, pm, ps);
  k_lse2<<<2*B_PAIR, 256, 0, stream>>>(pm, ps, accum, done, out);
}

// Round 11
// 880.992 us; speedup vs baseline: 5.6900x; 1.0095x over previous
//
#include <hip/hip_runtime.h>
#include <math.h>

#define N_ENT 30000
#define R_REL 1000
#define T_EDGE 300000
#define B_PAIR 1024
#define NNZ_E 600000
#define GAMMAF 3.0f
#define EPSV 1e-12f
#define EMBD 768
#define NPAD 30720           // N_ENT padded to 240 tiles of 128 (zeroed pad rows in Eh; qn[pad]=1e30)
#define NT128 240            // n-tiles of 128 for gemmB
#define PTILES 480           // lse partial tiles per row (2 per 128-tile)
#define SCB 118              // scan blocks per list (118*256 >= 30000)

typedef _Float16 half8 __attribute__((ext_vector_type(8)));
typedef _Float16 half4v __attribute__((ext_vector_type(4)));
typedef _Float16 half2v __attribute__((ext_vector_type(2)));
typedef float f32x4 __attribute__((ext_vector_type(4)));

__device__ inline void gl_lds16(const _Float16* g, _Float16* l){
  __builtin_amdgcn_global_load_lds(
      (const __attribute__((address_space(1))) unsigned int*)g,
      (__attribute__((address_space(3))) unsigned int*)l, 16, 0, 0);
}

__device__ inline float waveRedSum(float v){
  #pragma unroll
  for(int m=32;m>=1;m>>=1) v += __shfl_xor(v, m, 64);
  return v;
}

__device__ inline float fast_tanh(float x){
  x = fminf(10.f, fmaxf(-10.f, x));
  float e = __expf(2.f*x);
  return (e-1.f)/(e+1.f);
}

// ---- fused prep: fp16 convert embeddings + zero Eh pad rows + relnorm/expdot + edge counts ----
__global__ __launch_bounds__(256) void k_prep(const float* __restrict__ ent, const float* __restrict__ rel,
      const float* __restrict__ ae, const float* __restrict__ ar,
      _Float16* ehE, _Float16* ehR, _Float16* Eh, _Float16* relnH, float* expdot,
      const int* __restrict__ rA, int* cA, const int* __restrict__ rE, int* cE,
      const int* __restrict__ rR, int* cR){
  int i = blockIdx.x*256 + threadIdx.x;
  if(i < N_ENT*128) ehE[i] = (_Float16)ent[i];
  if(i < R_REL*128) ehR[i] = (_Float16)rel[i];
  if(i < (NPAD-N_ENT)*EMBD) Eh[(size_t)N_ENT*EMBD + i] = (_Float16)0.f;
  if(i < T_EDGE) atomicAdd(&cA[rA[i]], 1);
  if(i < NNZ_E){ atomicAdd(&cE[rE[i]], 1); atomicAdd(&cR[rR[i]], 1); }
  int r = i >> 6;
  if(r < R_REL){
    int lane = i & 63;
    float2 v = *(const float2*)(rel + (size_t)r*128 + lane*2);
    float ss = waveRedSum(v.x*v.x + v.y*v.y);
    float nrm = fmaxf(sqrtf(ss), EPSV);
    float2 u; u.x = v.x/nrm; u.y = v.y/nrm;
    half2v uh = {(_Float16)u.x, (_Float16)u.y};
    *(half2v*)(relnH + (size_t)r*128 + lane*2) = uh;
    const float* ks[4] = {ae, ae+128, ar, ar+128};   // ent l0, ent l1, rel l0, rel l1
    #pragma unroll
    for(int k=0;k<4;k++){
      float2 w = *(const float2*)(ks[k] + lane*2);
      float d = waveRedSum(u.x*w.x + u.y*w.y);
      if(lane==0) expdot[k*R_REL + r] = __expf(d);
    }
  }
}

// ---- scan phase A: per-block exclusive scan + block totals; grid (SCB, 3) ----
__global__ __launch_bounds__(256) void k_scanA(const int* c0, const int* c1, const int* c2,
                                               int* s0, int* s1, int* s2, int* part){
  const int* cnt = blockIdx.y==0 ? c0 : (blockIdx.y==1 ? c1 : c2);
  int* start     = blockIdx.y==0 ? s0 : (blockIdx.y==1 ? s1 : s2);
  __shared__ int wsum[4];
  int i = blockIdx.x*256 + threadIdx.x;
  int lane = threadIdx.x & 63, wid = threadIdx.x >> 6;
  int v = (i < N_ENT) ? cnt[i] : 0;
  int x = v;
  #pragma unroll
  for(int off=1; off<64; off<<=1){ int t=__shfl_up(x,off,64); if(lane>=off) x+=t; }
  if(lane==63) wsum[wid] = x;
  __syncthreads();
  int woff = 0;
  #pragma unroll
  for(int k=0;k<3;k++) if(k < wid) woff += wsum[k];
  if(i < N_ENT) start[i] = woff + x - v;
  if(threadIdx.x == 255) part[blockIdx.y*SCB + blockIdx.x] = woff + x;
}

// ---- scan phase B: 1 block; wave per list scans SCB partials ----
__global__ __launch_bounds__(256) void k_scanB(int* part, int* tots){
  int wid = threadIdx.x>>6, lane = threadIdx.x&63;
  if(wid >= 3) return;
  int base = wid*SCB;
  int v0 = part[base + lane];
  int i1 = 64 + lane;
  int v1 = (i1 < SCB) ? part[base + i1] : 0;
  int x0 = v0, x1 = v1;
  #pragma unroll
  for(int off=1; off<64; off<<=1){
    int t0=__shfl_up(x0,off,64), t1=__shfl_up(x1,off,64);
    if(lane>=off){ x0+=t0; x1+=t1; }
  }
  int t0 = __shfl(x0, 63, 64);
  int t1 = __shfl(x1, 63, 64);
  part[base + lane] = x0 - v0;
  if(i1 < SCB) part[base + i1] = t0 + x1 - v1;
  if(lane == 0) tots[wid] = t0 + t1;
}

// ---- scan phase C: add block offsets, write cursor + totals ----
__global__ __launch_bounds__(256) void k_scanC(int* s0, int* s1, int* s2,
                                               int* u0, int* u1, int* u2,
                                               const int* part, const int* tots){
  int y = blockIdx.y;
  int* start  = y==0 ? s0 : (y==1 ? s1 : s2);
  int* cursor = y==0 ? u0 : (y==1 ? u1 : u2);
  int i = blockIdx.x*256 + threadIdx.x;
  int off = part[y*SCB + blockIdx.x];
  if(i < N_ENT){ int v = start[i] + off; start[i] = v; cursor[i] = v; }
  if(i == 0) start[N_ENT] = tots[y];
}

// ---- scatter all three edge lists into CSR order, one launch ----
__global__ __launch_bounds__(256) void k_scatter3(
      const int* __restrict__ rA, const int* __restrict__ cAj, const int* __restrict__ rid,
      int* uA, int* scolA, int* sridA,
      const int* __restrict__ rE, const int* __restrict__ cEj, int* uE, int* scolE,
      const int* __restrict__ rR, const int* __restrict__ cRj, int* uR, int* scolR){
  int e = blockIdx.x*256 + threadIdx.x;
  if(e < T_EDGE){
    int p = atomicAdd(&uA[rA[e]], 1);
    scolA[p] = cAj[e];
    sridA[p] = rid[e];
  }
  if(e < NNZ_E){
    int p = atomicAdd(&uE[rE[e]], 1);
    scolE[p] = cEj[e];
    int q = atomicAdd(&uR[rR[e]], 1);
    scolR[q] = cRj[e];
  }
}

// ---- _avg via CSR gather from fp16 src (ent: y=0, rel: y=1), fused tanh ----
__global__ __launch_bounds__(256) void k_avg2(const int* __restrict__ startE, const int* __restrict__ scolE,
                        const _Float16* __restrict__ srcE,
                        const int* __restrict__ startR, const int* __restrict__ scolR,
                        const _Float16* __restrict__ srcR,
                        _Float16* featC, _Float16* Eh){
  int which = blockIdx.y;
  const int* start = which? startR : startE;
  const int* scol  = which? scolR : scolE;
  const _Float16* src = which? srcR : srcE;
  int pairOff = which? 2 : 0;
  int coloff  = which? 384 : 0;
  int r = blockIdx.x*4 + (threadIdx.x>>6);
  int lane = threadIdx.x & 63;
  int s0 = start[r], s1 = start[r+1];
  float ax=0.f, ay=0.f;
  int e = s0;
  for(; e+1<s1; e+=2){
    int c0 = scol[e], c1 = scol[e+1];
    half2v v0 = *(const half2v*)(src + (size_t)c0*128 + lane*2);
    half2v v1 = *(const half2v*)(src + (size_t)c1*128 + lane*2);
    ax += (float)v0[0] + (float)v1[0]; ay += (float)v0[1] + (float)v1[1];
  }
  if(e<s1){
    int c0 = scol[e];
    half2v v0 = *(const half2v*)(src + (size_t)c0*128 + lane*2);
    ax += (float)v0[0]; ay += (float)v0[1];
  }
  float inv = (s1>s0) ? 1.0f/(float)(s1-s0) : 0.f;
  float vx = fast_tanh(ax*inv), vy = fast_tanh(ay*inv);
  half2v hv = {(_Float16)vx, (_Float16)vy};
  *(half2v*)(featC + (size_t)r*256 + lane*4 + pairOff) = hv;
  *(half2v*)(Eh + (size_t)r*EMBD + coloff + lane*2) = hv;
}

// ---- fused dual-stack GAT layer: one pass does ent+rel Householder+softmax ----
__global__ __launch_bounds__(256) void k_edge2(const int* __restrict__ start, const int* __restrict__ scol,
      const int* __restrict__ srid, const _Float16* __restrict__ relnH,
      const float* __restrict__ expE, const float* __restrict__ expR,
      const _Float16* __restrict__ featIn, _Float16* featOut, _Float16* Eh, int colEnt, int colRel){
  int r = blockIdx.x*4 + (threadIdx.x>>6);
  int lane = threadIdx.x & 63;
  int s0 = start[r], s1 = start[r+1];
  float aEx=0,aEy=0,aRx=0,aRy=0, swE=0, swR=0;
  int e = s0;
  for(; e+1<s1; e+=2){
    int c0=scol[e], q0=srid[e], c1=scol[e+1], q1=srid[e+1];
    float wE0=expE[q0], wR0=expR[q0], wE1=expE[q1], wR1=expR[q1];
    half2v u0h = *(const half2v*)(relnH + (size_t)q0*128 + lane*2);
    half2v u1h = *(const half2v*)(relnH + (size_t)q1*128 + lane*2);
    half4v h0 = *(const half4v*)(featIn + (size_t)c0*256 + lane*4);
    half4v h1 = *(const half4v*)(featIn + (size_t)c1*256 + lane*4);
    float u0x=(float)u0h[0], u0y=(float)u0h[1], u1x=(float)u1h[0], u1y=(float)u1h[1];
    float e0x=(float)h0[0], e0y=(float)h0[1], r0x=(float)h0[2], r0y=(float)h0[3];
    float e1x=(float)h1[0], e1y=(float)h1[1], r1x=(float)h1[2], r1y=(float)h1[3];
    float d0 = e0x*u0x + e0y*u0y;
    float d1 = r0x*u0x + r0y*u0y;
    float d2 = e1x*u1x + e1y*u1y;
    float d3 = r1x*u1x + r1y*u1y;
    #pragma unroll
    for(int m=32;m>=1;m>>=1){
      d0 += __shfl_xor(d0,m,64); d1 += __shfl_xor(d1,m,64);
      d2 += __shfl_xor(d2,m,64); d3 += __shfl_xor(d3,m,64);
    }
    aEx += wE0*(e0x - 2.f*d0*u0x) + wE1*(e1x - 2.f*d2*u1x);
    aEy += wE0*(e0y - 2.f*d0*u0y) + wE1*(e1y - 2.f*d2*u1y);
    aRx += wR0*(r0x - 2.f*d1*u0x) + wR1*(r1x - 2.f*d3*u1x);
    aRy += wR0*(r0y - 2.f*d1*u0y) + wR1*(r1y - 2.f*d3*u1y);
    swE += wE0+wE1; swR += wR0+wR1;
  }
  if(e<s1){
    int c0=scol[e], q0=srid[e];
    float wE0=expE[q0], wR0=expR[q0];
    half2v u0h = *(const half2v*)(relnH + (size_t)q0*128 + lane*2);
    half4v h0 = *(const half4v*)(featIn + (size_t)c0*256 + lane*4);
    float u0x=(float)u0h[0], u0y=(float)u0h[1];
    float e0x=(float)h0[0], e0y=(float)h0[1], r0x=(float)h0[2], r0y=(float)h0[3];
    float d0 = e0x*u0x + e0y*u0y;
    float d1 = r0x*u0x + r0y*u0y;
    #pragma unroll
    for(int m=32;m>=1;m>>=1){ d0 += __shfl_xor(d0,m,64); d1 += __shfl_xor(d1,m,64); }
    aEx += wE0*(e0x - 2.f*d0*u0x);
    aEy += wE0*(e0y - 2.f*d0*u0y);
    aRx += wR0*(r0x - 2.f*d1*u0x);
    aRy += wR0*(r0y - 2.f*d1*u0y);
    swE += wE0; swR += wR0;
  }
  float iE = (s1>s0) ? 1.f/swE : 0.f;
  float iR = (s1>s0) ? 1.f/swR : 0.f;
  float vEx = fast_tanh(aEx*iE), vEy = fast_tanh(aEy*iE);
  float vRx = fast_tanh(aRx*iR), vRy = fast_tanh(aRy*iR);
  half4v ov = {(_Float16)vEx,(_Float16)vEy,(_Float16)vRx,(_Float16)vRy};
  *(half4v*)(featOut + (size_t)r*256 + lane*4) = ov;
  half2v he = {(_Float16)vEx,(_Float16)vEy};
  half2v hr = {(_Float16)vRx,(_Float16)vRy};
  *(half2v*)(Eh + (size_t)r*EMBD + colEnt + lane*2) = he;
  *(half2v*)(Eh + (size_t)r*EMBD + colRel + lane*2) = hr;
}

// ---- fused post-GAT pass: transp (b<5760) | gather (b<6784) | qnstats (b<7024) ----
__global__ __launch_bounds__(256) void k_post(const _Float16* __restrict__ Eh, _Float16* embT,
      const int* __restrict__ tp, _Float16* Wh, float* cvec,
      float* qn, float* Svec, float* Pvec, float* QQ){
  __shared__ __align__(16) _Float16 til[64][72];
  __shared__ float sh0[256], sh1[256], sh2[256];
  int b = blockIdx.x;
  int tid = threadIdx.x;
  if(b < 5760){
    // ---- transpose Eh -> embT (768 x NPAD) ----
    int r0 = (b % 480)*64, c0 = (b / 480)*64;
    int rr = tid>>3, c8 = (tid&7)*8;
    #pragma unroll
    for(int p=0;p<2;p++){
      int gr = r0 + rr + p*32;
      uint4 v = make_uint4(0u,0u,0u,0u);
      if(gr < N_ENT) v = *(const uint4*)(Eh + (size_t)gr*EMBD + c0 + c8);
      *(uint4*)&til[rr + p*32][c8] = v;
    }
    __syncthreads();
    #pragma unroll
    for(int p=0;p<2;p++){
      int cc = rr + p*32;
      __align__(16) _Float16 tmp[8];
      #pragma unroll
      for(int j=0;j<8;j++) tmp[j] = til[c8 + j][cc];
      *(uint4*)(embT + (size_t)(c0+cc)*NPAD + r0 + c8) = *(uint4*)tmp;
    }
  } else if(b < 5760 + B_PAIR){
    // ---- gather pair rows -> Wh, cvec ----
    int i = b - 5760;
    int l = tp[2*i], r = tp[2*i+1];
    float sl=0.f, sr=0.f, sp=0.f;
    for(int c=tid;c<EMBD;c+=256){
      _Float16 lh = Eh[(size_t)l*EMBD+c], rh = Eh[(size_t)r*EMBD+c];
      float le = (float)lh, re = (float)rh;
      Wh[(size_t)i*EMBD+c]=lh; Wh[(size_t)(B_PAIR+i)*EMBD+c]=rh;
      sl += le*le; sr += re*re; float d = le-re; sp += d*d;
    }
    sh0[tid]=sl; sh1[tid]=sr; sh2[tid]=sp;
    __syncthreads();
    for(int w=128;w>0;w>>=1){
      if(tid<w){ sh0[tid]+=sh0[tid+w]; sh1[tid]+=sh1[tid+w]; sh2[tid]+=sh2[tid+w]; }
      __syncthreads();
    }
    if(tid==0){
      float pos = sh2[0];
      cvec[i]        = pos + GAMMAF - sh0[0];
      cvec[B_PAIR+i] = pos + GAMMAF - sh1[0];
    }
  } else {
    // ---- qn + embstats: wave per row, strided over 960 waves ----
    int wid = tid>>6, lane = tid&63;
    int gw = (b - 5760 - B_PAIR)*4 + wid;
    float s[12], p[12];
    #pragma unroll
    for(int q=0;q<12;q++){ s[q]=0.f; p[q]=0.f; }
    float q1=0.f, q2=0.f;
    for(int r=gw; r<NPAD; r+=960){
      if(r >= N_ENT){ if(lane==0) qn[r] = 1e30f; continue; }
      float v[12]; float ss=0.f;
      #pragma unroll
      for(int q=0;q<12;q++){ v[q] = (float)Eh[(size_t)r*EMBD + lane + 64*q]; ss += v[q]*v[q]; }
      ss = waveRedSum(ss);
      ss = __shfl(ss, 0, 64);
      if(lane==0){ qn[r] = ss; q1 += ss; q2 += ss*ss; }
      #pragma unroll
      for(int q=0;q<12;q++){ s[q] += v[q]; p[q] += ss*v[q]; }
    }
    #pragma unroll
    for(int q=0;q<12;q++){
      unsafeAtomicAdd(&Svec[lane + 64*q], s[q]);
      unsafeAtomicAdd(&Pvec[lane + 64*q], p[q]);
    }
    if(lane==0){ unsafeAtomicAdd(&QQ[0], q1); unsafeAtomicAdd(&QQ[1], q2); }
  }
}

// ---- G = E^T E via f16 MFMA on embT; 128x128 tiles, split-K 16 with XCD-owned k-slices ----
//      grid 576: xcd = id&7, rest = id>>3; kslice = xcd + 8*(rest/36); tile = rest%36
__global__ __launch_bounds__(256) void k_syrk(const _Float16* __restrict__ embT, float* G){
  __shared__ __align__(16) _Float16 As[128*64];
  __shared__ __align__(16) _Float16 Bs[128*64];
  int id = blockIdx.x;
  int xcd = id & 7, rest = id >> 3;
  int kslc = xcd + 8*(rest/36);
  int tile = rest % 36;
  int m0 = (tile/6)*128, n0 = (tile%6)*128;
  int kbeg = kslc*1920, kend = kbeg + 1920;
  int tid = threadIdx.x;
  int w = tid>>6, lane = tid&63;
  int quad = lane>>4, l15 = lane&15;
  int lr = lane>>3, lc = lane&7;
  int wm = (w>>1)*64, wn = (w&1)*64;
  f32x4 acc[4][4];
  #pragma unroll
  for(int i=0;i<4;i++)
    #pragma unroll
    for(int j=0;j<4;j++) acc[i][j] = (f32x4){0.f,0.f,0.f,0.f};
  for(int k0=kbeg;k0<kend;k0+=64){
    #pragma unroll
    for(int p=0;p<4;p++){
      int r = p*32 + w*8 + lr;
      int cg = lc ^ (r&7);
      gl_lds16(embT + (size_t)(m0+r)*NPAD + k0 + cg*8, As + (p*32 + w*8)*64);
      gl_lds16(embT + (size_t)(n0+r)*NPAD + k0 + cg*8, Bs + (p*32 + w*8)*64);
    }
    __syncthreads();
    #pragma unroll
    for(int ks=0;ks<2;ks++){
      half8 af[4], bf[4];
      #pragma unroll
      for(int i=0;i<4;i++){
        int ml = wm + i*16 + l15;
        af[i] = *(half8*)(As + ml*64 + (((ks<<2)|quad) ^ (ml&7))*8);
      }
      #pragma unroll
      for(int j=0;j<4;j++){
        int nl = wn + j*16 + l15;
        bf[j] = *(half8*)(Bs + nl*64 + (((ks<<2)|quad) ^ (nl&7))*8);
      }
      #pragma unroll
      for(int i=0;i<4;i++)
        #pragma unroll
        for(int j=0;j<4;j++)
          acc[i][j] = __builtin_amdgcn_mfma_f32_16x16x32_f16(af[i], bf[j], acc[i][j], 0,0,0);
    }
    __syncthreads();
  }
  #pragma unroll
  for(int i=0;i<4;i++){
    #pragma unroll
    for(int r=0;r<4;r++){
      int m = m0 + wm + i*16 + quad*4 + r;
      #pragma unroll
      for(int j=0;j<4;j++){
        int n = n0 + wn + j*16 + l15;
        unsafeAtomicAdd(&G[(size_t)m*EMBD + n], acc[i][j][r]);
      }
    }
  }
}

// ---- T = Wh * G (G symmetric, fp32; convert inline), no-LDS MFMA ----
__global__ __launch_bounds__(256) void k_gemmTh(const _Float16* __restrict__ Wh, const float* __restrict__ G,
                                                float* Tm){
  int tid = threadIdx.x, w = tid>>6, lane = tid&63;
  int quad = lane>>4, l15 = lane&15;
  int n0 = blockIdx.x*64;
  #pragma unroll
  for(int half=0; half<2; half++){
    int m0 = (blockIdx.y*8 + half*4 + w)*64;
    f32x4 acc[4][4];
    #pragma unroll
    for(int i=0;i<4;i++)
      #pragma unroll
      for(int j=0;j<4;j++) acc[i][j] = (f32x4){0.f,0.f,0.f,0.f};
    const _Float16* aB[4]; const float* bB[4];
    #pragma unroll
    for(int i=0;i<4;i++){
      aB[i] = Wh + (size_t)(m0+i*16+l15)*EMBD + quad*8;
      bB[i] = G  + (size_t)(n0+i*16+l15)*EMBD + quad*8;
    }
    for(int ks=0; ks<24; ks++){
      half8 af[4], bf[4];
      #pragma unroll
      for(int i=0;i<4;i++) af[i] = *(const half8*)(aB[i] + ks*32);
      #pragma unroll
      for(int j=0;j<4;j++){
        float4 f0 = *(const float4*)(bB[j] + ks*32);
        float4 f1 = *(const float4*)(bB[j] + ks*32 + 4);
        half8 h = {(_Float16)f0.x,(_Float16)f0.y,(_Float16)f0.z,(_Float16)f0.w,
                   (_Float16)f1.x,(_Float16)f1.y,(_Float16)f1.z,(_Float16)f1.w};
        bf[j] = h;
      }
      #pragma unroll
      for(int i=0;i<4;i++)
        #pragma unroll
        for(int j=0;j<4;j++)
          acc[i][j] = __builtin_amdgcn_mfma_f32_16x16x32_f16(af[i], bf[j], acc[i][j], 0,0,0);
    }
    #pragma unroll
    for(int i=0;i<4;i++)
      #pragma unroll
      for(int r=0;r<4;r++){
        int mg = m0 + i*16 + quad*4 + r;
        #pragma unroll
        for(int j=0;j<4;j++)
          Tm[(size_t)mg*EMBD + n0 + j*16 + l15] = acc[i][j][r];
      }
  }
}

// ---- per-row closed-form stats ----
__global__ __launch_bounds__(256) void k_rowstats(const _Float16* __restrict__ Wh, const float* __restrict__ Tm,
      const _Float16* __restrict__ Eh, const float* __restrict__ qn, const float* __restrict__ cvec,
      const int* __restrict__ tp, const float* __restrict__ Svec, const float* __restrict__ Pvec,
      const float* __restrict__ QQ, float* alpha, float* betav){
  int row = blockIdx.x*4 + (threadIdx.x>>6);
  int lane = threadIdx.x & 63;
  if(row >= 2*B_PAIR) return;
  int pi = row & (B_PAIR-1);
  int lp = tp[2*pi], rp = tp[2*pi+1];
  float d1=0,d2=0,d3=0,dl=0,dr=0;
  #pragma unroll
  for(int k=0;k<12;k++){
    int d = lane + 64*k;
    float a = (float)Wh[(size_t)row*EMBD + d];
    d1 += a*Svec[d];
    d2 += a*Pvec[d];
    d3 += a*Tm[(size_t)row*EMBD + d];
    dl += a*(float)Eh[(size_t)lp*EMBD + d];
    dr += a*(float)Eh[(size_t)rp*EMBD + d];
  }
  d1=waveRedSum(d1); d2=waveRedSum(d2); d3=waveRedSum(d3);
  dl=waveRedSum(dl); dr=waveRedSum(dr);
  if(lane==0){
    double c = (double)cvec[row], Q = (double)QQ[0], Q2 = (double)QQ[1], Nn = (double)N_ENT;
    double su  = Nn*c - Q + 2.0*(double)d1;
    double su2 = Nn*c*c - 2.0*c*Q + Q2 + 4.0*(c*(double)d1 - (double)d2) + 4.0*(double)d3;
    double ul = c - (double)qn[lp] + 2.0*(double)dl;
    double ur = c - (double)qn[rp] + 2.0*(double)dr;
    su -= ul + ur;
    if(lp != rp) su2 -= ul*ul + ur*ur;
    double mu = su/Nn;
    double var = su2/Nn - mu*mu;
    double sd = sqrt(fmax(var, 0.0));
    double al = 20.0/sd;
    alpha[row] = (float)al;
    betav[row] = (float)(8.0 - al*mu);
  }
}

__device__ inline void lseMerge(float& mx, float& sm, float om, float os){
  if(om > mx){ sm = sm*expf(mx-om) + os; mx = om; }
  else if(om != -INFINITY){ sm += os*expf(om-mx); }
}

// ---- pass B: 128x128 f16 MFMA (DMA staging + XOR swizzle), in-loop masked online-lse epilogue.
//      1D grid 3840, XCD-ownership: id = xcd + 8*m + 128*tt -> ntile = xcd + 8*tt.
__global__ __launch_bounds__(256,3) void k_gemmB(const _Float16* __restrict__ Wh, const _Float16* __restrict__ Eh,
    const float* __restrict__ cvec, const float* __restrict__ qn, const int* __restrict__ tp,
    const float* __restrict__ alpha, const float* __restrict__ betav, float* pm, float* ps){
  __shared__ __align__(16) _Float16 As[128*64];
  __shared__ __align__(16) _Float16 Bs[128*64];
  int id = blockIdx.x;
  int ntile = (id & 7) + ((id >> 7) << 3);
  int m0 = ((id >> 3) & 15) * 128;
  int n0 = ntile * 128;
  int tid = threadIdx.x;
  int w = tid>>6, lane = tid&63;
  int quad = lane>>4, l15 = lane&15;
  int lr = lane>>3, lc = lane&7;
  int wm = (w&1)*64, wn = (w>>1)*64;
  f32x4 acc[4][4];
  #pragma unroll
  for(int i=0;i<4;i++)
    #pragma unroll
    for(int j=0;j<4;j++) acc[i][j] = (f32x4){0.f,0.f,0.f,0.f};
  for(int k0=0;k0<EMBD;k0+=64){
    #pragma unroll
    for(int p=0;p<4;p++){
      int r = p*32 + w*8 + lr;
      int cg = lc ^ (r&7);
      gl_lds16(Wh + (size_t)(m0+r)*EMBD + k0 + cg*8, As + (p*32 + w*8)*64);
      gl_lds16(Eh + (size_t)(n0+r)*EMBD + k0 + cg*8, Bs + (p*32 + w*8)*64);
    }
    __syncthreads();
    #pragma unroll
    for(int ks=0;ks<2;ks++){
      half8 af[4], bf[4];
      #pragma unroll
      for(int i=0;i<4;i++){
        int ml = wm + i*16 + l15;
        af[i] = *(half8*)(As + ml*64 + (((ks<<2)|quad) ^ (ml&7))*8);
      }
      #pragma unroll
      for(int j=0;j<4;j++){
        int nl = wn + j*16 + l15;
        bf[j] = *(half8*)(Bs + nl*64 + (((ks<<2)|quad) ^ (nl&7))*8);
      }
      #pragma unroll
      for(int i=0;i<4;i++)
        #pragma unroll
        for(int j=0;j<4;j++)
          acc[i][j] = __builtin_amdgcn_mfma_f32_16x16x32_f16(af[i], bf[j], acc[i][j], 0,0,0);
    }
    __syncthreads();
  }
  // epilogue: masked loss -> z -> online lse over this wave's 64 cols; reduce 16 lanes/row.
  float qv[4]; int jv[4];
  #pragma unroll
  for(int j=0;j<4;j++){ jv[j] = n0 + wn + j*16 + l15; qv[j] = qn[jv[j]]; }
  int ptile = ntile*2 + (w>>1);
  #pragma unroll
  for(int i=0;i<4;i++){
    int mbase = m0 + wm + i*16 + quad*4;
    #pragma unroll
    for(int r=0;r<4;r++){
      int mg = mbase + r;
      int pi = mg & (B_PAIR-1);
      int lp = tp[2*pi], rp = tp[2*pi+1];
      float cv = cvec[mg], al = alpha[mg], be = betav[mg];
      float mx = -INFINITY, sm = 0.f;
      #pragma unroll
      for(int j=0;j<4;j++){
        float u = fmaf(2.f, acc[i][j][r], cv - qv[j]);
        float z = fmaf(al, u, be);
        if(jv[j]==lp || jv[j]==rp) z = (lp==rp) ? fmaf(-al, u, be) : be;
        if(z > mx){ sm = sm*__expf(mx - z) + 1.f; mx = z; }
        else sm += __expf(z - mx);
      }
      #pragma unroll
      for(int m=8;m>=1;m>>=1){
        float om = __shfl_xor(mx, m, 64), os = __shfl_xor(sm, m, 64);
        lseMerge(mx, sm, om, os);
      }
      if(l15==0){ pm[(size_t)mg*PTILES + ptile] = mx; ps[(size_t)mg*PTILES + ptile] = sm; }
    }
  }
}

// ---- combine per-tile LSE partials + fused final mean via atomic ticket: block per row ----
__global__ __launch_bounds__(256) void k_lse2(const float* __restrict__ pm, const float* __restrict__ ps,
                        float* accum, int* done, float* out){
  __shared__ float shm[256], shs[256];
  int row = blockIdx.x, tid = threadIdx.x;
  float mx = -INFINITY, sm = 0.f;
  for(int t=tid;t<PTILES;t+=256) lseMerge(mx, sm, pm[(size_t)row*PTILES+t], ps[(size_t)row*PTILES+t]);
  shm[tid]=mx; shs[tid]=sm;
  __syncthreads();
  for(int w=128;w>0;w>>=1){
    if(tid<w){
      float m2=shm[tid], s2=shs[tid];
      lseMerge(m2, s2, shm[tid+w], shs[tid+w]);
      shm[tid]=m2; shs[tid]=s2;
    }
    __syncthreads();
  }
  if(tid==0){
    float l = shm[0] + logf(shs[0]);
    atomicAdd(accum, l);
    __threadfence();
    int t = atomicAdd(done, 1);
    if(t == 2*B_PAIR - 1){
      __threadfence();
      float total = atomicAdd(accum, 0.0f);
      out[0] = total / (float)B_PAIR;
    }
  }
}

extern "C" void kernel_launch(void* const* d_in, const int* in_sizes, int n_in,
                              void* d_out, int out_size, void* d_ws, size_t ws_size,
                              hipStream_t stream) {
  const float* ent_emb = (const float*)d_in[0];
  const float* rel_emb = (const float*)d_in[1];
  const float* attn_e  = (const float*)d_in[2];
  const float* attn_r  = (const float*)d_in[3];
  const int* adj     = (const int*)d_in[5];
  const int* r_index = (const int*)d_in[6];
  const int* ent_adj = (const int*)d_in[7];
  const int* rel_adj = (const int*)d_in[8];
  const int* tp      = (const int*)d_in[9];
  float* out = (float*)d_out;

  const int* adj_row = adj;
  const int* adj_col = adj + T_EDGE;
  const int* rid1    = r_index + T_EDGE;

  char* base = (char*)d_ws;
  size_t off = 0;
  auto A = [&](size_t b)->void*{ void* p = base + off; off = (off + b + 255) & ~(size_t)255; return p; };
  // zero region
  int*   cntA  = (int*)  A((size_t)N_ENT*4);
  int*   cntE  = (int*)  A((size_t)N_ENT*4);
  int*   cntR  = (int*)  A((size_t)N_ENT*4);
  float* G     = (float*)A((size_t)EMBD*EMBD*4);
  float* Svec  = (float*)A(EMBD*4);
  float* Pvec  = (float*)A(EMBD*4);
  float* QQ    = (float*)A(2*4);
  float* accum = (float*)A(4);
  int*   done  = (int*)  A(4);
  size_t zero_end = off;
  // plain buffers
  int* startA = (int*)A((size_t)(N_ENT+1)*4);
  int* startE = (int*)A((size_t)(N_ENT+1)*4);
  int* startR = (int*)A((size_t)(N_ENT+1)*4);
  int* curA   = (int*)A((size_t)N_ENT*4);
  int* curE   = (int*)A((size_t)N_ENT*4);
  int* curR   = (int*)A((size_t)N_ENT*4);
  int* part   = (int*)A(3*SCB*4);
  int* tots   = (int*)A(3*4);
  int* scolA  = (int*)A((size_t)T_EDGE*4);
  int* sridA  = (int*)A((size_t)T_EDGE*4);
  int* scolE  = (int*)A((size_t)NNZ_E*4);
  int* scolR  = (int*)A((size_t)NNZ_E*4);
  _Float16* Eh = (_Float16*)A((size_t)NPAD*EMBD*2);   // pad rows zeroed in k_prep
  // region X: phase-aliased (featC0/featC1 -> embT -> pm/ps)
  char* X = (char*)A((size_t)EMBD*NPAD*2);   // 47.2 MB
  _Float16* featC0 = (_Float16*)X;                       // 15.4 MB
  _Float16* featC1 = (_Float16*)(X + 16u*1024u*1024u);   // 15.4 MB
  _Float16* embT   = (_Float16*)X;
  float*    pm     = (float*)X;                          // 2048*480*4 = 3.93 MB
  float*    ps     = (float*)(X + 8u*1024u*1024u);
  _Float16* relnH  = (_Float16*)A((size_t)R_REL*128*2);
  _Float16* ehE   = (_Float16*)A((size_t)N_ENT*128*2);
  _Float16* ehR   = (_Float16*)A((size_t)R_REL*128*2);
  float* expdot  = (float*)A(4*R_REL*4);
  _Float16* Wh   = (_Float16*)A((size_t)2*B_PAIR*EMBD*2);
  float* Tm      = (float*)A((size_t)2*B_PAIR*EMBD*4);
  float* cvec    = (float*)A(2*B_PAIR*4);
  float* qn      = (float*)A((size_t)NPAD*4);
  float* alpha   = (float*)A(2*B_PAIR*4);
  float* betav   = (float*)A(2*B_PAIR*4);
  (void)ws_size; (void)in_sizes; (void)n_in; (void)out_size;

  hipMemsetAsync(d_ws, 0, zero_end, stream);

  // ---- fused prep: fp16 conversion + Eh pad zero + relnorm/expdot + edge counts ----
  k_prep<<<(N_ENT*128+255)/256, 256, 0, stream>>>(ent_emb, rel_emb, attn_e, attn_r,
                                                  ehE, ehR, Eh, relnH, expdot,
                                                  adj_row, cntA, ent_adj, cntE, rel_adj, cntR);

  // ---- parallel 3-phase scan ----
  dim3 gsa(SCB, 3);
  k_scanA<<<gsa, 256, 0, stream>>>(cntA, cntE, cntR, startA, startE, startR, part);
  k_scanB<<<1, 256, 0, stream>>>(part, tots);
  k_scanC<<<gsa, 256, 0, stream>>>(startA, startE, startR, curA, curE, curR, part, tots);
  k_scatter3<<<(NNZ_E+255)/256, 256, 0, stream>>>(adj_row, adj_col, rid1, curA, scolA, sridA,
                                                  ent_adj, ent_adj+NNZ_E, curE, scolE,
                                                  rel_adj, rel_adj+NNZ_E, curR, scolR);

  // ---- fused dual GAT stack: avg (ent|rel merged) -> layer0 -> layer1 ----
  dim3 gavg(N_ENT/4, 2);
  k_avg2<<<gavg, 256, 0, stream>>>(startE, scolE, ehE, startR, scolR, ehR, featC0, Eh);
  k_edge2<<<N_ENT/4, 256, 0, stream>>>(startA, scolA, sridA, relnH, expdot + 0*R_REL, expdot + 2*R_REL,
                                       featC0, featC1, Eh, 128, 512);
  k_edge2<<<N_ENT/4, 256, 0, stream>>>(startA, scolA, sridA, relnH, expdot + 1*R_REL, expdot + 3*R_REL,
                                       featC1, featC0, Eh, 256, 640);

  // ---- fused post pass: transp | gather | qnstats ----
  k_post<<<5760 + B_PAIR + 240, 256, 0, stream>>>(Eh, embT, tp, Wh, cvec, qn, Svec, Pvec, QQ);

  // ---- align loss ----
  k_syrk<<<576, 256, 0, stream>>>(embT, G);
  dim3 gT(EMBD/64, 4);
  k_gemmTh<<<gT, 256, 0, stream>>>(Wh, G, Tm);
  k_rowstats<<<2*B_PAIR/4, 256, 0, stream>>>(Wh, Tm, Eh, qn, cvec, tp, Svec, Pvec, QQ, alpha, betav);
  k_gemmB<<<NT128*16, 256, 0, stream>>>(Wh, Eh, cvec, qn, tp, alpha, betav, pm, ps);
  k_lse2<<<2*B_PAIR, 256, 0, stream>>>(pm, ps, accum, done, out);
}